// Round 1
// baseline (930.173 us; speedup 1.0000x reference)
//
#include <hip/hip_runtime.h>
#include <hip/hip_bf16.h>
#include <math.h>

// Problem constants
#define VOCAB 30522
#define EMB 768
#define MAXPOS 512
#define HID 512
#define IMG 2048
#define ATT 256
#define BB 32      // batch
#define LL 512     // text length
#define SS 6       // images/history slots
#define HL 128     // history length
#define LN_EPS 1e-12f

// ---------------- reduction helpers ----------------
__device__ __forceinline__ float wave_sum(float v) {
    v += __shfl_xor(v, 1);  v += __shfl_xor(v, 2);  v += __shfl_xor(v, 4);
    v += __shfl_xor(v, 8);  v += __shfl_xor(v, 16); v += __shfl_xor(v, 32);
    return v;
}
__device__ __forceinline__ float wave_max(float v) {
    v = fmaxf(v, __shfl_xor(v, 1));  v = fmaxf(v, __shfl_xor(v, 2));
    v = fmaxf(v, __shfl_xor(v, 4));  v = fmaxf(v, __shfl_xor(v, 8));
    v = fmaxf(v, __shfl_xor(v, 16)); v = fmaxf(v, __shfl_xor(v, 32));
    return v;
}

// ---------------- 1. BERT embed + LayerNorm for text ----------------
// one block (256 thr) per row; row r: b = r/LL, l = r%LL
__global__ void embed_ln_text(const int* __restrict__ ids,
                              const float* __restrict__ we,
                              const float* __restrict__ pe,
                              const float* __restrict__ te,
                              const float* __restrict__ g,
                              const float* __restrict__ bta,
                              float* __restrict__ out) {
    int r = blockIdx.x;
    int l = r & (LL - 1);
    int id = ids[r];
    const float* wrow = we + (size_t)id * EMB;
    const float* prow = pe + (size_t)l * EMB;
    int tid = threadIdx.x;
    float x0 = wrow[tid]       + prow[tid]       + te[tid];
    float x1 = wrow[tid + 256] + prow[tid + 256] + te[tid + 256];
    float x2 = wrow[tid + 512] + prow[tid + 512] + te[tid + 512];
    float s  = x0 + x1 + x2;
    float ss = x0 * x0 + x1 * x1 + x2 * x2;
    s = wave_sum(s); ss = wave_sum(ss);
    __shared__ float as_[4], ass_[4];
    int wid = tid >> 6, lane = tid & 63;
    if (lane == 0) { as_[wid] = s; ass_[wid] = ss; }
    __syncthreads();
    float tot  = as_[0] + as_[1] + as_[2] + as_[3];
    float tots = ass_[0] + ass_[1] + ass_[2] + ass_[3];
    float mu = tot * (1.0f / EMB);
    float var = tots * (1.0f / EMB) - mu * mu;
    float rs = rsqrtf(var + LN_EPS);
    float* orow = out + (size_t)r * EMB;
    orow[tid]       = g[tid]       * (x0 - mu) * rs + bta[tid];
    orow[tid + 256] = g[tid + 256] * (x1 - mu) * rs + bta[tid + 256];
    orow[tid + 512] = g[tid + 512] * (x2 - mu) * rs + bta[tid + 512];
}

// ---------------- 2. generic fp32 GEMM: C = act(A@B + bias (+ rowadd)) ----
// A: [M,K] lda=K ; B(weights): [K,N] row-major ldb=N ; C: [M,N]
// ACT: 0 none, 1 relu, 2 tanh.  HAS_ROWADD: acc += rowadd[(r/rowdiv)*N + c]
template <int ACT, bool HAS_ROWADD>
__global__ void gemm64(const float* __restrict__ A, int lda,
                       const float* __restrict__ B, int ldb,
                       const float* __restrict__ bias,
                       const float* __restrict__ rowadd, int rowdiv,
                       float* __restrict__ C, int ldc,
                       int M, int N, int K) {
    __shared__ float As[16][64];
    __shared__ float Bs[16][64];
    int tid = threadIdx.x;
    int tx = tid & 15, ty = tid >> 4;
    int col0 = blockIdx.x * 64;
    int row0 = blockIdx.y * 64;

    float acc[4][4] = {};
    int ar = tid >> 2;          // 0..63
    int ak = (tid & 3) << 2;    // 0,4,8,12
    int bk = tid >> 4;          // 0..15
    int bn = (tid & 15) << 2;   // 0..60

    for (int k0 = 0; k0 < K; k0 += 16) {
        float4 av;
        int arow = row0 + ar;
        if (arow < M) av = *(const float4*)(A + (size_t)arow * lda + k0 + ak);
        else av = make_float4(0.f, 0.f, 0.f, 0.f);
        As[ak + 0][ar] = av.x; As[ak + 1][ar] = av.y;
        As[ak + 2][ar] = av.z; As[ak + 3][ar] = av.w;
        *(float4*)&Bs[bk][bn] =
            *(const float4*)(B + (size_t)(k0 + bk) * ldb + col0 + bn);
        __syncthreads();
#pragma unroll
        for (int kk = 0; kk < 16; kk++) {
            float a0 = As[kk][ty * 4 + 0], a1 = As[kk][ty * 4 + 1];
            float a2 = As[kk][ty * 4 + 2], a3 = As[kk][ty * 4 + 3];
            float b0 = Bs[kk][tx * 4 + 0], b1 = Bs[kk][tx * 4 + 1];
            float b2 = Bs[kk][tx * 4 + 2], b3 = Bs[kk][tx * 4 + 3];
            acc[0][0] += a0 * b0; acc[0][1] += a0 * b1; acc[0][2] += a0 * b2; acc[0][3] += a0 * b3;
            acc[1][0] += a1 * b0; acc[1][1] += a1 * b1; acc[1][2] += a1 * b2; acc[1][3] += a1 * b3;
            acc[2][0] += a2 * b0; acc[2][1] += a2 * b1; acc[2][2] += a2 * b2; acc[2][3] += a2 * b3;
            acc[3][0] += a3 * b0; acc[3][1] += a3 * b1; acc[3][2] += a3 * b2; acc[3][3] += a3 * b3;
        }
        __syncthreads();
    }
#pragma unroll
    for (int i = 0; i < 4; i++) {
        int r = row0 + ty * 4 + i;
        if (r >= M) break;
#pragma unroll
        for (int j = 0; j < 4; j++) {
            int c = col0 + tx * 4 + j;
            float v = acc[i][j];
            if (bias) v += bias[c];
            if (HAS_ROWADD) v += rowadd[(size_t)(r / rowdiv) * N + c];
            if (ACT == 1) v = fmaxf(v, 0.f);
            if (ACT == 2) v = tanhf(v);
            C[(size_t)r * ldc + c] = v;
        }
    }
}

// ---------------- 3. att = tanh_out @ W_a2 + b_a2 (with mask) ------------
__global__ void att_dot(const float* __restrict__ t,
                        const float* __restrict__ w2,
                        const float* __restrict__ b2,
                        const unsigned char* __restrict__ masks,
                        float* __restrict__ att) {
    int r = blockIdx.x;
    int tid = threadIdx.x;
    float v = t[(size_t)r * ATT + tid] * w2[tid];
    v = wave_sum(v);
    __shared__ float arr[4];
    if ((tid & 63) == 0) arr[tid >> 6] = v;
    __syncthreads();
    if (tid == 0) {
        float s = arr[0] + arr[1] + arr[2] + arr[3] + b2[0];
        if (masks[r]) s = -INFINITY;
        att[r] = s;
    }
}

// ---------------- 4. softmax over L + attended sum -----------------------
__global__ void softmax_attend(const float* __restrict__ att,
                               const float* __restrict__ mm,
                               float* __restrict__ out) {
    int b = blockIdx.x;
    int tid = threadIdx.x;
    __shared__ float wsm[LL];
    __shared__ float arr[4];
    float v0 = att[b * LL + tid];
    float v1 = att[b * LL + 256 + tid];
    float m = fmaxf(v0, v1);
    m = wave_max(m);
    if ((tid & 63) == 0) arr[tid >> 6] = m;
    __syncthreads();
    float M = fmaxf(fmaxf(arr[0], arr[1]), fmaxf(arr[2], arr[3]));
    float e0 = expf(v0 - M), e1 = expf(v1 - M);
    wsm[tid] = e0; wsm[256 + tid] = e1;
    float s = wave_sum(e0 + e1);
    __syncthreads();
    if ((tid & 63) == 0) arr[tid >> 6] = s;
    __syncthreads();
    float S = arr[0] + arr[1] + arr[2] + arr[3];
    float inv = 1.0f / S;
    float acc0 = 0.f, acc1 = 0.f;
    const float* base = mm + (size_t)b * LL * HID;
    for (int l = 0; l < LL; l++) {
        float w = wsm[l];
        acc0 += base[(size_t)l * HID + tid] * w;
        acc1 += base[(size_t)l * HID + 256 + tid] * w;
    }
    out[b * HID + tid] = acc0 * inv;
    out[b * HID + 256 + tid] = acc1 * inv;
}

// ---------------- 5. history: embed+LN per token, masked average ---------
__global__ void hist_embed_avg(const int* __restrict__ ids,
                               const int* __restrict__ lens,
                               const float* __restrict__ we,
                               const float* __restrict__ pe,
                               const float* __restrict__ te,
                               const float* __restrict__ g,
                               const float* __restrict__ bta,
                               float* __restrict__ out) {
    int bs = blockIdx.x;   // 0..191
    int len = lens[bs];
    __shared__ float acc[EMB];
    int tid = threadIdx.x;
    for (int j = tid; j < EMB; j += 256) acc[j] = 0.f;
    __syncthreads();
    int wid = tid >> 6, lane = tid & 63;
    for (int h = wid; h < len; h += 4) {
        int id = ids[bs * HL + h];
        const float* wrow = we + (size_t)id * EMB;
        const float* prow = pe + (size_t)h * EMB;
        float x[12]; float s = 0.f, ss = 0.f;
#pragma unroll
        for (int k = 0; k < 12; k++) {
            int j = lane + k * 64;
            float v = wrow[j] + prow[j] + te[j];
            x[k] = v; s += v; ss += v * v;
        }
        s = wave_sum(s); ss = wave_sum(ss);
        float mu = s * (1.0f / EMB);
        float var = ss * (1.0f / EMB) - mu * mu;
        float rs = rsqrtf(var + LN_EPS);
#pragma unroll
        for (int k = 0; k < 12; k++) {
            int j = lane + k * 64;
            float y = g[j] * (x[k] - mu) * rs + bta[j];
            atomicAdd(&acc[j], y);
        }
    }
    __syncthreads();
    float invd = 1.0f / fmaxf((float)len, 1.0f);
    for (int j = tid; j < EMB; j += 256) out[(size_t)bs * EMB + j] = acc[j] * invd;
}

// ---------------- 6. sep = relu(sep_lin+contrib*(len>0)); L2-norm; mean --
__global__ void sep_fuse(const float* __restrict__ sep_lin,
                         const float* __restrict__ contrib,
                         const int* __restrict__ lens,
                         float* __restrict__ out) {
    int b = blockIdx.x;
    int tid = threadIdx.x;
    __shared__ float arr[4];
    float acc0 = 0.f, acc1 = 0.f;
    for (int s = 0; s < SS; s++) {
        int idx = b * SS + s;
        int len = lens[idx];
        float c0 = len > 0 ? contrib[(size_t)idx * HID + tid] : 0.f;
        float c1 = len > 0 ? contrib[(size_t)idx * HID + 256 + tid] : 0.f;
        float y0 = fmaxf(sep_lin[(size_t)idx * HID + tid] + c0, 0.f);
        float y1 = fmaxf(sep_lin[(size_t)idx * HID + 256 + tid] + c1, 0.f);
        float ssq = wave_sum(y0 * y0 + y1 * y1);
        if ((tid & 63) == 0) arr[tid >> 6] = ssq;
        __syncthreads();
        float tot = arr[0] + arr[1] + arr[2] + arr[3];
        float inv = 1.0f / fmaxf(sqrtf(tot), 1e-12f);
        acc0 += y0 * inv; acc1 += y1 * inv;
        __syncthreads();
    }
    out[b * HID + tid] = acc0 * (1.0f / SS);
    out[b * HID + 256 + tid] = acc1 * (1.0f / SS);
}

// ---------------- 7. final MLP: gelu(x@W1+b1)@W2+b2 ----------------------
__global__ void final_mlp(const float* __restrict__ sep_mean,
                          const float* __restrict__ attended,
                          const float* __restrict__ W1,
                          const float* __restrict__ b1,
                          const float* __restrict__ W2,
                          const float* __restrict__ b2,
                          float* __restrict__ out) {
    int b = blockIdx.x;
    int tid = threadIdx.x;
    __shared__ float x[2 * HID];
    __shared__ float h[HID];
    x[tid]       = sep_mean[b * HID + tid];
    x[tid + 256] = sep_mean[b * HID + 256 + tid];
    x[tid + 512] = attended[b * HID + tid];
    x[tid + 768] = attended[b * HID + 256 + tid];
    __syncthreads();
#pragma unroll
    for (int jj = 0; jj < 2; jj++) {
        int j = tid + jj * 256;
        float a = b1[j];
        for (int k = 0; k < 2 * HID; k++) a += x[k] * W1[(size_t)k * HID + j];
        h[j] = 0.5f * a * (1.0f + erff(a * 0.70710678118654752f));
    }
    __syncthreads();
    float p0 = 0.f, p1 = 0.f;
    for (int j = tid; j < HID; j += 256) {
        float hv = h[j];
        p0 += hv * W2[j * 2 + 0];
        p1 += hv * W2[j * 2 + 1];
    }
    p0 = wave_sum(p0); p1 = wave_sum(p1);
    __shared__ float r0[4], r1[4];
    if ((tid & 63) == 0) { r0[tid >> 6] = p0; r1[tid >> 6] = p1; }
    __syncthreads();
    if (tid == 0) {
        out[b * 2 + 0] = r0[0] + r0[1] + r0[2] + r0[3] + b2[0];
        out[b * 2 + 1] = r1[0] + r1[1] + r1[2] + r1[3] + b2[1];
    }
}

// ---------------- launch ----------------
extern "C" void kernel_launch(void* const* d_in, const int* in_sizes, int n_in,
                              void* d_out, int out_size, void* d_ws, size_t ws_size,
                              hipStream_t stream) {
    const float* sep_images   = (const float*)d_in[0];
    const float* img_pred     = (const float*)d_in[1];
    const int*   input_text   = (const int*)d_in[2];
    const int*   prev_hist    = (const int*)d_in[3];
    const int*   prev_hist_ln = (const int*)d_in[4];
    const unsigned char* masks = (const unsigned char*)d_in[5];
    const float* word_emb = (const float*)d_in[6];
    const float* pos_emb  = (const float*)d_in[7];
    const float* type_emb = (const float*)d_in[8];
    const float* ln_g = (const float*)d_in[9];
    const float* ln_b = (const float*)d_in[10];
    const float* W_sep = (const float*)d_in[11]; const float* b_sep = (const float*)d_in[12];
    const float* W_e2h = (const float*)d_in[13]; const float* b_e2h = (const float*)d_in[14];
    const float* W_hist = (const float*)d_in[15]; const float* b_hist = (const float*)d_in[16];
    const float* W_img = (const float*)d_in[17]; const float* b_img = (const float*)d_in[18];
    const float* W_mm = (const float*)d_in[19]; const float* b_mm = (const float*)d_in[20];
    const float* W_a1 = (const float*)d_in[21]; const float* b_a1 = (const float*)d_in[22];
    const float* W_a2 = (const float*)d_in[23]; const float* b_a2 = (const float*)d_in[24];
    const float* W_f1 = (const float*)d_in[25]; const float* b_f1 = (const float*)d_in[26];
    const float* W_f2 = (const float*)d_in[27]; const float* b_f2 = (const float*)d_in[28];

    float* ws = (float*)d_ws;
    size_t o = 0;
    float* reps       = ws + o; o += (size_t)BB * LL * EMB;   // 12.58M (reused as mm_reps)
    float* input_reps = ws + o; o += (size_t)BB * LL * HID;   // 8.39M
    float* tanh_out   = ws + o; o += (size_t)BB * LL * ATT;   // 4.19M
    float* att        = ws + o; o += (size_t)BB * LL;
    float* proj_img   = ws + o; o += (size_t)BB * HID;
    float* img_part   = ws + o; o += (size_t)BB * HID;
    float* attended   = ws + o; o += (size_t)BB * HID;
    float* hist_avg   = ws + o; o += (size_t)BB * SS * EMB;
    float* sep_lin    = ws + o; o += (size_t)BB * SS * HID;
    float* contrib    = ws + o; o += (size_t)BB * SS * HID;
    float* sep_mean   = ws + o; o += (size_t)BB * HID;
    float* mm_reps = reps;  // reps dead after e2h GEMM

    const int NROWS = BB * LL;  // 16384

    // utterance path
    embed_ln_text<<<NROWS, 256, 0, stream>>>(input_text, word_emb, pos_emb,
                                             type_emb, ln_g, ln_b, reps);
    // input_reps = relu(reps @ W_e2h + b)
    gemm64<1, false><<<dim3(HID / 64, NROWS / 64), 256, 0, stream>>>(
        reps, EMB, W_e2h, HID, b_e2h, nullptr, 1, input_reps, HID, NROWS, HID, EMB);
    // proj_img = relu(img_pred @ W_img + b)
    gemm64<1, false><<<dim3(HID / 64, 1), 256, 0, stream>>>(
        img_pred, IMG, W_img, HID, b_img, nullptr, 1, proj_img, HID, BB, HID, IMG);
    // img_part = proj_img @ W_mm[512:1024]
    gemm64<0, false><<<dim3(HID / 64, 1), 256, 0, stream>>>(
        proj_img, HID, W_mm + (size_t)HID * HID, HID, nullptr, nullptr, 1,
        img_part, HID, BB, HID, HID);
    // mm_reps = relu(input_reps @ W_mm[:512] + img_part[b] + b_mm)
    gemm64<1, true><<<dim3(HID / 64, NROWS / 64), 256, 0, stream>>>(
        input_reps, HID, W_mm, HID, b_mm, img_part, LL, mm_reps, HID, NROWS, HID, HID);
    // tanh_out = tanh(mm_reps @ W_a1 + b_a1)
    gemm64<2, false><<<dim3(ATT / 64, NROWS / 64), 256, 0, stream>>>(
        mm_reps, HID, W_a1, ATT, b_a1, nullptr, 1, tanh_out, ATT, NROWS, ATT, HID);
    // att scores + mask
    att_dot<<<NROWS, 256, 0, stream>>>(tanh_out, W_a2, b_a2, masks, att);
    // softmax + attended
    softmax_attend<<<BB, 256, 0, stream>>>(att, mm_reps, attended);

    // history/image path
    hist_embed_avg<<<BB * SS, 256, 0, stream>>>(prev_hist, prev_hist_ln, word_emb,
                                                pos_emb, type_emb, ln_g, ln_b, hist_avg);
    gemm64<0, false><<<dim3(HID / 64, (BB * SS + 63) / 64), 256, 0, stream>>>(
        sep_images, IMG, W_sep, HID, b_sep, nullptr, 1, sep_lin, HID, BB * SS, HID, IMG);
    gemm64<1, false><<<dim3(HID / 64, (BB * SS + 63) / 64), 256, 0, stream>>>(
        hist_avg, EMB, W_hist, HID, b_hist, nullptr, 1, contrib, HID, BB * SS, HID, EMB);
    sep_fuse<<<BB, 256, 0, stream>>>(sep_lin, contrib, prev_hist_ln, sep_mean);

    // final MLP -> d_out [32,2]
    final_mlp<<<BB, 256, 0, stream>>>(sep_mean, attended, W_f1, b_f1, W_f2, b_f2,
                                      (float*)d_out);
}

// Round 2
// 615.135 us; speedup vs baseline: 1.5121x; 1.5121x over previous
//
#include <hip/hip_runtime.h>
#include <hip/hip_bf16.h>
#include <math.h>

// Problem constants
#define VOCAB 30522
#define EMB 768
#define MAXPOS 512
#define HID 512
#define IMG 2048
#define ATT 256
#define BB 32      // batch
#define LL 512     // text length
#define SS 6       // images/history slots
#define HL 128     // history length
#define LN_EPS 1e-12f

typedef __bf16 bf16_t;
typedef __attribute__((ext_vector_type(8))) __bf16 bf16x8;
typedef __attribute__((ext_vector_type(4))) float f32x4;

// ---------------- reduction helpers ----------------
__device__ __forceinline__ float wave_sum(float v) {
    v += __shfl_xor(v, 1);  v += __shfl_xor(v, 2);  v += __shfl_xor(v, 4);
    v += __shfl_xor(v, 8);  v += __shfl_xor(v, 16); v += __shfl_xor(v, 32);
    return v;
}
__device__ __forceinline__ float wave_max(float v) {
    v = fmaxf(v, __shfl_xor(v, 1));  v = fmaxf(v, __shfl_xor(v, 2));
    v = fmaxf(v, __shfl_xor(v, 4));  v = fmaxf(v, __shfl_xor(v, 8));
    v = fmaxf(v, __shfl_xor(v, 16)); v = fmaxf(v, __shfl_xor(v, 32));
    return v;
}

// ---------------- 1. BERT embed + LayerNorm for text (bf16 out) ----------
__global__ void embed_ln_text(const int* __restrict__ ids,
                              const float* __restrict__ we,
                              const float* __restrict__ pe,
                              const float* __restrict__ te,
                              const float* __restrict__ g,
                              const float* __restrict__ bta,
                              bf16_t* __restrict__ out) {
    int r = blockIdx.x;
    int l = r & (LL - 1);
    int id = ids[r];
    const float* wrow = we + (size_t)id * EMB;
    const float* prow = pe + (size_t)l * EMB;
    int tid = threadIdx.x;
    float x0 = wrow[tid]       + prow[tid]       + te[tid];
    float x1 = wrow[tid + 256] + prow[tid + 256] + te[tid + 256];
    float x2 = wrow[tid + 512] + prow[tid + 512] + te[tid + 512];
    float s  = x0 + x1 + x2;
    float ss = x0 * x0 + x1 * x1 + x2 * x2;
    s = wave_sum(s); ss = wave_sum(ss);
    __shared__ float as_[4], ass_[4];
    int wid = tid >> 6, lane = tid & 63;
    if (lane == 0) { as_[wid] = s; ass_[wid] = ss; }
    __syncthreads();
    float tot  = as_[0] + as_[1] + as_[2] + as_[3];
    float tots = ass_[0] + ass_[1] + ass_[2] + ass_[3];
    float mu = tot * (1.0f / EMB);
    float var = tots * (1.0f / EMB) - mu * mu;
    float rs = rsqrtf(var + LN_EPS);
    bf16_t* orow = out + (size_t)r * EMB;
    orow[tid]       = (bf16_t)(g[tid]       * (x0 - mu) * rs + bta[tid]);
    orow[tid + 256] = (bf16_t)(g[tid + 256] * (x1 - mu) * rs + bta[tid + 256]);
    orow[tid + 512] = (bf16_t)(g[tid + 512] * (x2 - mu) * rs + bta[tid + 512]);
}

// ---------------- weight transpose + bf16 convert: [K][N] -> [N][K] ------
__global__ void conv_w(const float* __restrict__ in, bf16_t* __restrict__ out,
                       int K, int N) {
    int idx = blockIdx.x * 256 + threadIdx.x;
    if (idx >= K * N) return;
    int n = idx / K, k = idx - n * K;
    out[idx] = (bf16_t)in[(size_t)k * N + n];
}

// ---------------- MFMA bf16 GEMM: C = act(A@B^T + bias (+rowadd)) --------
// A: [M,K] bf16 row-major; Bt: [N,K] bf16 row-major (pre-transposed weights)
// 128x128 tile, BK=32, 4 waves (2x2), each wave 64x64 via 4x4 16x16x32 MFMA
template <int ACT, bool OBF16, bool ROWADD>
__global__ __launch_bounds__(256)
void mfma_gemm(const bf16_t* __restrict__ A, const bf16_t* __restrict__ Bt,
               const float* __restrict__ bias,
               const float* __restrict__ rowadd, int rowdiv,
               void* __restrict__ Cv, int M, int N, int K) {
    __shared__ __align__(16) bf16_t As[128][40];  // +16B pad: 2-way conflict (free)
    __shared__ __align__(16) bf16_t Bs[128][40];
    int tid = threadIdx.x;
    int lane = tid & 63, wid = tid >> 6;
    int wr = wid >> 1, wc = wid & 1;
    int row0 = blockIdx.y * 128, col0 = blockIdx.x * 128;

    int r2 = tid >> 2;            // 0..63 staging row
    int kc = (tid & 3) * 8;       // 0,8,16,24 staging k-col

    f32x4 acc[4][4] = {};

    const bf16_t* Ab = A + (size_t)(row0 + r2) * K + kc;
    const bf16_t* Bb = Bt + (size_t)(col0 + r2) * K + kc;
    uint4 ra0, ra1, rb0, rb1;
    ra0 = *(const uint4*)(Ab);
    ra1 = *(const uint4*)(Ab + (size_t)64 * K);
    rb0 = *(const uint4*)(Bb);
    rb1 = *(const uint4*)(Bb + (size_t)64 * K);

    int lrow = lane & 15, k0 = (lane >> 4) * 8;

    for (int kb = 0; kb < K; kb += 32) {
        __syncthreads();
        *(uint4*)&As[r2][kc] = ra0;
        *(uint4*)&As[r2 + 64][kc] = ra1;
        *(uint4*)&Bs[r2][kc] = rb0;
        *(uint4*)&Bs[r2 + 64][kc] = rb1;
        if (kb + 32 < K) {
            ra0 = *(const uint4*)(Ab + kb + 32);
            ra1 = *(const uint4*)(Ab + (size_t)64 * K + kb + 32);
            rb0 = *(const uint4*)(Bb + kb + 32);
            rb1 = *(const uint4*)(Bb + (size_t)64 * K + kb + 32);
        }
        __syncthreads();
        bf16x8 af[4], bfr[4];
#pragma unroll
        for (int mi = 0; mi < 4; mi++)
            af[mi] = *(const bf16x8*)&As[wr * 64 + mi * 16 + lrow][k0];
#pragma unroll
        for (int ni = 0; ni < 4; ni++)
            bfr[ni] = *(const bf16x8*)&Bs[wc * 64 + ni * 16 + lrow][k0];
#pragma unroll
        for (int mi = 0; mi < 4; mi++)
#pragma unroll
            for (int ni = 0; ni < 4; ni++)
                acc[mi][ni] = __builtin_amdgcn_mfma_f32_16x16x32_bf16(
                    af[mi], bfr[ni], acc[mi][ni], 0, 0, 0);
    }

    float* Cf = (float*)Cv;
    bf16_t* Cb = (bf16_t*)Cv;
    int rg = (lane >> 4) * 4;
#pragma unroll
    for (int mi = 0; mi < 4; mi++) {
#pragma unroll
        for (int ni = 0; ni < 4; ni++) {
            int col = col0 + wc * 64 + ni * 16 + lrow;
#pragma unroll
            for (int r = 0; r < 4; r++) {
                int row = row0 + wr * 64 + mi * 16 + rg + r;
                float v = acc[mi][ni][r] + bias[col];
                if (ROWADD) v += rowadd[(size_t)(row / rowdiv) * N + col];
                if (ACT == 1) v = fmaxf(v, 0.f);
                if (ACT == 2) v = tanhf(v);
                if (OBF16) Cb[(size_t)row * N + col] = (bf16_t)v;
                else       Cf[(size_t)row * N + col] = v;
            }
        }
    }
}

// ---------------- 2. generic fp32 GEMM (small matrices only) -------------
template <int ACT, bool HAS_ROWADD>
__global__ void gemm64(const float* __restrict__ A, int lda,
                       const float* __restrict__ B, int ldb,
                       const float* __restrict__ bias,
                       const float* __restrict__ rowadd, int rowdiv,
                       float* __restrict__ C, int ldc,
                       int M, int N, int K) {
    __shared__ float As[16][64];
    __shared__ float Bs[16][64];
    int tid = threadIdx.x;
    int tx = tid & 15, ty = tid >> 4;
    int col0 = blockIdx.x * 64;
    int row0 = blockIdx.y * 64;

    float acc[4][4] = {};
    int ar = tid >> 2;
    int ak = (tid & 3) << 2;
    int bk = tid >> 4;
    int bn = (tid & 15) << 2;

    for (int k0 = 0; k0 < K; k0 += 16) {
        float4 av;
        int arow = row0 + ar;
        if (arow < M) av = *(const float4*)(A + (size_t)arow * lda + k0 + ak);
        else av = make_float4(0.f, 0.f, 0.f, 0.f);
        As[ak + 0][ar] = av.x; As[ak + 1][ar] = av.y;
        As[ak + 2][ar] = av.z; As[ak + 3][ar] = av.w;
        *(float4*)&Bs[bk][bn] =
            *(const float4*)(B + (size_t)(k0 + bk) * ldb + col0 + bn);
        __syncthreads();
#pragma unroll
        for (int kk = 0; kk < 16; kk++) {
            float a0 = As[kk][ty * 4 + 0], a1 = As[kk][ty * 4 + 1];
            float a2 = As[kk][ty * 4 + 2], a3 = As[kk][ty * 4 + 3];
            float b0 = Bs[kk][tx * 4 + 0], b1 = Bs[kk][tx * 4 + 1];
            float b2 = Bs[kk][tx * 4 + 2], b3 = Bs[kk][tx * 4 + 3];
            acc[0][0] += a0 * b0; acc[0][1] += a0 * b1; acc[0][2] += a0 * b2; acc[0][3] += a0 * b3;
            acc[1][0] += a1 * b0; acc[1][1] += a1 * b1; acc[1][2] += a1 * b2; acc[1][3] += a1 * b3;
            acc[2][0] += a2 * b0; acc[2][1] += a2 * b1; acc[2][2] += a2 * b2; acc[2][3] += a2 * b3;
            acc[3][0] += a3 * b0; acc[3][1] += a3 * b1; acc[3][2] += a3 * b2; acc[3][3] += a3 * b3;
        }
        __syncthreads();
    }
#pragma unroll
    for (int i = 0; i < 4; i++) {
        int r = row0 + ty * 4 + i;
        if (r >= M) break;
#pragma unroll
        for (int j = 0; j < 4; j++) {
            int c = col0 + tx * 4 + j;
            float v = acc[i][j];
            if (bias) v += bias[c];
            if (HAS_ROWADD) v += rowadd[(size_t)(r / rowdiv) * N + c];
            if (ACT == 1) v = fmaxf(v, 0.f);
            if (ACT == 2) v = tanhf(v);
            C[(size_t)r * ldc + c] = v;
        }
    }
}

// ---------------- 3. att = tanh_out @ W_a2 + b_a2 (with mask) ------------
__global__ void att_dot(const float* __restrict__ t,
                        const float* __restrict__ w2,
                        const float* __restrict__ b2,
                        const unsigned char* __restrict__ masks,
                        float* __restrict__ att) {
    int r = blockIdx.x;
    int tid = threadIdx.x;
    float v = t[(size_t)r * ATT + tid] * w2[tid];
    v = wave_sum(v);
    __shared__ float arr[4];
    if ((tid & 63) == 0) arr[tid >> 6] = v;
    __syncthreads();
    if (tid == 0) {
        float s = arr[0] + arr[1] + arr[2] + arr[3] + b2[0];
        if (masks[r]) s = -INFINITY;
        att[r] = s;
    }
}

// ---------------- 4. softmax over L + attended sum (bf16 mm) -------------
__global__ void softmax_attend(const float* __restrict__ att,
                               const bf16_t* __restrict__ mm,
                               float* __restrict__ out) {
    int b = blockIdx.x;
    int tid = threadIdx.x;
    __shared__ float wsm[LL];
    __shared__ float arr[4];
    float v0 = att[b * LL + tid];
    float v1 = att[b * LL + 256 + tid];
    float m = fmaxf(v0, v1);
    m = wave_max(m);
    if ((tid & 63) == 0) arr[tid >> 6] = m;
    __syncthreads();
    float M = fmaxf(fmaxf(arr[0], arr[1]), fmaxf(arr[2], arr[3]));
    float e0 = expf(v0 - M), e1 = expf(v1 - M);
    wsm[tid] = e0; wsm[256 + tid] = e1;
    float s = wave_sum(e0 + e1);
    __syncthreads();
    if ((tid & 63) == 0) arr[tid >> 6] = s;
    __syncthreads();
    float S = arr[0] + arr[1] + arr[2] + arr[3];
    float inv = 1.0f / S;
    float acc0 = 0.f, acc1 = 0.f;
    const bf16_t* base = mm + (size_t)b * LL * HID;
    for (int l = 0; l < LL; l++) {
        float w = wsm[l];
        acc0 += (float)base[(size_t)l * HID + tid] * w;
        acc1 += (float)base[(size_t)l * HID + 256 + tid] * w;
    }
    out[b * HID + tid] = acc0 * inv;
    out[b * HID + 256 + tid] = acc1 * inv;
}

// ---------------- 5. history: embed+LN per token, masked average ---------
__global__ void hist_embed_avg(const int* __restrict__ ids,
                               const int* __restrict__ lens,
                               const float* __restrict__ we,
                               const float* __restrict__ pe,
                               const float* __restrict__ te,
                               const float* __restrict__ g,
                               const float* __restrict__ bta,
                               float* __restrict__ out) {
    int bs = blockIdx.x;   // 0..191
    int len = lens[bs];
    __shared__ float acc[EMB];
    int tid = threadIdx.x;
    for (int j = tid; j < EMB; j += 256) acc[j] = 0.f;
    __syncthreads();
    int wid = tid >> 6, lane = tid & 63;
    for (int h = wid; h < len; h += 4) {
        int id = ids[bs * HL + h];
        const float* wrow = we + (size_t)id * EMB;
        const float* prow = pe + (size_t)h * EMB;
        float x[12]; float s = 0.f, ss = 0.f;
#pragma unroll
        for (int k = 0; k < 12; k++) {
            int j = lane + k * 64;
            float v = wrow[j] + prow[j] + te[j];
            x[k] = v; s += v; ss += v * v;
        }
        s = wave_sum(s); ss = wave_sum(ss);
        float mu = s * (1.0f / EMB);
        float var = ss * (1.0f / EMB) - mu * mu;
        float rs = rsqrtf(var + LN_EPS);
#pragma unroll
        for (int k = 0; k < 12; k++) {
            int j = lane + k * 64;
            float y = g[j] * (x[k] - mu) * rs + bta[j];
            atomicAdd(&acc[j], y);
        }
    }
    __syncthreads();
    float invd = 1.0f / fmaxf((float)len, 1.0f);
    for (int j = tid; j < EMB; j += 256) out[(size_t)bs * EMB + j] = acc[j] * invd;
}

// ---------------- 6. sep = relu(sep_lin+contrib*(len>0)); L2-norm; mean --
__global__ void sep_fuse(const float* __restrict__ sep_lin,
                         const float* __restrict__ contrib,
                         const int* __restrict__ lens,
                         float* __restrict__ out) {
    int b = blockIdx.x;
    int tid = threadIdx.x;
    __shared__ float arr[4];
    float acc0 = 0.f, acc1 = 0.f;
    for (int s = 0; s < SS; s++) {
        int idx = b * SS + s;
        int len = lens[idx];
        float c0 = len > 0 ? contrib[(size_t)idx * HID + tid] : 0.f;
        float c1 = len > 0 ? contrib[(size_t)idx * HID + 256 + tid] : 0.f;
        float y0 = fmaxf(sep_lin[(size_t)idx * HID + tid] + c0, 0.f);
        float y1 = fmaxf(sep_lin[(size_t)idx * HID + 256 + tid] + c1, 0.f);
        float ssq = wave_sum(y0 * y0 + y1 * y1);
        if ((tid & 63) == 0) arr[tid >> 6] = ssq;
        __syncthreads();
        float tot = arr[0] + arr[1] + arr[2] + arr[3];
        float inv = 1.0f / fmaxf(sqrtf(tot), 1e-12f);
        acc0 += y0 * inv; acc1 += y1 * inv;
        __syncthreads();
    }
    out[b * HID + tid] = acc0 * (1.0f / SS);
    out[b * HID + 256 + tid] = acc1 * (1.0f / SS);
}

// ---------------- 7. final MLP: gelu(x@W1+b1)@W2+b2 ----------------------
__global__ void final_mlp(const float* __restrict__ sep_mean,
                          const float* __restrict__ attended,
                          const float* __restrict__ W1,
                          const float* __restrict__ b1,
                          const float* __restrict__ W2,
                          const float* __restrict__ b2,
                          float* __restrict__ out) {
    int b = blockIdx.x;
    int tid = threadIdx.x;
    __shared__ float x[2 * HID];
    __shared__ float h[HID];
    x[tid]       = sep_mean[b * HID + tid];
    x[tid + 256] = sep_mean[b * HID + 256 + tid];
    x[tid + 512] = attended[b * HID + tid];
    x[tid + 768] = attended[b * HID + 256 + tid];
    __syncthreads();
#pragma unroll
    for (int jj = 0; jj < 2; jj++) {
        int j = tid + jj * 256;
        float a = b1[j];
        for (int k = 0; k < 2 * HID; k++) a += x[k] * W1[(size_t)k * HID + j];
        h[j] = 0.5f * a * (1.0f + erff(a * 0.70710678118654752f));
    }
    __syncthreads();
    float p0 = 0.f, p1 = 0.f;
    for (int j = tid; j < HID; j += 256) {
        float hv = h[j];
        p0 += hv * W2[j * 2 + 0];
        p1 += hv * W2[j * 2 + 1];
    }
    p0 = wave_sum(p0); p1 = wave_sum(p1);
    __shared__ float r0[4], r1[4];
    if ((tid & 63) == 0) { r0[tid >> 6] = p0; r1[tid >> 6] = p1; }
    __syncthreads();
    if (tid == 0) {
        out[b * 2 + 0] = r0[0] + r0[1] + r0[2] + r0[3] + b2[0];
        out[b * 2 + 1] = r1[0] + r1[1] + r1[2] + r1[3] + b2[1];
    }
}

// ---------------- launch ----------------
extern "C" void kernel_launch(void* const* d_in, const int* in_sizes, int n_in,
                              void* d_out, int out_size, void* d_ws, size_t ws_size,
                              hipStream_t stream) {
    const float* sep_images   = (const float*)d_in[0];
    const float* img_pred     = (const float*)d_in[1];
    const int*   input_text   = (const int*)d_in[2];
    const int*   prev_hist    = (const int*)d_in[3];
    const int*   prev_hist_ln = (const int*)d_in[4];
    const unsigned char* masks = (const unsigned char*)d_in[5];
    const float* word_emb = (const float*)d_in[6];
    const float* pos_emb  = (const float*)d_in[7];
    const float* type_emb = (const float*)d_in[8];
    const float* ln_g = (const float*)d_in[9];
    const float* ln_b = (const float*)d_in[10];
    const float* W_sep = (const float*)d_in[11]; const float* b_sep = (const float*)d_in[12];
    const float* W_e2h = (const float*)d_in[13]; const float* b_e2h = (const float*)d_in[14];
    const float* W_hist = (const float*)d_in[15]; const float* b_hist = (const float*)d_in[16];
    const float* W_img = (const float*)d_in[17]; const float* b_img = (const float*)d_in[18];
    const float* W_mm = (const float*)d_in[19]; const float* b_mm = (const float*)d_in[20];
    const float* W_a1 = (const float*)d_in[21]; const float* b_a1 = (const float*)d_in[22];
    const float* W_a2 = (const float*)d_in[23]; const float* b_a2 = (const float*)d_in[24];
    const float* W_f1 = (const float*)d_in[25]; const float* b_f1 = (const float*)d_in[26];
    const float* W_f2 = (const float*)d_in[27]; const float* b_f2 = (const float*)d_in[28];

    const int NROWS = BB * LL;  // 16384

    char* ws = (char*)d_ws;
    size_t o = 0;
    auto alloc = [&](size_t bytes) { void* p = ws + o; o += (bytes + 255) & ~(size_t)255; return p; };

    bf16_t* reps_bf     = (bf16_t*)alloc((size_t)NROWS * EMB * 2);
    bf16_t* input_reps  = (bf16_t*)alloc((size_t)NROWS * HID * 2);
    bf16_t* mm_reps     = (bf16_t*)alloc((size_t)NROWS * HID * 2);
    float*  tanh_out    = (float*)alloc((size_t)NROWS * ATT * 4);
    float*  att         = (float*)alloc((size_t)NROWS * 4);
    float*  proj_img    = (float*)alloc((size_t)BB * HID * 4);
    float*  img_part    = (float*)alloc((size_t)BB * HID * 4);
    float*  attended    = (float*)alloc((size_t)BB * HID * 4);
    float*  hist_avg    = (float*)alloc((size_t)BB * SS * EMB * 4);
    float*  sep_lin     = (float*)alloc((size_t)BB * SS * HID * 4);
    float*  contrib     = (float*)alloc((size_t)BB * SS * HID * 4);
    float*  sep_mean    = (float*)alloc((size_t)BB * HID * 4);
    bf16_t* Wt_e2h      = (bf16_t*)alloc((size_t)EMB * HID * 2);
    bf16_t* Wt_mm       = (bf16_t*)alloc((size_t)HID * HID * 2);
    bf16_t* Wt_a1       = (bf16_t*)alloc((size_t)HID * ATT * 2);

    // weight transpose+convert
    conv_w<<<(EMB * HID + 255) / 256, 256, 0, stream>>>(W_e2h, Wt_e2h, EMB, HID);
    conv_w<<<(HID * HID + 255) / 256, 256, 0, stream>>>(W_mm, Wt_mm, HID, HID);
    conv_w<<<(HID * ATT + 255) / 256, 256, 0, stream>>>(W_a1, Wt_a1, HID, ATT);

    // utterance path
    embed_ln_text<<<NROWS, 256, 0, stream>>>(input_text, word_emb, pos_emb,
                                             type_emb, ln_g, ln_b, reps_bf);
    // proj_img = relu(img_pred @ W_img + b)   [32,512]
    gemm64<1, false><<<dim3(HID / 64, 1), 256, 0, stream>>>(
        img_pred, IMG, W_img, HID, b_img, nullptr, 1, proj_img, HID, BB, HID, IMG);
    // img_part = proj_img @ W_mm[512:1024]    [32,512]
    gemm64<0, false><<<dim3(HID / 64, 1), 256, 0, stream>>>(
        proj_img, HID, W_mm + (size_t)HID * HID, HID, nullptr, nullptr, 1,
        img_part, HID, BB, HID, HID);

    // input_reps = relu(reps @ W_e2h + b)  (MFMA, bf16 out)
    mfma_gemm<1, true, false><<<dim3(HID / 128, NROWS / 128), 256, 0, stream>>>(
        reps_bf, Wt_e2h, b_e2h, nullptr, 1, input_reps, NROWS, HID, EMB);
    // mm_reps = relu(input_reps @ W_mm[:512] + img_part[b] + b_mm)  (MFMA, bf16 out)
    mfma_gemm<1, true, true><<<dim3(HID / 128, NROWS / 128), 256, 0, stream>>>(
        input_reps, Wt_mm, b_mm, img_part, LL, mm_reps, NROWS, HID, HID);
    // tanh_out = tanh(mm_reps @ W_a1 + b_a1)  (MFMA, f32 out)
    mfma_gemm<2, false, false><<<dim3(ATT / 128, NROWS / 128), 256, 0, stream>>>(
        mm_reps, Wt_a1, b_a1, nullptr, 1, tanh_out, NROWS, ATT, HID);

    // att scores + mask
    att_dot<<<NROWS, 256, 0, stream>>>(tanh_out, W_a2, b_a2, masks, att);
    // softmax + attended
    softmax_attend<<<BB, 256, 0, stream>>>(att, mm_reps, attended);

    // history/image path
    hist_embed_avg<<<BB * SS, 256, 0, stream>>>(prev_hist, prev_hist_ln, word_emb,
                                                pos_emb, type_emb, ln_g, ln_b, hist_avg);
    gemm64<0, false><<<dim3(HID / 64, (BB * SS + 63) / 64), 256, 0, stream>>>(
        sep_images, IMG, W_sep, HID, b_sep, nullptr, 1, sep_lin, HID, BB * SS, HID, IMG);
    gemm64<1, false><<<dim3(HID / 64, (BB * SS + 63) / 64), 256, 0, stream>>>(
        hist_avg, EMB, W_hist, HID, b_hist, nullptr, 1, contrib, HID, BB * SS, HID, EMB);
    sep_fuse<<<BB, 256, 0, stream>>>(sep_lin, contrib, prev_hist_ln, sep_mean);

    // final MLP -> d_out [32,2]
    final_mlp<<<BB, 256, 0, stream>>>(sep_mean, attended, W_f1, b_f1, W_f2, b_f2,
                                      (float*)d_out);
}

// Round 3
// 482.249 us; speedup vs baseline: 1.9288x; 1.2756x over previous
//
#include <hip/hip_runtime.h>
#include <hip/hip_bf16.h>
#include <math.h>

// Problem constants
#define VOCAB 30522
#define EMB 768
#define MAXPOS 512
#define HID 512
#define IMG 2048
#define ATT 256
#define BB 32      // batch
#define LL 512     // text length
#define SS 6       // images/history slots
#define HL 128     // history length
#define LN_EPS 1e-12f

typedef __bf16 bf16_t;
typedef __attribute__((ext_vector_type(8))) __bf16 bf16x8;
typedef __attribute__((ext_vector_type(4))) float f32x4;

// ---------------- reduction helpers ----------------
__device__ __forceinline__ float wave_sum(float v) {
    v += __shfl_xor(v, 1);  v += __shfl_xor(v, 2);  v += __shfl_xor(v, 4);
    v += __shfl_xor(v, 8);  v += __shfl_xor(v, 16); v += __shfl_xor(v, 32);
    return v;
}
__device__ __forceinline__ float wave_max(float v) {
    v = fmaxf(v, __shfl_xor(v, 1));  v = fmaxf(v, __shfl_xor(v, 2));
    v = fmaxf(v, __shfl_xor(v, 4));  v = fmaxf(v, __shfl_xor(v, 8));
    v = fmaxf(v, __shfl_xor(v, 16)); v = fmaxf(v, __shfl_xor(v, 32));
    return v;
}

// ---------------- 1. BERT embed + LayerNorm for text (bf16 out) ----------
__global__ void embed_ln_text(const int* __restrict__ ids,
                              const float* __restrict__ we,
                              const float* __restrict__ pe,
                              const float* __restrict__ te,
                              const float* __restrict__ g,
                              const float* __restrict__ bta,
                              bf16_t* __restrict__ out) {
    int r = blockIdx.x;
    int l = r & (LL - 1);
    int id = ids[r];
    const float* wrow = we + (size_t)id * EMB;
    const float* prow = pe + (size_t)l * EMB;
    int tid = threadIdx.x;
    float x0 = wrow[tid]       + prow[tid]       + te[tid];
    float x1 = wrow[tid + 256] + prow[tid + 256] + te[tid + 256];
    float x2 = wrow[tid + 512] + prow[tid + 512] + te[tid + 512];
    float s  = x0 + x1 + x2;
    float ss = x0 * x0 + x1 * x1 + x2 * x2;
    s = wave_sum(s); ss = wave_sum(ss);
    __shared__ float as_[4], ass_[4];
    int wid = tid >> 6, lane = tid & 63;
    if (lane == 0) { as_[wid] = s; ass_[wid] = ss; }
    __syncthreads();
    float tot  = as_[0] + as_[1] + as_[2] + as_[3];
    float tots = ass_[0] + ass_[1] + ass_[2] + ass_[3];
    float mu = tot * (1.0f / EMB);
    float var = tots * (1.0f / EMB) - mu * mu;
    float rs = rsqrtf(var + LN_EPS);
    bf16_t* orow = out + (size_t)r * EMB;
    orow[tid]       = (bf16_t)(g[tid]       * (x0 - mu) * rs + bta[tid]);
    orow[tid + 256] = (bf16_t)(g[tid + 256] * (x1 - mu) * rs + bta[tid + 256]);
    orow[tid + 512] = (bf16_t)(g[tid + 512] * (x2 - mu) * rs + bta[tid + 512]);
}

// ---------------- weight transpose + bf16 convert: [K][N] -> [N][K] ------
__global__ void conv_w(const float* __restrict__ in, bf16_t* __restrict__ out,
                       int K, int N) {
    int idx = blockIdx.x * 256 + threadIdx.x;
    if (idx >= K * N) return;
    int n = idx / K, k = idx - n * K;
    out[idx] = (bf16_t)in[(size_t)k * N + n];
}

// ---------------- MFMA bf16 GEMM: C = act(A@B^T + bias (+rowadd)) --------
// A: [M,K] bf16 row-major; Bt: [N,K] bf16 row-major (pre-transposed weights)
// 128x128 tile, BK=32, 4 waves (2x2), each wave 64x64 via 4x4 16x16x32 MFMA
template <int ACT, bool OBF16, bool ROWADD>
__global__ __launch_bounds__(256)
void mfma_gemm(const bf16_t* __restrict__ A, const bf16_t* __restrict__ Bt,
               const float* __restrict__ bias,
               const float* __restrict__ rowadd, int rowdiv,
               void* __restrict__ Cv, int M, int N, int K) {
    __shared__ __align__(16) bf16_t As[128][40];  // +16B pad: 2-way conflict (free)
    __shared__ __align__(16) bf16_t Bs[128][40];
    int tid = threadIdx.x;
    int lane = tid & 63, wid = tid >> 6;
    int wr = wid >> 1, wc = wid & 1;
    int row0 = blockIdx.y * 128, col0 = blockIdx.x * 128;

    int r2 = tid >> 2;            // 0..63 staging row
    int kc = (tid & 3) * 8;       // 0,8,16,24 staging k-col

    f32x4 acc[4][4] = {};

    const bf16_t* Ab = A + (size_t)(row0 + r2) * K + kc;
    const bf16_t* Bb = Bt + (size_t)(col0 + r2) * K + kc;
    uint4 ra0, ra1, rb0, rb1;
    ra0 = *(const uint4*)(Ab);
    ra1 = *(const uint4*)(Ab + (size_t)64 * K);
    rb0 = *(const uint4*)(Bb);
    rb1 = *(const uint4*)(Bb + (size_t)64 * K);

    int lrow = lane & 15, k0 = (lane >> 4) * 8;

    for (int kb = 0; kb < K; kb += 32) {
        __syncthreads();
        *(uint4*)&As[r2][kc] = ra0;
        *(uint4*)&As[r2 + 64][kc] = ra1;
        *(uint4*)&Bs[r2][kc] = rb0;
        *(uint4*)&Bs[r2 + 64][kc] = rb1;
        if (kb + 32 < K) {
            ra0 = *(const uint4*)(Ab + kb + 32);
            ra1 = *(const uint4*)(Ab + (size_t)64 * K + kb + 32);
            rb0 = *(const uint4*)(Bb + kb + 32);
            rb1 = *(const uint4*)(Bb + (size_t)64 * K + kb + 32);
        }
        __syncthreads();
        bf16x8 af[4], bfr[4];
#pragma unroll
        for (int mi = 0; mi < 4; mi++)
            af[mi] = *(const bf16x8*)&As[wr * 64 + mi * 16 + lrow][k0];
#pragma unroll
        for (int ni = 0; ni < 4; ni++)
            bfr[ni] = *(const bf16x8*)&Bs[wc * 64 + ni * 16 + lrow][k0];
#pragma unroll
        for (int mi = 0; mi < 4; mi++)
#pragma unroll
            for (int ni = 0; ni < 4; ni++)
                acc[mi][ni] = __builtin_amdgcn_mfma_f32_16x16x32_bf16(
                    af[mi], bfr[ni], acc[mi][ni], 0, 0, 0);
    }

    float* Cf = (float*)Cv;
    bf16_t* Cb = (bf16_t*)Cv;
    int rg = (lane >> 4) * 4;
#pragma unroll
    for (int mi = 0; mi < 4; mi++) {
#pragma unroll
        for (int ni = 0; ni < 4; ni++) {
            int col = col0 + wc * 64 + ni * 16 + lrow;
#pragma unroll
            for (int r = 0; r < 4; r++) {
                int row = row0 + wr * 64 + mi * 16 + rg + r;
                float v = acc[mi][ni][r] + bias[col];
                if (ROWADD) v += rowadd[(size_t)(row / rowdiv) * N + col];
                if (ACT == 1) v = fmaxf(v, 0.f);
                if (ACT == 2) v = tanhf(v);
                if (OBF16) Cb[(size_t)row * N + col] = (bf16_t)v;
                else       Cf[(size_t)row * N + col] = v;
            }
        }
    }
}

// ---------------- split-K thin GEMM for tiny-M fp32 matmuls --------------
// part[ks][m][n] = sum_{k in 256-chunk ks} A[m][k] * B[k][n]
// grid (N/256, M/16, K/256), block 256. Tile: 16m x 256n x 256k.
__global__ __launch_bounds__(256)
void thin_gemm_part(const float* __restrict__ A, int lda,
                    const float* __restrict__ B, int ldb,
                    float* __restrict__ part, int M, int N) {
    __shared__ float As[16][256];
    int tid = threadIdx.x;
    int n0 = blockIdx.x * 256, m0 = blockIdx.y * 16, k0 = blockIdx.z * 256;
#pragma unroll
    for (int i = 0; i < 4; i++) {
        int lin = (i * 256 + tid) * 4;
        int m = lin >> 8, k = lin & 255;
        *(float4*)&As[m][k] = *(const float4*)(A + (size_t)(m0 + m) * lda + k0 + k);
    }
    __syncthreads();
    int nq = tid & 63, mg = tid >> 6;  // thread owns n0+nq*4..+3, m0+mg*4..+3
    const float* Bp = B + (size_t)k0 * ldb + n0 + nq * 4;
    float4 acc[4] = {};
#pragma unroll 2
    for (int k = 0; k < 256; k++) {
        float4 b = *(const float4*)(Bp + (size_t)k * ldb);
#pragma unroll
        for (int mi = 0; mi < 4; mi++) {
            float a = As[mg * 4 + mi][k];
            acc[mi].x += a * b.x; acc[mi].y += a * b.y;
            acc[mi].z += a * b.z; acc[mi].w += a * b.w;
        }
    }
    size_t MN = (size_t)M * N;
#pragma unroll
    for (int mi = 0; mi < 4; mi++)
        *(float4*)(part + (size_t)blockIdx.z * MN +
                   (size_t)(m0 + mg * 4 + mi) * N + n0 + nq * 4) = acc[mi];
}

// out[m][n] = act(sum_ks part[ks][m][n] + bias[n]);  grid: M*N/1024
template <int ACT>
__global__ void thin_reduce(const float* __restrict__ part,
                            const float* __restrict__ bias,
                            float* __restrict__ out, int N, int KS, size_t MN) {
    int idx4 = (blockIdx.x * 256 + threadIdx.x) * 4;
    int n = idx4 & (N - 1);  // N is power of two (512)
    float4 v = {};
    if (bias) v = *(const float4*)(bias + n);
    for (int ks = 0; ks < KS; ks++) {
        float4 p = *(const float4*)(part + (size_t)ks * MN + idx4);
        v.x += p.x; v.y += p.y; v.z += p.z; v.w += p.w;
    }
    if (ACT == 1) {
        v.x = fmaxf(v.x, 0.f); v.y = fmaxf(v.y, 0.f);
        v.z = fmaxf(v.z, 0.f); v.w = fmaxf(v.w, 0.f);
    }
    *(float4*)(out + idx4) = v;
}

// ---------------- 3. att = tanh_out @ W_a2 + b_a2 (with mask) ------------
__global__ void att_dot(const float* __restrict__ t,
                        const float* __restrict__ w2,
                        const float* __restrict__ b2,
                        const unsigned char* __restrict__ masks,
                        float* __restrict__ att) {
    int r = blockIdx.x;
    int tid = threadIdx.x;
    float v = t[(size_t)r * ATT + tid] * w2[tid];
    v = wave_sum(v);
    __shared__ float arr[4];
    if ((tid & 63) == 0) arr[tid >> 6] = v;
    __syncthreads();
    if (tid == 0) {
        float s = arr[0] + arr[1] + arr[2] + arr[3] + b2[0];
        if (masks[r]) s = -INFINITY;
        att[r] = s;
    }
}

// ---------------- 4. softmax over L + attended sum (bf16 mm) -------------
__global__ void softmax_attend(const float* __restrict__ att,
                               const bf16_t* __restrict__ mm,
                               float* __restrict__ out) {
    int b = blockIdx.x;
    int tid = threadIdx.x;
    __shared__ float wsm[LL];
    __shared__ float arr[4];
    float v0 = att[b * LL + tid];
    float v1 = att[b * LL + 256 + tid];
    float m = fmaxf(v0, v1);
    m = wave_max(m);
    if ((tid & 63) == 0) arr[tid >> 6] = m;
    __syncthreads();
    float M = fmaxf(fmaxf(arr[0], arr[1]), fmaxf(arr[2], arr[3]));
    float e0 = expf(v0 - M), e1 = expf(v1 - M);
    wsm[tid] = e0; wsm[256 + tid] = e1;
    float s = wave_sum(e0 + e1);
    __syncthreads();
    if ((tid & 63) == 0) arr[tid >> 6] = s;
    __syncthreads();
    float S = arr[0] + arr[1] + arr[2] + arr[3];
    float inv = 1.0f / S;
    float acc0 = 0.f, acc1 = 0.f;
    const bf16_t* base = mm + (size_t)b * LL * HID;
    for (int l = 0; l < LL; l++) {
        float w = wsm[l];
        acc0 += (float)base[(size_t)l * HID + tid] * w;
        acc1 += (float)base[(size_t)l * HID + 256 + tid] * w;
    }
    out[b * HID + tid] = acc0 * inv;
    out[b * HID + 256 + tid] = acc1 * inv;
}

// ---------------- 5. history: embed+LN per token, masked average ---------
__global__ void hist_embed_avg(const int* __restrict__ ids,
                               const int* __restrict__ lens,
                               const float* __restrict__ we,
                               const float* __restrict__ pe,
                               const float* __restrict__ te,
                               const float* __restrict__ g,
                               const float* __restrict__ bta,
                               float* __restrict__ out) {
    int bs = blockIdx.x;   // 0..191
    int len = lens[bs];
    __shared__ float acc[EMB];
    int tid = threadIdx.x;
    for (int j = tid; j < EMB; j += 256) acc[j] = 0.f;
    __syncthreads();
    int wid = tid >> 6, lane = tid & 63;
    for (int h = wid; h < len; h += 4) {
        int id = ids[bs * HL + h];
        const float* wrow = we + (size_t)id * EMB;
        const float* prow = pe + (size_t)h * EMB;
        float x[12]; float s = 0.f, ss = 0.f;
#pragma unroll
        for (int k = 0; k < 12; k++) {
            int j = lane + k * 64;
            float v = wrow[j] + prow[j] + te[j];
            x[k] = v; s += v; ss += v * v;
        }
        s = wave_sum(s); ss = wave_sum(ss);
        float mu = s * (1.0f / EMB);
        float var = ss * (1.0f / EMB) - mu * mu;
        float rs = rsqrtf(var + LN_EPS);
#pragma unroll
        for (int k = 0; k < 12; k++) {
            int j = lane + k * 64;
            float y = g[j] * (x[k] - mu) * rs + bta[j];
            atomicAdd(&acc[j], y);
        }
    }
    __syncthreads();
    float invd = 1.0f / fmaxf((float)len, 1.0f);
    for (int j = tid; j < EMB; j += 256) out[(size_t)bs * EMB + j] = acc[j] * invd;
}

// ---------------- 6. sep = relu(sep_lin+contrib*(len>0)); L2-norm; mean --
__global__ void sep_fuse(const float* __restrict__ sep_lin,
                         const float* __restrict__ contrib,
                         const int* __restrict__ lens,
                         float* __restrict__ out) {
    int b = blockIdx.x;
    int tid = threadIdx.x;
    __shared__ float arr[4];
    float acc0 = 0.f, acc1 = 0.f;
    for (int s = 0; s < SS; s++) {
        int idx = b * SS + s;
        int len = lens[idx];
        float c0 = len > 0 ? contrib[(size_t)idx * HID + tid] : 0.f;
        float c1 = len > 0 ? contrib[(size_t)idx * HID + 256 + tid] : 0.f;
        float y0 = fmaxf(sep_lin[(size_t)idx * HID + tid] + c0, 0.f);
        float y1 = fmaxf(sep_lin[(size_t)idx * HID + 256 + tid] + c1, 0.f);
        float ssq = wave_sum(y0 * y0 + y1 * y1);
        if ((tid & 63) == 0) arr[tid >> 6] = ssq;
        __syncthreads();
        float tot = arr[0] + arr[1] + arr[2] + arr[3];
        float inv = 1.0f / fmaxf(sqrtf(tot), 1e-12f);
        acc0 += y0 * inv; acc1 += y1 * inv;
        __syncthreads();
    }
    out[b * HID + tid] = acc0 * (1.0f / SS);
    out[b * HID + 256 + tid] = acc1 * (1.0f / SS);
}

// ---------------- 7. final MLP: gelu(x@W1+b1)@W2+b2 ----------------------
__global__ void final_mlp(const float* __restrict__ sep_mean,
                          const float* __restrict__ attended,
                          const float* __restrict__ W1,
                          const float* __restrict__ b1,
                          const float* __restrict__ W2,
                          const float* __restrict__ b2,
                          float* __restrict__ out) {
    int b = blockIdx.x;
    int tid = threadIdx.x;
    __shared__ float x[2 * HID];
    __shared__ float h[HID];
    x[tid]       = sep_mean[b * HID + tid];
    x[tid + 256] = sep_mean[b * HID + 256 + tid];
    x[tid + 512] = attended[b * HID + tid];
    x[tid + 768] = attended[b * HID + 256 + tid];
    __syncthreads();
#pragma unroll
    for (int jj = 0; jj < 2; jj++) {
        int j = tid + jj * 256;
        float a = b1[j];
        for (int k = 0; k < 2 * HID; k++) a += x[k] * W1[(size_t)k * HID + j];
        h[j] = 0.5f * a * (1.0f + erff(a * 0.70710678118654752f));
    }
    __syncthreads();
    float p0 = 0.f, p1 = 0.f;
    for (int j = tid; j < HID; j += 256) {
        float hv = h[j];
        p0 += hv * W2[j * 2 + 0];
        p1 += hv * W2[j * 2 + 1];
    }
    p0 = wave_sum(p0); p1 = wave_sum(p1);
    __shared__ float r0[4], r1[4];
    if ((tid & 63) == 0) { r0[tid >> 6] = p0; r1[tid >> 6] = p1; }
    __syncthreads();
    if (tid == 0) {
        out[b * 2 + 0] = r0[0] + r0[1] + r0[2] + r0[3] + b2[0];
        out[b * 2 + 1] = r1[0] + r1[1] + r1[2] + r1[3] + b2[1];
    }
}

// ---------------- launch ----------------
extern "C" void kernel_launch(void* const* d_in, const int* in_sizes, int n_in,
                              void* d_out, int out_size, void* d_ws, size_t ws_size,
                              hipStream_t stream) {
    const float* sep_images   = (const float*)d_in[0];
    const float* img_pred     = (const float*)d_in[1];
    const int*   input_text   = (const int*)d_in[2];
    const int*   prev_hist    = (const int*)d_in[3];
    const int*   prev_hist_ln = (const int*)d_in[4];
    const unsigned char* masks = (const unsigned char*)d_in[5];
    const float* word_emb = (const float*)d_in[6];
    const float* pos_emb  = (const float*)d_in[7];
    const float* type_emb = (const float*)d_in[8];
    const float* ln_g = (const float*)d_in[9];
    const float* ln_b = (const float*)d_in[10];
    const float* W_sep = (const float*)d_in[11]; const float* b_sep = (const float*)d_in[12];
    const float* W_e2h = (const float*)d_in[13]; const float* b_e2h = (const float*)d_in[14];
    const float* W_hist = (const float*)d_in[15]; const float* b_hist = (const float*)d_in[16];
    const float* W_img = (const float*)d_in[17]; const float* b_img = (const float*)d_in[18];
    const float* W_mm = (const float*)d_in[19]; const float* b_mm = (const float*)d_in[20];
    const float* W_a1 = (const float*)d_in[21]; const float* b_a1 = (const float*)d_in[22];
    const float* W_a2 = (const float*)d_in[23]; const float* b_a2 = (const float*)d_in[24];
    const float* W_f1 = (const float*)d_in[25]; const float* b_f1 = (const float*)d_in[26];
    const float* W_f2 = (const float*)d_in[27]; const float* b_f2 = (const float*)d_in[28];

    const int NROWS = BB * LL;  // 16384

    char* ws = (char*)d_ws;
    size_t o = 0;
    auto alloc = [&](size_t bytes) { void* p = ws + o; o += (bytes + 255) & ~(size_t)255; return p; };

    bf16_t* reps_bf     = (bf16_t*)alloc((size_t)NROWS * EMB * 2);
    bf16_t* input_reps  = (bf16_t*)alloc((size_t)NROWS * HID * 2);
    bf16_t* mm_reps     = (bf16_t*)alloc((size_t)NROWS * HID * 2);
    float*  tanh_out    = (float*)alloc((size_t)NROWS * ATT * 4);
    float*  att         = (float*)alloc((size_t)NROWS * 4);
    float*  proj_img    = (float*)alloc((size_t)BB * HID * 4);
    float*  img_part    = (float*)alloc((size_t)BB * HID * 4);
    float*  attended    = (float*)alloc((size_t)BB * HID * 4);
    float*  hist_avg    = (float*)alloc((size_t)BB * SS * EMB * 4);
    float*  sep_lin     = (float*)alloc((size_t)BB * SS * HID * 4);
    float*  contrib     = (float*)alloc((size_t)BB * SS * HID * 4);
    float*  sep_mean    = (float*)alloc((size_t)BB * HID * 4);
    bf16_t* Wt_e2h      = (bf16_t*)alloc((size_t)EMB * HID * 2);
    bf16_t* Wt_mm       = (bf16_t*)alloc((size_t)HID * HID * 2);
    bf16_t* Wt_a1       = (bf16_t*)alloc((size_t)HID * ATT * 2);
    float*  part        = (float*)alloc((size_t)8 * BB * SS * HID * 4);  // split-K scratch (max 3MB)

    // weight transpose+convert for MFMA GEMMs
    conv_w<<<(EMB * HID + 255) / 256, 256, 0, stream>>>(W_e2h, Wt_e2h, EMB, HID);
    conv_w<<<(HID * HID + 255) / 256, 256, 0, stream>>>(W_mm, Wt_mm, HID, HID);
    conv_w<<<(HID * ATT + 255) / 256, 256, 0, stream>>>(W_a1, Wt_a1, HID, ATT);

    // utterance path: embeddings
    embed_ln_text<<<NROWS, 256, 0, stream>>>(input_text, word_emb, pos_emb,
                                             type_emb, ln_g, ln_b, reps_bf);

    // proj_img = relu(img_pred @ W_img + b_img)  [32,512], K=2048, KS=8
    thin_gemm_part<<<dim3(HID / 256, BB / 16, IMG / 256), 256, 0, stream>>>(
        img_pred, IMG, W_img, HID, part, BB, HID);
    thin_reduce<1><<<BB * HID / 1024, 256, 0, stream>>>(
        part, b_img, proj_img, HID, IMG / 256, (size_t)BB * HID);
    // img_part = proj_img @ W_mm[512:1024]  [32,512], K=512, KS=2
    thin_gemm_part<<<dim3(HID / 256, BB / 16, HID / 256), 256, 0, stream>>>(
        proj_img, HID, W_mm + (size_t)HID * HID, HID, part, BB, HID);
    thin_reduce<0><<<BB * HID / 1024, 256, 0, stream>>>(
        part, nullptr, img_part, HID, HID / 256, (size_t)BB * HID);

    // input_reps = relu(reps @ W_e2h + b)  (MFMA, bf16 out)
    mfma_gemm<1, true, false><<<dim3(HID / 128, NROWS / 128), 256, 0, stream>>>(
        reps_bf, Wt_e2h, b_e2h, nullptr, 1, input_reps, NROWS, HID, EMB);
    // mm_reps = relu(input_reps @ W_mm[:512] + img_part[b] + b_mm)  (MFMA, bf16 out)
    mfma_gemm<1, true, true><<<dim3(HID / 128, NROWS / 128), 256, 0, stream>>>(
        input_reps, Wt_mm, b_mm, img_part, LL, mm_reps, NROWS, HID, HID);
    // tanh_out = tanh(mm_reps @ W_a1 + b_a1)  (MFMA, f32 out)
    mfma_gemm<2, false, false><<<dim3(ATT / 128, NROWS / 128), 256, 0, stream>>>(
        mm_reps, Wt_a1, b_a1, nullptr, 1, tanh_out, NROWS, ATT, HID);

    // att scores + mask
    att_dot<<<NROWS, 256, 0, stream>>>(tanh_out, W_a2, b_a2, masks, att);
    // softmax + attended
    softmax_attend<<<BB, 256, 0, stream>>>(att, mm_reps, attended);

    // history/image path
    hist_embed_avg<<<BB * SS, 256, 0, stream>>>(prev_hist, prev_hist_ln, word_emb,
                                                pos_emb, type_emb, ln_g, ln_b, hist_avg);
    // sep_lin = sep_images @ W_sep + b_sep  [192,512], K=2048, KS=8
    thin_gemm_part<<<dim3(HID / 256, BB * SS / 16, IMG / 256), 256, 0, stream>>>(
        sep_images, IMG, W_sep, HID, part, BB * SS, HID);
    thin_reduce<0><<<BB * SS * HID / 1024, 256, 0, stream>>>(
        part, b_sep, sep_lin, HID, IMG / 256, (size_t)BB * SS * HID);
    // contrib = relu(hist_avg @ W_hist + b_hist)  [192,512], K=768, KS=3
    thin_gemm_part<<<dim3(HID / 256, BB * SS / 16, EMB / 256), 256, 0, stream>>>(
        hist_avg, EMB, W_hist, HID, part, BB * SS, HID);
    thin_reduce<1><<<BB * SS * HID / 1024, 256, 0, stream>>>(
        part, b_hist, contrib, HID, EMB / 256, (size_t)BB * SS * HID);

    sep_fuse<<<BB, 256, 0, stream>>>(sep_lin, contrib, prev_hist_ln, sep_mean);

    // final MLP -> d_out [32,2]
    final_mlp<<<BB, 256, 0, stream>>>(sep_mean, attended, W_f1, b_f1, W_f2, b_f2,
                                      (float*)d_out);
}

// Round 4
// 357.362 us; speedup vs baseline: 2.6029x; 1.3495x over previous
//
#include <hip/hip_runtime.h>
#include <hip/hip_bf16.h>
#include <math.h>

// Problem constants
#define VOCAB 30522
#define EMB 768
#define MAXPOS 512
#define HID 512
#define IMG 2048
#define ATT 256
#define BB 32      // batch
#define LL 512     // text length
#define SS 6       // images/history slots
#define HL 128     // history length
#define LN_EPS 1e-12f

typedef __bf16 bf16_t;
typedef __attribute__((ext_vector_type(8))) __bf16 bf16x8;
typedef __attribute__((ext_vector_type(4))) float f32x4;

// ---------------- reduction helpers ----------------
__device__ __forceinline__ float wave_sum(float v) {
    v += __shfl_xor(v, 1);  v += __shfl_xor(v, 2);  v += __shfl_xor(v, 4);
    v += __shfl_xor(v, 8);  v += __shfl_xor(v, 16); v += __shfl_xor(v, 32);
    return v;
}
__device__ __forceinline__ float wave_max(float v) {
    v = fmaxf(v, __shfl_xor(v, 1));  v = fmaxf(v, __shfl_xor(v, 2));
    v = fmaxf(v, __shfl_xor(v, 4));  v = fmaxf(v, __shfl_xor(v, 8));
    v = fmaxf(v, __shfl_xor(v, 16)); v = fmaxf(v, __shfl_xor(v, 32));
    return v;
}

// ---------------- 1. BERT embed + LayerNorm for text (bf16 out) ----------
__global__ void embed_ln_text(const int* __restrict__ ids,
                              const float* __restrict__ we,
                              const float* __restrict__ pe,
                              const float* __restrict__ te,
                              const float* __restrict__ g,
                              const float* __restrict__ bta,
                              bf16_t* __restrict__ out) {
    int r = blockIdx.x;
    int l = r & (LL - 1);
    int id = ids[r];
    const float* wrow = we + (size_t)id * EMB;
    const float* prow = pe + (size_t)l * EMB;
    int tid = threadIdx.x;
    float x0 = wrow[tid]       + prow[tid]       + te[tid];
    float x1 = wrow[tid + 256] + prow[tid + 256] + te[tid + 256];
    float x2 = wrow[tid + 512] + prow[tid + 512] + te[tid + 512];
    float s  = x0 + x1 + x2;
    float ss = x0 * x0 + x1 * x1 + x2 * x2;
    s = wave_sum(s); ss = wave_sum(ss);
    __shared__ float as_[4], ass_[4];
    int wid = tid >> 6, lane = tid & 63;
    if (lane == 0) { as_[wid] = s; ass_[wid] = ss; }
    __syncthreads();
    float tot  = as_[0] + as_[1] + as_[2] + as_[3];
    float tots = ass_[0] + ass_[1] + ass_[2] + ass_[3];
    float mu = tot * (1.0f / EMB);
    float var = tots * (1.0f / EMB) - mu * mu;
    float rs = rsqrtf(var + LN_EPS);
    bf16_t* orow = out + (size_t)r * EMB;
    orow[tid]       = (bf16_t)(g[tid]       * (x0 - mu) * rs + bta[tid]);
    orow[tid + 256] = (bf16_t)(g[tid + 256] * (x1 - mu) * rs + bta[tid + 256]);
    orow[tid + 512] = (bf16_t)(g[tid + 512] * (x2 - mu) * rs + bta[tid + 512]);
}

// ---------------- weight transpose + bf16 convert: [K][N] -> [N][K] ------
__global__ void conv_w(const float* __restrict__ in, bf16_t* __restrict__ out,
                       int K, int N) {
    int idx = blockIdx.x * 256 + threadIdx.x;
    if (idx >= K * N) return;
    int n = idx / K, k = idx - n * K;
    out[idx] = (bf16_t)in[(size_t)k * N + n];
}

// ---------------- MFMA bf16 GEMM: C = act(A@B^T + bias (+rowadd)) --------
template <int ACT, bool OBF16, bool ROWADD>
__global__ __launch_bounds__(256)
void mfma_gemm(const bf16_t* __restrict__ A, const bf16_t* __restrict__ Bt,
               const float* __restrict__ bias,
               const float* __restrict__ rowadd, int rowdiv,
               void* __restrict__ Cv, int M, int N, int K) {
    __shared__ __align__(16) bf16_t As[128][40];
    __shared__ __align__(16) bf16_t Bs[128][40];
    int tid = threadIdx.x;
    int lane = tid & 63, wid = tid >> 6;
    int wr = wid >> 1, wc = wid & 1;
    int row0 = blockIdx.y * 128, col0 = blockIdx.x * 128;

    int r2 = tid >> 2;
    int kc = (tid & 3) * 8;

    f32x4 acc[4][4] = {};

    const bf16_t* Ab = A + (size_t)(row0 + r2) * K + kc;
    const bf16_t* Bb = Bt + (size_t)(col0 + r2) * K + kc;
    uint4 ra0, ra1, rb0, rb1;
    ra0 = *(const uint4*)(Ab);
    ra1 = *(const uint4*)(Ab + (size_t)64 * K);
    rb0 = *(const uint4*)(Bb);
    rb1 = *(const uint4*)(Bb + (size_t)64 * K);

    int lrow = lane & 15, k0 = (lane >> 4) * 8;

    for (int kb = 0; kb < K; kb += 32) {
        __syncthreads();
        *(uint4*)&As[r2][kc] = ra0;
        *(uint4*)&As[r2 + 64][kc] = ra1;
        *(uint4*)&Bs[r2][kc] = rb0;
        *(uint4*)&Bs[r2 + 64][kc] = rb1;
        if (kb + 32 < K) {
            ra0 = *(const uint4*)(Ab + kb + 32);
            ra1 = *(const uint4*)(Ab + (size_t)64 * K + kb + 32);
            rb0 = *(const uint4*)(Bb + kb + 32);
            rb1 = *(const uint4*)(Bb + (size_t)64 * K + kb + 32);
        }
        __syncthreads();
        bf16x8 af[4], bfr[4];
#pragma unroll
        for (int mi = 0; mi < 4; mi++)
            af[mi] = *(const bf16x8*)&As[wr * 64 + mi * 16 + lrow][k0];
#pragma unroll
        for (int ni = 0; ni < 4; ni++)
            bfr[ni] = *(const bf16x8*)&Bs[wc * 64 + ni * 16 + lrow][k0];
#pragma unroll
        for (int mi = 0; mi < 4; mi++)
#pragma unroll
            for (int ni = 0; ni < 4; ni++)
                acc[mi][ni] = __builtin_amdgcn_mfma_f32_16x16x32_bf16(
                    af[mi], bfr[ni], acc[mi][ni], 0, 0, 0);
    }

    float* Cf = (float*)Cv;
    bf16_t* Cb = (bf16_t*)Cv;
    int rg = (lane >> 4) * 4;
#pragma unroll
    for (int mi = 0; mi < 4; mi++) {
#pragma unroll
        for (int ni = 0; ni < 4; ni++) {
            int col = col0 + wc * 64 + ni * 16 + lrow;
#pragma unroll
            for (int r = 0; r < 4; r++) {
                int row = row0 + wr * 64 + mi * 16 + rg + r;
                float v = acc[mi][ni][r] + bias[col];
                if (ROWADD) v += rowadd[(size_t)(row / rowdiv) * N + col];
                if (ACT == 1) v = fmaxf(v, 0.f);
                if (ACT == 2) v = tanhf(v);
                if (OBF16) Cb[(size_t)row * N + col] = (bf16_t)v;
                else       Cf[(size_t)row * N + col] = v;
            }
        }
    }
}

// ---------------- split-K thin GEMM for tiny-M fp32 matmuls --------------
__global__ __launch_bounds__(256)
void thin_gemm_part(const float* __restrict__ A, int lda,
                    const float* __restrict__ B, int ldb,
                    float* __restrict__ part, int M, int N) {
    __shared__ float As[16][256];
    int tid = threadIdx.x;
    int n0 = blockIdx.x * 256, m0 = blockIdx.y * 16, k0 = blockIdx.z * 256;
#pragma unroll
    for (int i = 0; i < 4; i++) {
        int lin = (i * 256 + tid) * 4;
        int m = lin >> 8, k = lin & 255;
        *(float4*)&As[m][k] = *(const float4*)(A + (size_t)(m0 + m) * lda + k0 + k);
    }
    __syncthreads();
    int nq = tid & 63, mg = tid >> 6;
    const float* Bp = B + (size_t)k0 * ldb + n0 + nq * 4;
    float4 acc[4] = {};
#pragma unroll 2
    for (int k = 0; k < 256; k++) {
        float4 b = *(const float4*)(Bp + (size_t)k * ldb);
#pragma unroll
        for (int mi = 0; mi < 4; mi++) {
            float a = As[mg * 4 + mi][k];
            acc[mi].x += a * b.x; acc[mi].y += a * b.y;
            acc[mi].z += a * b.z; acc[mi].w += a * b.w;
        }
    }
    size_t MN = (size_t)M * N;
#pragma unroll
    for (int mi = 0; mi < 4; mi++)
        *(float4*)(part + (size_t)blockIdx.z * MN +
                   (size_t)(m0 + mg * 4 + mi) * N + n0 + nq * 4) = acc[mi];
}

template <int ACT>
__global__ void thin_reduce(const float* __restrict__ part,
                            const float* __restrict__ bias,
                            float* __restrict__ out, int N, int KS, size_t MN) {
    int idx4 = (blockIdx.x * 256 + threadIdx.x) * 4;
    int n = idx4 & (N - 1);
    float4 v = {};
    if (bias) v = *(const float4*)(bias + n);
    for (int ks = 0; ks < KS; ks++) {
        float4 p = *(const float4*)(part + (size_t)ks * MN + idx4);
        v.x += p.x; v.y += p.y; v.z += p.z; v.w += p.w;
    }
    if (ACT == 1) {
        v.x = fmaxf(v.x, 0.f); v.y = fmaxf(v.y, 0.f);
        v.z = fmaxf(v.z, 0.f); v.w = fmaxf(v.w, 0.f);
    }
    *(float4*)(out + idx4) = v;
}

// ---------------- 3. att = tanh_out @ W_a2 + b_a2 (with mask) ------------
__global__ void att_dot(const float* __restrict__ t,
                        const float* __restrict__ w2,
                        const float* __restrict__ b2,
                        const unsigned char* __restrict__ masks,
                        float* __restrict__ att) {
    int r = blockIdx.x;
    int tid = threadIdx.x;
    float v = t[(size_t)r * ATT + tid] * w2[tid];
    v = wave_sum(v);
    __shared__ float arr[4];
    if ((tid & 63) == 0) arr[tid >> 6] = v;
    __syncthreads();
    if (tid == 0) {
        float s = arr[0] + arr[1] + arr[2] + arr[3] + b2[0];
        if (masks[r]) s = -INFINITY;
        att[r] = s;
    }
}

// ---------------- 4a. normalized softmax weights over L ------------------
__global__ void softmax_w(const float* __restrict__ att,
                          float* __restrict__ wsm) {
    int b = blockIdx.x;
    int tid = threadIdx.x;  // 512 threads
    float v = att[b * LL + tid];
    float m = wave_max(v);
    __shared__ float arr[8];
    if ((tid & 63) == 0) arr[tid >> 6] = m;
    __syncthreads();
    float M = arr[0];
#pragma unroll
    for (int i = 1; i < 8; i++) M = fmaxf(M, arr[i]);
    float e = expf(v - M);
    float s = wave_sum(e);
    __syncthreads();
    if ((tid & 63) == 0) arr[tid >> 6] = s;
    __syncthreads();
    float S = 0.f;
#pragma unroll
    for (int i = 0; i < 8; i++) S += arr[i];
    wsm[b * LL + tid] = e / S;
}

// ---------------- 4b. attended[b][h] = sum_l wsm[b][l]*mm[b][l][h] -------
// grid (BB, HID/64); 4 waves each cover 128 l's for 64 h-columns
__global__ void attend(const float* __restrict__ wsm,
                       const bf16_t* __restrict__ mm,
                       float* __restrict__ out) {
    int b = blockIdx.x, hc = blockIdx.y;
    int tid = threadIdx.x, wid = tid >> 6, lane = tid & 63;
    int h = hc * 64 + lane;
    const bf16_t* base = mm + (size_t)b * LL * HID + h;
    const float* wp = wsm + b * LL;
    float acc = 0.f;
    int l0 = wid * 128;
#pragma unroll 4
    for (int l = l0; l < l0 + 128; l++)
        acc += (float)base[(size_t)l * HID] * wp[l];
    __shared__ float red[4][64];
    red[wid][lane] = acc;
    __syncthreads();
    if (wid == 0)
        out[b * HID + h] = red[0][lane] + red[1][lane] + red[2][lane] + red[3][lane];
}

// ---------------- 5a. history embed+LN partial sums ----------------------
// grid (192, 8); wave w handles tokens h = grp + 8*w + 32*i (i=0..3)
__global__ void hist_embed_part(const int* __restrict__ ids,
                                const int* __restrict__ lens,
                                const float* __restrict__ we,
                                const float* __restrict__ pe,
                                const float* __restrict__ te,
                                const float* __restrict__ g,
                                const float* __restrict__ bta,
                                float* __restrict__ parts) {  // [8][192][768]
    int bs = blockIdx.x;
    int grp = blockIdx.y;
    int len = lens[bs];
    int tid = threadIdx.x, wid = tid >> 6, lane = tid & 63;
    __shared__ float acc[4][EMB];
#pragma unroll
    for (int k = 0; k < 12; k++) acc[wid][lane + k * 64] = 0.f;
#pragma unroll
    for (int i = 0; i < 4; i++) {
        int h = grp + 8 * wid + 32 * i;
        if (h >= len) continue;
        int id = ids[bs * HL + h];
        const float* wrow = we + (size_t)id * EMB;
        const float* prow = pe + (size_t)h * EMB;
        float x[12]; float s = 0.f, ss = 0.f;
#pragma unroll
        for (int k = 0; k < 12; k++) {
            int j = lane + k * 64;
            float v = wrow[j] + prow[j] + te[j];
            x[k] = v; s += v; ss += v * v;
        }
        s = wave_sum(s); ss = wave_sum(ss);
        float mu = s * (1.0f / EMB);
        float var = ss * (1.0f / EMB) - mu * mu;
        float rs = rsqrtf(var + LN_EPS);
#pragma unroll
        for (int k = 0; k < 12; k++) {
            int j = lane + k * 64;
            acc[wid][j] += g[j] * (x[k] - mu) * rs + bta[j];
        }
    }
    __syncthreads();
    float* dst = parts + ((size_t)grp * (BB * SS) + bs) * EMB;
    for (int j = tid; j < EMB; j += 256)
        dst[j] = acc[0][j] + acc[1][j] + acc[2][j] + acc[3][j];
}

// ---------------- 5b. hist_avg = (sum_g parts) / max(len,1) --------------
__global__ void hist_avg_reduce(const float* __restrict__ parts,
                                const int* __restrict__ lens,
                                float* __restrict__ out) {
    int bs = blockIdx.x;
    int tid = threadIdx.x;
    float invd = 1.0f / fmaxf((float)lens[bs], 1.0f);
    for (int j = tid; j < EMB; j += 256) {
        float s = 0.f;
#pragma unroll
        for (int g = 0; g < 8; g++)
            s += parts[((size_t)g * (BB * SS) + bs) * EMB + j];
        out[(size_t)bs * EMB + j] = s * invd;
    }
}

// ---------------- 6. sep = relu(sep_lin+contrib*(len>0)); L2-norm; mean --
__global__ void sep_fuse(const float* __restrict__ sep_lin,
                         const float* __restrict__ contrib,
                         const int* __restrict__ lens,
                         float* __restrict__ out) {
    int b = blockIdx.x;
    int tid = threadIdx.x;
    __shared__ float arr[4];
    float acc0 = 0.f, acc1 = 0.f;
    for (int s = 0; s < SS; s++) {
        int idx = b * SS + s;
        int len = lens[idx];
        float c0 = len > 0 ? contrib[(size_t)idx * HID + tid] : 0.f;
        float c1 = len > 0 ? contrib[(size_t)idx * HID + 256 + tid] : 0.f;
        float y0 = fmaxf(sep_lin[(size_t)idx * HID + tid] + c0, 0.f);
        float y1 = fmaxf(sep_lin[(size_t)idx * HID + 256 + tid] + c1, 0.f);
        float ssq = wave_sum(y0 * y0 + y1 * y1);
        if ((tid & 63) == 0) arr[tid >> 6] = ssq;
        __syncthreads();
        float tot = arr[0] + arr[1] + arr[2] + arr[3];
        float inv = 1.0f / fmaxf(sqrtf(tot), 1e-12f);
        acc0 += y0 * inv; acc1 += y1 * inv;
        __syncthreads();
    }
    out[b * HID + tid] = acc0 * (1.0f / SS);
    out[b * HID + 256 + tid] = acc1 * (1.0f / SS);
}

// ---------------- 7. final MLP: gelu(x@W1+b1)@W2+b2 ----------------------
__global__ void final_mlp(const float* __restrict__ sep_mean,
                          const float* __restrict__ attended,
                          const float* __restrict__ W1,
                          const float* __restrict__ b1,
                          const float* __restrict__ W2,
                          const float* __restrict__ b2,
                          float* __restrict__ out) {
    int b = blockIdx.x;
    int tid = threadIdx.x;
    __shared__ float x[2 * HID];
    __shared__ float h[HID];
    x[tid]       = sep_mean[b * HID + tid];
    x[tid + 256] = sep_mean[b * HID + 256 + tid];
    x[tid + 512] = attended[b * HID + tid];
    x[tid + 768] = attended[b * HID + 256 + tid];
    __syncthreads();
#pragma unroll
    for (int jj = 0; jj < 2; jj++) {
        int j = tid + jj * 256;
        float a = b1[j];
        for (int k = 0; k < 2 * HID; k++) a += x[k] * W1[(size_t)k * HID + j];
        h[j] = 0.5f * a * (1.0f + erff(a * 0.70710678118654752f));
    }
    __syncthreads();
    float p0 = 0.f, p1 = 0.f;
    for (int j = tid; j < HID; j += 256) {
        float hv = h[j];
        p0 += hv * W2[j * 2 + 0];
        p1 += hv * W2[j * 2 + 1];
    }
    p0 = wave_sum(p0); p1 = wave_sum(p1);
    __shared__ float r0[4], r1[4];
    if ((tid & 63) == 0) { r0[tid >> 6] = p0; r1[tid >> 6] = p1; }
    __syncthreads();
    if (tid == 0) {
        out[b * 2 + 0] = r0[0] + r0[1] + r0[2] + r0[3] + b2[0];
        out[b * 2 + 1] = r1[0] + r1[1] + r1[2] + r1[3] + b2[1];
    }
}

// ---------------- launch ----------------
extern "C" void kernel_launch(void* const* d_in, const int* in_sizes, int n_in,
                              void* d_out, int out_size, void* d_ws, size_t ws_size,
                              hipStream_t stream) {
    const float* sep_images   = (const float*)d_in[0];
    const float* img_pred     = (const float*)d_in[1];
    const int*   input_text   = (const int*)d_in[2];
    const int*   prev_hist    = (const int*)d_in[3];
    const int*   prev_hist_ln = (const int*)d_in[4];
    const unsigned char* masks = (const unsigned char*)d_in[5];
    const float* word_emb = (const float*)d_in[6];
    const float* pos_emb  = (const float*)d_in[7];
    const float* type_emb = (const float*)d_in[8];
    const float* ln_g = (const float*)d_in[9];
    const float* ln_b = (const float*)d_in[10];
    const float* W_sep = (const float*)d_in[11]; const float* b_sep = (const float*)d_in[12];
    const float* W_e2h = (const float*)d_in[13]; const float* b_e2h = (const float*)d_in[14];
    const float* W_hist = (const float*)d_in[15]; const float* b_hist = (const float*)d_in[16];
    const float* W_img = (const float*)d_in[17]; const float* b_img = (const float*)d_in[18];
    const float* W_mm = (const float*)d_in[19]; const float* b_mm = (const float*)d_in[20];
    const float* W_a1 = (const float*)d_in[21]; const float* b_a1 = (const float*)d_in[22];
    const float* W_a2 = (const float*)d_in[23]; const float* b_a2 = (const float*)d_in[24];
    const float* W_f1 = (const float*)d_in[25]; const float* b_f1 = (const float*)d_in[26];
    const float* W_f2 = (const float*)d_in[27]; const float* b_f2 = (const float*)d_in[28];

    const int NROWS = BB * LL;  // 16384

    char* ws = (char*)d_ws;
    size_t o = 0;
    auto alloc = [&](size_t bytes) { void* p = ws + o; o += (bytes + 255) & ~(size_t)255; return p; };

    bf16_t* reps_bf     = (bf16_t*)alloc((size_t)NROWS * EMB * 2);
    bf16_t* input_reps  = (bf16_t*)alloc((size_t)NROWS * HID * 2);
    bf16_t* mm_reps     = (bf16_t*)alloc((size_t)NROWS * HID * 2);
    float*  tanh_out    = (float*)alloc((size_t)NROWS * ATT * 4);
    float*  att         = (float*)alloc((size_t)NROWS * 4);
    float*  wsm         = (float*)alloc((size_t)BB * LL * 4);
    float*  proj_img    = (float*)alloc((size_t)BB * HID * 4);
    float*  img_part    = (float*)alloc((size_t)BB * HID * 4);
    float*  attended    = (float*)alloc((size_t)BB * HID * 4);
    float*  hist_avg    = (float*)alloc((size_t)BB * SS * EMB * 4);
    float*  hist_parts  = (float*)alloc((size_t)8 * BB * SS * EMB * 4);
    float*  sep_lin     = (float*)alloc((size_t)BB * SS * HID * 4);
    float*  contrib     = (float*)alloc((size_t)BB * SS * HID * 4);
    float*  sep_mean    = (float*)alloc((size_t)BB * HID * 4);
    bf16_t* Wt_e2h      = (bf16_t*)alloc((size_t)EMB * HID * 2);
    bf16_t* Wt_mm       = (bf16_t*)alloc((size_t)HID * HID * 2);
    bf16_t* Wt_a1       = (bf16_t*)alloc((size_t)HID * ATT * 2);
    float*  part        = (float*)alloc((size_t)8 * BB * SS * HID * 4);

    // weight transpose+convert for MFMA GEMMs
    conv_w<<<(EMB * HID + 255) / 256, 256, 0, stream>>>(W_e2h, Wt_e2h, EMB, HID);
    conv_w<<<(HID * HID + 255) / 256, 256, 0, stream>>>(W_mm, Wt_mm, HID, HID);
    conv_w<<<(HID * ATT + 255) / 256, 256, 0, stream>>>(W_a1, Wt_a1, HID, ATT);

    // utterance path: embeddings
    embed_ln_text<<<NROWS, 256, 0, stream>>>(input_text, word_emb, pos_emb,
                                             type_emb, ln_g, ln_b, reps_bf);

    // proj_img = relu(img_pred @ W_img + b_img)
    thin_gemm_part<<<dim3(HID / 256, BB / 16, IMG / 256), 256, 0, stream>>>(
        img_pred, IMG, W_img, HID, part, BB, HID);
    thin_reduce<1><<<BB * HID / 1024, 256, 0, stream>>>(
        part, b_img, proj_img, HID, IMG / 256, (size_t)BB * HID);
    // img_part = proj_img @ W_mm[512:1024]
    thin_gemm_part<<<dim3(HID / 256, BB / 16, HID / 256), 256, 0, stream>>>(
        proj_img, HID, W_mm + (size_t)HID * HID, HID, part, BB, HID);
    thin_reduce<0><<<BB * HID / 1024, 256, 0, stream>>>(
        part, nullptr, img_part, HID, HID / 256, (size_t)BB * HID);

    // MFMA GEMM chain
    mfma_gemm<1, true, false><<<dim3(HID / 128, NROWS / 128), 256, 0, stream>>>(
        reps_bf, Wt_e2h, b_e2h, nullptr, 1, input_reps, NROWS, HID, EMB);
    mfma_gemm<1, true, true><<<dim3(HID / 128, NROWS / 128), 256, 0, stream>>>(
        input_reps, Wt_mm, b_mm, img_part, LL, mm_reps, NROWS, HID, HID);
    mfma_gemm<2, false, false><<<dim3(ATT / 128, NROWS / 128), 256, 0, stream>>>(
        mm_reps, Wt_a1, b_a1, nullptr, 1, tanh_out, NROWS, ATT, HID);

    // att scores + mask, softmax weights, attend
    att_dot<<<NROWS, 256, 0, stream>>>(tanh_out, W_a2, b_a2, masks, att);
    softmax_w<<<BB, 512, 0, stream>>>(att, wsm);
    attend<<<dim3(BB, HID / 64), 256, 0, stream>>>(wsm, mm_reps, attended);

    // history/image path (token-parallel)
    hist_embed_part<<<dim3(BB * SS, 8), 256, 0, stream>>>(
        prev_hist, prev_hist_ln, word_emb, pos_emb, type_emb, ln_g, ln_b, hist_parts);
    hist_avg_reduce<<<BB * SS, 256, 0, stream>>>(hist_parts, prev_hist_ln, hist_avg);

    thin_gemm_part<<<dim3(HID / 256, BB * SS / 16, IMG / 256), 256, 0, stream>>>(
        sep_images, IMG, W_sep, HID, part, BB * SS, HID);
    thin_reduce<0><<<BB * SS * HID / 1024, 256, 0, stream>>>(
        part, b_sep, sep_lin, HID, IMG / 256, (size_t)BB * SS * HID);
    thin_gemm_part<<<dim3(HID / 256, BB * SS / 16, EMB / 256), 256, 0, stream>>>(
        hist_avg, EMB, W_hist, HID, part, BB * SS, HID);
    thin_reduce<1><<<BB * SS * HID / 1024, 256, 0, stream>>>(
        part, b_hist, contrib, HID, EMB / 256, (size_t)BB * SS * HID);

    sep_fuse<<<BB, 256, 0, stream>>>(sep_lin, contrib, prev_hist_ln, sep_mean);

    // final MLP -> d_out [32,2]
    final_mlp<<<BB, 256, 0, stream>>>(sep_mean, attended, W_f1, b_f1, W_f2, b_f2,
                                      (float*)d_out);
}

// Round 5
// 345.200 us; speedup vs baseline: 2.6946x; 1.0352x over previous
//
#include <hip/hip_runtime.h>
#include <hip/hip_bf16.h>
#include <math.h>

// Problem constants
#define VOCAB 30522
#define EMB 768
#define MAXPOS 512
#define HID 512
#define IMG 2048
#define ATT 256
#define BB 32      // batch
#define LL 512     // text length
#define SS 6       // images/history slots
#define HL 128     // history length
#define LN_EPS 1e-12f

typedef __bf16 bf16_t;
typedef __attribute__((ext_vector_type(8))) __bf16 bf16x8;
typedef __attribute__((ext_vector_type(4))) float f32x4;

// ---------------- reduction helpers ----------------
__device__ __forceinline__ float wave_sum(float v) {
    v += __shfl_xor(v, 1);  v += __shfl_xor(v, 2);  v += __shfl_xor(v, 4);
    v += __shfl_xor(v, 8);  v += __shfl_xor(v, 16); v += __shfl_xor(v, 32);
    return v;
}
__device__ __forceinline__ float wave_max(float v) {
    v = fmaxf(v, __shfl_xor(v, 1));  v = fmaxf(v, __shfl_xor(v, 2));
    v = fmaxf(v, __shfl_xor(v, 4));  v = fmaxf(v, __shfl_xor(v, 8));
    v = fmaxf(v, __shfl_xor(v, 16)); v = fmaxf(v, __shfl_xor(v, 32));
    return v;
}

// ---------------- 1. BERT embed + LayerNorm for text (bf16 out) ----------
__global__ void embed_ln_text(const int* __restrict__ ids,
                              const float* __restrict__ we,
                              const float* __restrict__ pe,
                              const float* __restrict__ te,
                              const float* __restrict__ g,
                              const float* __restrict__ bta,
                              bf16_t* __restrict__ out) {
    int r = blockIdx.x;
    int l = r & (LL - 1);
    int id = ids[r];
    const float* wrow = we + (size_t)id * EMB;
    const float* prow = pe + (size_t)l * EMB;
    int tid = threadIdx.x;
    float x0 = wrow[tid]       + prow[tid]       + te[tid];
    float x1 = wrow[tid + 256] + prow[tid + 256] + te[tid + 256];
    float x2 = wrow[tid + 512] + prow[tid + 512] + te[tid + 512];
    float s  = x0 + x1 + x2;
    float ss = x0 * x0 + x1 * x1 + x2 * x2;
    s = wave_sum(s); ss = wave_sum(ss);
    __shared__ float as_[4], ass_[4];
    int wid = tid >> 6, lane = tid & 63;
    if (lane == 0) { as_[wid] = s; ass_[wid] = ss; }
    __syncthreads();
    float tot  = as_[0] + as_[1] + as_[2] + as_[3];
    float tots = ass_[0] + ass_[1] + ass_[2] + ass_[3];
    float mu = tot * (1.0f / EMB);
    float var = tots * (1.0f / EMB) - mu * mu;
    float rs = rsqrtf(var + LN_EPS);
    bf16_t* orow = out + (size_t)r * EMB;
    orow[tid]       = (bf16_t)(g[tid]       * (x0 - mu) * rs + bta[tid]);
    orow[tid + 256] = (bf16_t)(g[tid + 256] * (x1 - mu) * rs + bta[tid + 256]);
    orow[tid + 512] = (bf16_t)(g[tid + 512] * (x2 - mu) * rs + bta[tid + 512]);
}

// ---------------- weight transpose + bf16 convert: [K][N] -> [N][K] ------
__global__ void conv_w(const float* __restrict__ in, bf16_t* __restrict__ out,
                       int K, int N) {
    int idx = blockIdx.x * 256 + threadIdx.x;
    if (idx >= K * N) return;
    int n = idx / K, k = idx - n * K;
    out[idx] = (bf16_t)in[(size_t)k * N + n];
}

// ---------------- MFMA bf16 GEMM: C = act(A@B^T + bias (+rowadd)) --------
template <int ACT, bool OBF16, bool ROWADD>
__global__ __launch_bounds__(256)
void mfma_gemm(const bf16_t* __restrict__ A, const bf16_t* __restrict__ Bt,
               const float* __restrict__ bias,
               const float* __restrict__ rowadd, int rowdiv,
               void* __restrict__ Cv, int M, int N, int K) {
    __shared__ __align__(16) bf16_t As[128][40];
    __shared__ __align__(16) bf16_t Bs[128][40];
    int tid = threadIdx.x;
    int lane = tid & 63, wid = tid >> 6;
    int wr = wid >> 1, wc = wid & 1;
    int row0 = blockIdx.y * 128, col0 = blockIdx.x * 128;

    int r2 = tid >> 2;
    int kc = (tid & 3) * 8;

    f32x4 acc[4][4] = {};

    const bf16_t* Ab = A + (size_t)(row0 + r2) * K + kc;
    const bf16_t* Bb = Bt + (size_t)(col0 + r2) * K + kc;
    uint4 ra0, ra1, rb0, rb1;
    ra0 = *(const uint4*)(Ab);
    ra1 = *(const uint4*)(Ab + (size_t)64 * K);
    rb0 = *(const uint4*)(Bb);
    rb1 = *(const uint4*)(Bb + (size_t)64 * K);

    int lrow = lane & 15, k0 = (lane >> 4) * 8;

    for (int kb = 0; kb < K; kb += 32) {
        __syncthreads();
        *(uint4*)&As[r2][kc] = ra0;
        *(uint4*)&As[r2 + 64][kc] = ra1;
        *(uint4*)&Bs[r2][kc] = rb0;
        *(uint4*)&Bs[r2 + 64][kc] = rb1;
        if (kb + 32 < K) {
            ra0 = *(const uint4*)(Ab + kb + 32);
            ra1 = *(const uint4*)(Ab + (size_t)64 * K + kb + 32);
            rb0 = *(const uint4*)(Bb + kb + 32);
            rb1 = *(const uint4*)(Bb + (size_t)64 * K + kb + 32);
        }
        __syncthreads();
        bf16x8 af[4], bfr[4];
#pragma unroll
        for (int mi = 0; mi < 4; mi++)
            af[mi] = *(const bf16x8*)&As[wr * 64 + mi * 16 + lrow][k0];
#pragma unroll
        for (int ni = 0; ni < 4; ni++)
            bfr[ni] = *(const bf16x8*)&Bs[wc * 64 + ni * 16 + lrow][k0];
#pragma unroll
        for (int mi = 0; mi < 4; mi++)
#pragma unroll
            for (int ni = 0; ni < 4; ni++)
                acc[mi][ni] = __builtin_amdgcn_mfma_f32_16x16x32_bf16(
                    af[mi], bfr[ni], acc[mi][ni], 0, 0, 0);
    }

    float* Cf = (float*)Cv;
    bf16_t* Cb = (bf16_t*)Cv;
    int rg = (lane >> 4) * 4;
#pragma unroll
    for (int mi = 0; mi < 4; mi++) {
#pragma unroll
        for (int ni = 0; ni < 4; ni++) {
            int col = col0 + wc * 64 + ni * 16 + lrow;
#pragma unroll
            for (int r = 0; r < 4; r++) {
                int row = row0 + wr * 64 + mi * 16 + rg + r;
                float v = acc[mi][ni][r] + bias[col];
                if (ROWADD) v += rowadd[(size_t)(row / rowdiv) * N + col];
                if (ACT == 1) v = fmaxf(v, 0.f);
                if (ACT == 2) v = tanhf(v);
                if (OBF16) Cb[(size_t)row * N + col] = (bf16_t)v;
                else       Cf[(size_t)row * N + col] = v;
            }
        }
    }
}

// ---------------- split-K thin GEMM for tiny-M fp32 matmuls --------------
__global__ __launch_bounds__(256)
void thin_gemm_part(const float* __restrict__ A, int lda,
                    const float* __restrict__ B, int ldb,
                    float* __restrict__ part, int M, int N) {
    __shared__ float As[16][256];
    int tid = threadIdx.x;
    int n0 = blockIdx.x * 256, m0 = blockIdx.y * 16, k0 = blockIdx.z * 256;
#pragma unroll
    for (int i = 0; i < 4; i++) {
        int lin = (i * 256 + tid) * 4;
        int m = lin >> 8, k = lin & 255;
        *(float4*)&As[m][k] = *(const float4*)(A + (size_t)(m0 + m) * lda + k0 + k);
    }
    __syncthreads();
    int nq = tid & 63, mg = tid >> 6;
    const float* Bp = B + (size_t)k0 * ldb + n0 + nq * 4;
    float4 acc[4] = {};
#pragma unroll 2
    for (int k = 0; k < 256; k++) {
        float4 b = *(const float4*)(Bp + (size_t)k * ldb);
#pragma unroll
        for (int mi = 0; mi < 4; mi++) {
            float a = As[mg * 4 + mi][k];
            acc[mi].x += a * b.x; acc[mi].y += a * b.y;
            acc[mi].z += a * b.z; acc[mi].w += a * b.w;
        }
    }
    size_t MN = (size_t)M * N;
#pragma unroll
    for (int mi = 0; mi < 4; mi++)
        *(float4*)(part + (size_t)blockIdx.z * MN +
                   (size_t)(m0 + mg * 4 + mi) * N + n0 + nq * 4) = acc[mi];
}

// ACT: 0 none, 1 relu, 3 exact gelu
template <int ACT>
__global__ void thin_reduce(const float* __restrict__ part,
                            const float* __restrict__ bias,
                            float* __restrict__ out, int N, int KS, size_t MN) {
    int idx4 = (blockIdx.x * 256 + threadIdx.x) * 4;
    int n = idx4 & (N - 1);
    float4 v = {};
    if (bias) v = *(const float4*)(bias + n);
    for (int ks = 0; ks < KS; ks++) {
        float4 p = *(const float4*)(part + (size_t)ks * MN + idx4);
        v.x += p.x; v.y += p.y; v.z += p.z; v.w += p.w;
    }
    if (ACT == 1) {
        v.x = fmaxf(v.x, 0.f); v.y = fmaxf(v.y, 0.f);
        v.z = fmaxf(v.z, 0.f); v.w = fmaxf(v.w, 0.f);
    }
    if (ACT == 3) {
        v.x = 0.5f * v.x * (1.0f + erff(v.x * 0.70710678118654752f));
        v.y = 0.5f * v.y * (1.0f + erff(v.y * 0.70710678118654752f));
        v.z = 0.5f * v.z * (1.0f + erff(v.z * 0.70710678118654752f));
        v.w = 0.5f * v.w * (1.0f + erff(v.w * 0.70710678118654752f));
    }
    *(float4*)(out + idx4) = v;
}

// ---------------- 3. att = tanh_out @ W_a2 + b_a2 (with mask) ------------
__global__ void att_dot(const float* __restrict__ t,
                        const float* __restrict__ w2,
                        const float* __restrict__ b2,
                        const unsigned char* __restrict__ masks,
                        float* __restrict__ att) {
    int r = blockIdx.x;
    int tid = threadIdx.x;
    float v = t[(size_t)r * ATT + tid] * w2[tid];
    v = wave_sum(v);
    __shared__ float arr[4];
    if ((tid & 63) == 0) arr[tid >> 6] = v;
    __syncthreads();
    if (tid == 0) {
        float s = arr[0] + arr[1] + arr[2] + arr[3] + b2[0];
        if (masks[r]) s = -INFINITY;
        att[r] = s;
    }
}

// ---------------- 4a. normalized softmax weights over L ------------------
__global__ void softmax_w(const float* __restrict__ att,
                          float* __restrict__ wsm) {
    int b = blockIdx.x;
    int tid = threadIdx.x;  // 512 threads
    float v = att[b * LL + tid];
    float m = wave_max(v);
    __shared__ float arr[8];
    if ((tid & 63) == 0) arr[tid >> 6] = m;
    __syncthreads();
    float M = arr[0];
#pragma unroll
    for (int i = 1; i < 8; i++) M = fmaxf(M, arr[i]);
    float e = expf(v - M);
    float s = wave_sum(e);
    __syncthreads();
    if ((tid & 63) == 0) arr[tid >> 6] = s;
    __syncthreads();
    float S = 0.f;
#pragma unroll
    for (int i = 0; i < 8; i++) S += arr[i];
    wsm[b * LL + tid] = e / S;
}

// ---------------- 4b. attended -> xcat[b][512+h] -------------------------
// grid (BB, HID/64); 4 waves each cover 128 l's for 64 h-columns
__global__ void attend(const float* __restrict__ wsm,
                       const bf16_t* __restrict__ mm,
                       float* __restrict__ xcat) {  // [BB][1024]
    int b = blockIdx.x, hc = blockIdx.y;
    int tid = threadIdx.x, wid = tid >> 6, lane = tid & 63;
    int h = hc * 64 + lane;
    const bf16_t* base = mm + (size_t)b * LL * HID + h;
    const float* wp = wsm + b * LL;
    float acc = 0.f;
    int l0 = wid * 128;
#pragma unroll 4
    for (int l = l0; l < l0 + 128; l++)
        acc += (float)base[(size_t)l * HID] * wp[l];
    __shared__ float red[4][64];
    red[wid][lane] = acc;
    __syncthreads();
    if (wid == 0)
        xcat[b * 1024 + 512 + h] =
            red[0][lane] + red[1][lane] + red[2][lane] + red[3][lane];
}

// ---------------- 5a. history embed+LN partial sums ----------------------
__global__ void hist_embed_part(const int* __restrict__ ids,
                                const int* __restrict__ lens,
                                const float* __restrict__ we,
                                const float* __restrict__ pe,
                                const float* __restrict__ te,
                                const float* __restrict__ g,
                                const float* __restrict__ bta,
                                float* __restrict__ parts) {  // [8][192][768]
    int bs = blockIdx.x;
    int grp = blockIdx.y;
    int len = lens[bs];
    int tid = threadIdx.x, wid = tid >> 6, lane = tid & 63;
    __shared__ float acc[4][EMB];
#pragma unroll
    for (int k = 0; k < 12; k++) acc[wid][lane + k * 64] = 0.f;
#pragma unroll
    for (int i = 0; i < 4; i++) {
        int h = grp + 8 * wid + 32 * i;
        if (h >= len) continue;
        int id = ids[bs * HL + h];
        const float* wrow = we + (size_t)id * EMB;
        const float* prow = pe + (size_t)h * EMB;
        float x[12]; float s = 0.f, ss = 0.f;
#pragma unroll
        for (int k = 0; k < 12; k++) {
            int j = lane + k * 64;
            float v = wrow[j] + prow[j] + te[j];
            x[k] = v; s += v; ss += v * v;
        }
        s = wave_sum(s); ss = wave_sum(ss);
        float mu = s * (1.0f / EMB);
        float var = ss * (1.0f / EMB) - mu * mu;
        float rs = rsqrtf(var + LN_EPS);
#pragma unroll
        for (int k = 0; k < 12; k++) {
            int j = lane + k * 64;
            acc[wid][j] += g[j] * (x[k] - mu) * rs + bta[j];
        }
    }
    __syncthreads();
    float* dst = parts + ((size_t)grp * (BB * SS) + bs) * EMB;
    for (int j = tid; j < EMB; j += 256)
        dst[j] = acc[0][j] + acc[1][j] + acc[2][j] + acc[3][j];
}

// ---------------- 5b. hist_avg = (sum_g parts) / max(len,1) --------------
__global__ void hist_avg_reduce(const float* __restrict__ parts,
                                const int* __restrict__ lens,
                                float* __restrict__ out) {
    int bs = blockIdx.x;
    int tid = threadIdx.x;
    float invd = 1.0f / fmaxf((float)lens[bs], 1.0f);
    for (int j = tid; j < EMB; j += 256) {
        float s = 0.f;
#pragma unroll
        for (int g = 0; g < 8; g++)
            s += parts[((size_t)g * (BB * SS) + bs) * EMB + j];
        out[(size_t)bs * EMB + j] = s * invd;
    }
}

// ---------------- 6. sep fuse -> xcat[b][0..511] -------------------------
__global__ void sep_fuse(const float* __restrict__ sep_lin,
                         const float* __restrict__ contrib,
                         const int* __restrict__ lens,
                         float* __restrict__ xcat) {  // [BB][1024]
    int b = blockIdx.x;
    int tid = threadIdx.x;
    __shared__ float arr[4];
    float acc0 = 0.f, acc1 = 0.f;
    for (int s = 0; s < SS; s++) {
        int idx = b * SS + s;
        int len = lens[idx];
        float c0 = len > 0 ? contrib[(size_t)idx * HID + tid] : 0.f;
        float c1 = len > 0 ? contrib[(size_t)idx * HID + 256 + tid] : 0.f;
        float y0 = fmaxf(sep_lin[(size_t)idx * HID + tid] + c0, 0.f);
        float y1 = fmaxf(sep_lin[(size_t)idx * HID + 256 + tid] + c1, 0.f);
        float ssq = wave_sum(y0 * y0 + y1 * y1);
        if ((tid & 63) == 0) arr[tid >> 6] = ssq;
        __syncthreads();
        float tot = arr[0] + arr[1] + arr[2] + arr[3];
        float inv = 1.0f / fmaxf(sqrtf(tot), 1e-12f);
        acc0 += y0 * inv; acc1 += y1 * inv;
        __syncthreads();
    }
    xcat[b * 1024 + tid] = acc0 * (1.0f / SS);
    xcat[b * 1024 + 256 + tid] = acc1 * (1.0f / SS);
}

// ---------------- 7. final output: out = h @ W_f2 + b_f2 -----------------
__global__ void final_out(const float* __restrict__ h,
                          const float* __restrict__ W2,
                          const float* __restrict__ b2,
                          float* __restrict__ out) {
    int b = blockIdx.x;
    int tid = threadIdx.x;
    float p0 = 0.f, p1 = 0.f;
    for (int j = tid; j < HID; j += 256) {
        float hv = h[b * HID + j];
        p0 += hv * W2[j * 2 + 0];
        p1 += hv * W2[j * 2 + 1];
    }
    p0 = wave_sum(p0); p1 = wave_sum(p1);
    __shared__ float r0[4], r1[4];
    int wid = tid >> 6;
    if ((tid & 63) == 0) { r0[wid] = p0; r1[wid] = p1; }
    __syncthreads();
    if (tid == 0) {
        out[b * 2 + 0] = r0[0] + r0[1] + r0[2] + r0[3] + b2[0];
        out[b * 2 + 1] = r1[0] + r1[1] + r1[2] + r1[3] + b2[1];
    }
}

// ---------------- launch ----------------
extern "C" void kernel_launch(void* const* d_in, const int* in_sizes, int n_in,
                              void* d_out, int out_size, void* d_ws, size_t ws_size,
                              hipStream_t stream) {
    const float* sep_images   = (const float*)d_in[0];
    const float* img_pred     = (const float*)d_in[1];
    const int*   input_text   = (const int*)d_in[2];
    const int*   prev_hist    = (const int*)d_in[3];
    const int*   prev_hist_ln = (const int*)d_in[4];
    const unsigned char* masks = (const unsigned char*)d_in[5];
    const float* word_emb = (const float*)d_in[6];
    const float* pos_emb  = (const float*)d_in[7];
    const float* type_emb = (const float*)d_in[8];
    const float* ln_g = (const float*)d_in[9];
    const float* ln_b = (const float*)d_in[10];
    const float* W_sep = (const float*)d_in[11]; const float* b_sep = (const float*)d_in[12];
    const float* W_e2h = (const float*)d_in[13]; const float* b_e2h = (const float*)d_in[14];
    const float* W_hist = (const float*)d_in[15]; const float* b_hist = (const float*)d_in[16];
    const float* W_img = (const float*)d_in[17]; const float* b_img = (const float*)d_in[18];
    const float* W_mm = (const float*)d_in[19]; const float* b_mm = (const float*)d_in[20];
    const float* W_a1 = (const float*)d_in[21]; const float* b_a1 = (const float*)d_in[22];
    const float* W_a2 = (const float*)d_in[23]; const float* b_a2 = (const float*)d_in[24];
    const float* W_f1 = (const float*)d_in[25]; const float* b_f1 = (const float*)d_in[26];
    const float* W_f2 = (const float*)d_in[27]; const float* b_f2 = (const float*)d_in[28];

    const int NROWS = BB * LL;  // 16384

    char* ws = (char*)d_ws;
    size_t o = 0;
    auto alloc = [&](size_t bytes) { void* p = ws + o; o += (bytes + 255) & ~(size_t)255; return p; };

    bf16_t* reps_bf     = (bf16_t*)alloc((size_t)NROWS * EMB * 2);
    bf16_t* input_reps  = (bf16_t*)alloc((size_t)NROWS * HID * 2);
    bf16_t* mm_reps     = (bf16_t*)alloc((size_t)NROWS * HID * 2);
    float*  tanh_out    = (float*)alloc((size_t)NROWS * ATT * 4);
    float*  att         = (float*)alloc((size_t)NROWS * 4);
    float*  wsm         = (float*)alloc((size_t)BB * LL * 4);
    float*  proj_img    = (float*)alloc((size_t)BB * HID * 4);
    float*  img_part    = (float*)alloc((size_t)BB * HID * 4);
    float*  xcat        = (float*)alloc((size_t)BB * 1024 * 4);
    float*  hmid        = (float*)alloc((size_t)BB * HID * 4);
    float*  hist_avg    = (float*)alloc((size_t)BB * SS * EMB * 4);
    float*  hist_parts  = (float*)alloc((size_t)8 * BB * SS * EMB * 4);
    float*  sep_lin     = (float*)alloc((size_t)BB * SS * HID * 4);
    float*  contrib     = (float*)alloc((size_t)BB * SS * HID * 4);
    bf16_t* Wt_e2h      = (bf16_t*)alloc((size_t)EMB * HID * 2);
    bf16_t* Wt_mm       = (bf16_t*)alloc((size_t)HID * HID * 2);
    bf16_t* Wt_a1       = (bf16_t*)alloc((size_t)HID * ATT * 2);
    float*  part        = (float*)alloc((size_t)8 * BB * SS * HID * 4);

    // weight transpose+convert for MFMA GEMMs
    conv_w<<<(EMB * HID + 255) / 256, 256, 0, stream>>>(W_e2h, Wt_e2h, EMB, HID);
    conv_w<<<(HID * HID + 255) / 256, 256, 0, stream>>>(W_mm, Wt_mm, HID, HID);
    conv_w<<<(HID * ATT + 255) / 256, 256, 0, stream>>>(W_a1, Wt_a1, HID, ATT);

    // utterance path: embeddings
    embed_ln_text<<<NROWS, 256, 0, stream>>>(input_text, word_emb, pos_emb,
                                             type_emb, ln_g, ln_b, reps_bf);

    // proj_img = relu(img_pred @ W_img + b_img)
    thin_gemm_part<<<dim3(HID / 256, BB / 16, IMG / 256), 256, 0, stream>>>(
        img_pred, IMG, W_img, HID, part, BB, HID);
    thin_reduce<1><<<BB * HID / 1024, 256, 0, stream>>>(
        part, b_img, proj_img, HID, IMG / 256, (size_t)BB * HID);
    // img_part = proj_img @ W_mm[512:1024]
    thin_gemm_part<<<dim3(HID / 256, BB / 16, HID / 256), 256, 0, stream>>>(
        proj_img, HID, W_mm + (size_t)HID * HID, HID, part, BB, HID);
    thin_reduce<0><<<BB * HID / 1024, 256, 0, stream>>>(
        part, nullptr, img_part, HID, HID / 256, (size_t)BB * HID);

    // MFMA GEMM chain
    mfma_gemm<1, true, false><<<dim3(HID / 128, NROWS / 128), 256, 0, stream>>>(
        reps_bf, Wt_e2h, b_e2h, nullptr, 1, input_reps, NROWS, HID, EMB);
    mfma_gemm<1, true, true><<<dim3(HID / 128, NROWS / 128), 256, 0, stream>>>(
        input_reps, Wt_mm, b_mm, img_part, LL, mm_reps, NROWS, HID, HID);
    mfma_gemm<2, false, false><<<dim3(ATT / 128, NROWS / 128), 256, 0, stream>>>(
        mm_reps, Wt_a1, b_a1, nullptr, 1, tanh_out, NROWS, ATT, HID);

    // att scores + mask, softmax weights, attend (writes xcat[:,512:])
    att_dot<<<NROWS, 256, 0, stream>>>(tanh_out, W_a2, b_a2, masks, att);
    softmax_w<<<BB, 512, 0, stream>>>(att, wsm);
    attend<<<dim3(BB, HID / 64), 256, 0, stream>>>(wsm, mm_reps, xcat);

    // history/image path (token-parallel)
    hist_embed_part<<<dim3(BB * SS, 8), 256, 0, stream>>>(
        prev_hist, prev_hist_ln, word_emb, pos_emb, type_emb, ln_g, ln_b, hist_parts);
    hist_avg_reduce<<<BB * SS, 256, 0, stream>>>(hist_parts, prev_hist_ln, hist_avg);

    thin_gemm_part<<<dim3(HID / 256, BB * SS / 16, IMG / 256), 256, 0, stream>>>(
        sep_images, IMG, W_sep, HID, part, BB * SS, HID);
    thin_reduce<0><<<BB * SS * HID / 1024, 256, 0, stream>>>(
        part, b_sep, sep_lin, HID, IMG / 256, (size_t)BB * SS * HID);
    thin_gemm_part<<<dim3(HID / 256, BB * SS / 16, EMB / 256), 256, 0, stream>>>(
        hist_avg, EMB, W_hist, HID, part, BB * SS, HID);
    thin_reduce<1><<<BB * SS * HID / 1024, 256, 0, stream>>>(
        part, b_hist, contrib, HID, EMB / 256, (size_t)BB * SS * HID);

    sep_fuse<<<BB, 256, 0, stream>>>(sep_lin, contrib, prev_hist_ln, xcat);

    // final MLP via split-K: hmid = gelu(xcat @ W_f1 + b_f1)
    thin_gemm_part<<<dim3(HID / 256, BB / 16, 1024 / 256), 256, 0, stream>>>(
        xcat, 1024, W_f1, HID, part, BB, HID);
    thin_reduce<3><<<BB * HID / 1024, 256, 0, stream>>>(
        part, b_f1, hmid, HID, 1024 / 256, (size_t)BB * HID);
    // out = hmid @ W_f2 + b_f2
    final_out<<<BB, 256, 0, stream>>>(hmid, W_f2, b_f2, (float*)d_out);
}

// Round 6
// 224.990 us; speedup vs baseline: 4.1343x; 1.5343x over previous
//
#include <hip/hip_runtime.h>
#include <hip/hip_bf16.h>
#include <math.h>

// Problem constants
#define VOCAB 30522
#define EMB 768
#define MAXPOS 512
#define HID 512
#define IMG 2048
#define ATT 256
#define BB 32      // batch
#define LL 512     // text length
#define SS 6       // images/history slots
#define HL 128     // history length
#define LN_EPS 1e-12f
#define KCH 128    // thin-GEMM k-chunk

typedef __bf16 bf16_t;
typedef __attribute__((ext_vector_type(8))) __bf16 bf16x8;
typedef __attribute__((ext_vector_type(4))) float f32x4;

// ---------------- reduction helpers ----------------
__device__ __forceinline__ float wave_sum(float v) {
    v += __shfl_xor(v, 1);  v += __shfl_xor(v, 2);  v += __shfl_xor(v, 4);
    v += __shfl_xor(v, 8);  v += __shfl_xor(v, 16); v += __shfl_xor(v, 32);
    return v;
}
__device__ __forceinline__ float wave_max(float v) {
    v = fmaxf(v, __shfl_xor(v, 1));  v = fmaxf(v, __shfl_xor(v, 2));
    v = fmaxf(v, __shfl_xor(v, 4));  v = fmaxf(v, __shfl_xor(v, 8));
    v = fmaxf(v, __shfl_xor(v, 16)); v = fmaxf(v, __shfl_xor(v, 32));
    return v;
}

// ---------------- 1. BERT embed + LayerNorm for text (bf16 out) ----------
__global__ void embed_ln_text(const int* __restrict__ ids,
                              const float* __restrict__ we,
                              const float* __restrict__ pe,
                              const float* __restrict__ te,
                              const float* __restrict__ g,
                              const float* __restrict__ bta,
                              bf16_t* __restrict__ out) {
    int r = blockIdx.x;
    int l = r & (LL - 1);
    int id = ids[r];
    const float* wrow = we + (size_t)id * EMB;
    const float* prow = pe + (size_t)l * EMB;
    int tid = threadIdx.x;
    float x0 = wrow[tid]       + prow[tid]       + te[tid];
    float x1 = wrow[tid + 256] + prow[tid + 256] + te[tid + 256];
    float x2 = wrow[tid + 512] + prow[tid + 512] + te[tid + 512];
    float s  = x0 + x1 + x2;
    float ss = x0 * x0 + x1 * x1 + x2 * x2;
    s = wave_sum(s); ss = wave_sum(ss);
    __shared__ float as_[4], ass_[4];
    int wid = tid >> 6, lane = tid & 63;
    if (lane == 0) { as_[wid] = s; ass_[wid] = ss; }
    __syncthreads();
    float tot  = as_[0] + as_[1] + as_[2] + as_[3];
    float tots = ass_[0] + ass_[1] + ass_[2] + ass_[3];
    float mu = tot * (1.0f / EMB);
    float var = tots * (1.0f / EMB) - mu * mu;
    float rs = rsqrtf(var + LN_EPS);
    bf16_t* orow = out + (size_t)r * EMB;
    orow[tid]       = (bf16_t)(g[tid]       * (x0 - mu) * rs + bta[tid]);
    orow[tid + 256] = (bf16_t)(g[tid + 256] * (x1 - mu) * rs + bta[tid + 256]);
    orow[tid + 512] = (bf16_t)(g[tid + 512] * (x2 - mu) * rs + bta[tid + 512]);
}

// ---------------- weight transpose + bf16 convert: [K][N] -> [N][K] ------
__global__ void conv_w(const float* __restrict__ in, bf16_t* __restrict__ out,
                       int K, int N) {
    int idx = blockIdx.x * 256 + threadIdx.x;
    if (idx >= K * N) return;
    int n = idx / K, k = idx - n * K;
    out[idx] = (bf16_t)in[(size_t)k * N + n];
}

// ---------------- MFMA bf16 GEMM: C = act(A@B^T + bias (+rowadd)) --------
template <int ACT, bool OBF16, bool ROWADD>
__global__ __launch_bounds__(256)
void mfma_gemm(const bf16_t* __restrict__ A, const bf16_t* __restrict__ Bt,
               const float* __restrict__ bias,
               const float* __restrict__ rowadd, int rowdiv,
               void* __restrict__ Cv, int M, int N, int K) {
    __shared__ __align__(16) bf16_t As[128][40];
    __shared__ __align__(16) bf16_t Bs[128][40];
    int tid = threadIdx.x;
    int lane = tid & 63, wid = tid >> 6;
    int wr = wid >> 1, wc = wid & 1;
    int row0 = blockIdx.y * 128, col0 = blockIdx.x * 128;

    int r2 = tid >> 2;
    int kc = (tid & 3) * 8;

    f32x4 acc[4][4] = {};

    const bf16_t* Ab = A + (size_t)(row0 + r2) * K + kc;
    const bf16_t* Bb = Bt + (size_t)(col0 + r2) * K + kc;
    uint4 ra0, ra1, rb0, rb1;
    ra0 = *(const uint4*)(Ab);
    ra1 = *(const uint4*)(Ab + (size_t)64 * K);
    rb0 = *(const uint4*)(Bb);
    rb1 = *(const uint4*)(Bb + (size_t)64 * K);

    int lrow = lane & 15, k0 = (lane >> 4) * 8;

    for (int kb = 0; kb < K; kb += 32) {
        __syncthreads();
        *(uint4*)&As[r2][kc] = ra0;
        *(uint4*)&As[r2 + 64][kc] = ra1;
        *(uint4*)&Bs[r2][kc] = rb0;
        *(uint4*)&Bs[r2 + 64][kc] = rb1;
        if (kb + 32 < K) {
            ra0 = *(const uint4*)(Ab + kb + 32);
            ra1 = *(const uint4*)(Ab + (size_t)64 * K + kb + 32);
            rb0 = *(const uint4*)(Bb + kb + 32);
            rb1 = *(const uint4*)(Bb + (size_t)64 * K + kb + 32);
        }
        __syncthreads();
        bf16x8 af[4], bfr[4];
#pragma unroll
        for (int mi = 0; mi < 4; mi++)
            af[mi] = *(const bf16x8*)&As[wr * 64 + mi * 16 + lrow][k0];
#pragma unroll
        for (int ni = 0; ni < 4; ni++)
            bfr[ni] = *(const bf16x8*)&Bs[wc * 64 + ni * 16 + lrow][k0];
#pragma unroll
        for (int mi = 0; mi < 4; mi++)
#pragma unroll
            for (int ni = 0; ni < 4; ni++)
                acc[mi][ni] = __builtin_amdgcn_mfma_f32_16x16x32_bf16(
                    af[mi], bfr[ni], acc[mi][ni], 0, 0, 0);
    }

    float* Cf = (float*)Cv;
    bf16_t* Cb = (bf16_t*)Cv;
    int rg = (lane >> 4) * 4;
#pragma unroll
    for (int mi = 0; mi < 4; mi++) {
#pragma unroll
        for (int ni = 0; ni < 4; ni++) {
            int col = col0 + wc * 64 + ni * 16 + lrow;
#pragma unroll
            for (int r = 0; r < 4; r++) {
                int row = row0 + wr * 64 + mi * 16 + rg + r;
                float v = acc[mi][ni][r] + bias[col];
                if (ROWADD) v += rowadd[(size_t)(row / rowdiv) * N + col];
                if (ACT == 1) v = fmaxf(v, 0.f);
                if (ACT == 2) v = tanhf(v);
                if (OBF16) Cb[(size_t)row * N + col] = (bf16_t)v;
                else       Cf[(size_t)row * N + col] = v;
            }
        }
    }
}

// ---------------- split-K thin GEMM for tiny-M fp32 matmuls --------------
// Tile: 16m x 256n x KCH(=128)k.  grid (N/256, M/16, K/KCH), block 256.
// Inner loop: batches of 8 explicit B-loads (register array) -> latency hiding.
__global__ __launch_bounds__(256)
void thin_gemm_part(const float* __restrict__ A, int lda,
                    const float* __restrict__ B, int ldb,
                    float* __restrict__ part, int M, int N) {
    __shared__ float As[16][KCH];
    int tid = threadIdx.x;
    int n0 = blockIdx.x * 256, m0 = blockIdx.y * 16, k0 = blockIdx.z * KCH;
#pragma unroll
    for (int i = 0; i < 2; i++) {
        int lin = (i * 256 + tid) * 4;
        int m = lin >> 7, k = lin & (KCH - 1);
        *(float4*)&As[m][k] = *(const float4*)(A + (size_t)(m0 + m) * lda + k0 + k);
    }
    __syncthreads();
    int nq = tid & 63, mg = tid >> 6;  // thread: cols n0+nq*4..+3, rows m0+mg*4..+3
    const float* Bp = B + (size_t)k0 * ldb + n0 + nq * 4;
    float4 acc[4] = {};
    for (int kk = 0; kk < KCH; kk += 8) {
        float4 b0 = *(const float4*)(Bp + (size_t)(kk + 0) * ldb);
        float4 b1 = *(const float4*)(Bp + (size_t)(kk + 1) * ldb);
        float4 b2 = *(const float4*)(Bp + (size_t)(kk + 2) * ldb);
        float4 b3 = *(const float4*)(Bp + (size_t)(kk + 3) * ldb);
        float4 b4 = *(const float4*)(Bp + (size_t)(kk + 4) * ldb);
        float4 b5 = *(const float4*)(Bp + (size_t)(kk + 5) * ldb);
        float4 b6 = *(const float4*)(Bp + (size_t)(kk + 6) * ldb);
        float4 b7 = *(const float4*)(Bp + (size_t)(kk + 7) * ldb);
        float4 bv[8] = {b0, b1, b2, b3, b4, b5, b6, b7};
#pragma unroll
        for (int j = 0; j < 8; j++) {
#pragma unroll
            for (int mi = 0; mi < 4; mi++) {
                float a = As[mg * 4 + mi][kk + j];
                acc[mi].x += a * bv[j].x; acc[mi].y += a * bv[j].y;
                acc[mi].z += a * bv[j].z; acc[mi].w += a * bv[j].w;
            }
        }
    }
    size_t MN = (size_t)M * N;
#pragma unroll
    for (int mi = 0; mi < 4; mi++)
        *(float4*)(part + (size_t)blockIdx.z * MN +
                   (size_t)(m0 + mg * 4 + mi) * N + n0 + nq * 4) = acc[mi];
}

// ACT: 0 none, 1 relu, 3 exact gelu
template <int ACT>
__global__ void thin_reduce(const float* __restrict__ part,
                            const float* __restrict__ bias,
                            float* __restrict__ out, int N, int KS, size_t MN) {
    int idx4 = (blockIdx.x * 256 + threadIdx.x) * 4;
    int n = idx4 & (N - 1);
    float4 v = {};
    if (bias) v = *(const float4*)(bias + n);
    for (int ks = 0; ks < KS; ks++) {
        float4 p = *(const float4*)(part + (size_t)ks * MN + idx4);
        v.x += p.x; v.y += p.y; v.z += p.z; v.w += p.w;
    }
    if (ACT == 1) {
        v.x = fmaxf(v.x, 0.f); v.y = fmaxf(v.y, 0.f);
        v.z = fmaxf(v.z, 0.f); v.w = fmaxf(v.w, 0.f);
    }
    if (ACT == 3) {
        v.x = 0.5f * v.x * (1.0f + erff(v.x * 0.70710678118654752f));
        v.y = 0.5f * v.y * (1.0f + erff(v.y * 0.70710678118654752f));
        v.z = 0.5f * v.z * (1.0f + erff(v.z * 0.70710678118654752f));
        v.w = 0.5f * v.w * (1.0f + erff(v.w * 0.70710678118654752f));
    }
    *(float4*)(out + idx4) = v;
}

// ---------------- 3. att = tanh_out @ W_a2 + b_a2 (with mask) ------------
__global__ void att_dot(const float* __restrict__ t,
                        const float* __restrict__ w2,
                        const float* __restrict__ b2,
                        const unsigned char* __restrict__ masks,
                        float* __restrict__ att) {
    int r = blockIdx.x;
    int tid = threadIdx.x;
    float v = t[(size_t)r * ATT + tid] * w2[tid];
    v = wave_sum(v);
    __shared__ float arr[4];
    if ((tid & 63) == 0) arr[tid >> 6] = v;
    __syncthreads();
    if (tid == 0) {
        float s = arr[0] + arr[1] + arr[2] + arr[3] + b2[0];
        if (masks[r]) s = -INFINITY;
        att[r] = s;
    }
}

// ---------------- 4a. normalized softmax weights over L ------------------
__global__ void softmax_w(const float* __restrict__ att,
                          float* __restrict__ wsm) {
    int b = blockIdx.x;
    int tid = threadIdx.x;  // 512 threads
    float v = att[b * LL + tid];
    float m = wave_max(v);
    __shared__ float arr[8];
    if ((tid & 63) == 0) arr[tid >> 6] = m;
    __syncthreads();
    float M = arr[0];
#pragma unroll
    for (int i = 1; i < 8; i++) M = fmaxf(M, arr[i]);
    float e = expf(v - M);
    float s = wave_sum(e);
    __syncthreads();
    if ((tid & 63) == 0) arr[tid >> 6] = s;
    __syncthreads();
    float S = 0.f;
#pragma unroll
    for (int i = 0; i < 8; i++) S += arr[i];
    wsm[b * LL + tid] = e / S;
}

// ---------------- 4b. attended -> xcat[b][512+h] -------------------------
__global__ void attend(const float* __restrict__ wsm,
                       const bf16_t* __restrict__ mm,
                       float* __restrict__ xcat) {  // [BB][1024]
    int b = blockIdx.x, hc = blockIdx.y;
    int tid = threadIdx.x, wid = tid >> 6, lane = tid & 63;
    int h = hc * 64 + lane;
    const bf16_t* base = mm + (size_t)b * LL * HID + h;
    const float* wp = wsm + b * LL;
    float acc = 0.f;
    int l0 = wid * 128;
#pragma unroll 4
    for (int l = l0; l < l0 + 128; l++)
        acc += (float)base[(size_t)l * HID] * wp[l];
    __shared__ float red[4][64];
    red[wid][lane] = acc;
    __syncthreads();
    if (wid == 0)
        xcat[b * 1024 + 512 + h] =
            red[0][lane] + red[1][lane] + red[2][lane] + red[3][lane];
}

// ---------------- 5a. history embed+LN partial sums ----------------------
__global__ void hist_embed_part(const int* __restrict__ ids,
                                const int* __restrict__ lens,
                                const float* __restrict__ we,
                                const float* __restrict__ pe,
                                const float* __restrict__ te,
                                const float* __restrict__ g,
                                const float* __restrict__ bta,
                                float* __restrict__ parts) {  // [8][192][768]
    int bs = blockIdx.x;
    int grp = blockIdx.y;
    int len = lens[bs];
    int tid = threadIdx.x, wid = tid >> 6, lane = tid & 63;
    __shared__ float acc[4][EMB];
#pragma unroll
    for (int k = 0; k < 12; k++) acc[wid][lane + k * 64] = 0.f;
#pragma unroll
    for (int i = 0; i < 4; i++) {
        int h = grp + 8 * wid + 32 * i;
        if (h >= len) continue;
        int id = ids[bs * HL + h];
        const float* wrow = we + (size_t)id * EMB;
        const float* prow = pe + (size_t)h * EMB;
        float x[12]; float s = 0.f, ss = 0.f;
#pragma unroll
        for (int k = 0; k < 12; k++) {
            int j = lane + k * 64;
            float v = wrow[j] + prow[j] + te[j];
            x[k] = v; s += v; ss += v * v;
        }
        s = wave_sum(s); ss = wave_sum(ss);
        float mu = s * (1.0f / EMB);
        float var = ss * (1.0f / EMB) - mu * mu;
        float rs = rsqrtf(var + LN_EPS);
#pragma unroll
        for (int k = 0; k < 12; k++) {
            int j = lane + k * 64;
            acc[wid][j] += g[j] * (x[k] - mu) * rs + bta[j];
        }
    }
    __syncthreads();
    float* dst = parts + ((size_t)grp * (BB * SS) + bs) * EMB;
    for (int j = tid; j < EMB; j += 256)
        dst[j] = acc[0][j] + acc[1][j] + acc[2][j] + acc[3][j];
}

// ---------------- 5b. hist_avg = (sum_g parts) / max(len,1) --------------
__global__ void hist_avg_reduce(const float* __restrict__ parts,
                                const int* __restrict__ lens,
                                float* __restrict__ out) {
    int bs = blockIdx.x;
    int tid = threadIdx.x;
    float invd = 1.0f / fmaxf((float)lens[bs], 1.0f);
    for (int j = tid; j < EMB; j += 256) {
        float s = 0.f;
#pragma unroll
        for (int g = 0; g < 8; g++)
            s += parts[((size_t)g * (BB * SS) + bs) * EMB + j];
        out[(size_t)bs * EMB + j] = s * invd;
    }
}

// ---------------- 6. sep fuse -> xcat[b][0..511] -------------------------
__global__ void sep_fuse(const float* __restrict__ sep_lin,
                         const float* __restrict__ contrib,
                         const int* __restrict__ lens,
                         float* __restrict__ xcat) {  // [BB][1024]
    int b = blockIdx.x;
    int tid = threadIdx.x;
    __shared__ float arr[4];
    float acc0 = 0.f, acc1 = 0.f;
    for (int s = 0; s < SS; s++) {
        int idx = b * SS + s;
        int len = lens[idx];
        float c0 = len > 0 ? contrib[(size_t)idx * HID + tid] : 0.f;
        float c1 = len > 0 ? contrib[(size_t)idx * HID + 256 + tid] : 0.f;
        float y0 = fmaxf(sep_lin[(size_t)idx * HID + tid] + c0, 0.f);
        float y1 = fmaxf(sep_lin[(size_t)idx * HID + 256 + tid] + c1, 0.f);
        float ssq = wave_sum(y0 * y0 + y1 * y1);
        if ((tid & 63) == 0) arr[tid >> 6] = ssq;
        __syncthreads();
        float tot = arr[0] + arr[1] + arr[2] + arr[3];
        float inv = 1.0f / fmaxf(sqrtf(tot), 1e-12f);
        acc0 += y0 * inv; acc1 += y1 * inv;
        __syncthreads();
    }
    xcat[b * 1024 + tid] = acc0 * (1.0f / SS);
    xcat[b * 1024 + 256 + tid] = acc1 * (1.0f / SS);
}

// ---------------- 7. final output: out = h @ W_f2 + b_f2 -----------------
__global__ void final_out(const float* __restrict__ h,
                          const float* __restrict__ W2,
                          const float* __restrict__ b2,
                          float* __restrict__ out) {
    int b = blockIdx.x;
    int tid = threadIdx.x;
    float p0 = 0.f, p1 = 0.f;
    for (int j = tid; j < HID; j += 256) {
        float hv = h[b * HID + j];
        p0 += hv * W2[j * 2 + 0];
        p1 += hv * W2[j * 2 + 1];
    }
    p0 = wave_sum(p0); p1 = wave_sum(p1);
    __shared__ float r0[4], r1[4];
    int wid = tid >> 6;
    if ((tid & 63) == 0) { r0[wid] = p0; r1[wid] = p1; }
    __syncthreads();
    if (tid == 0) {
        out[b * 2 + 0] = r0[0] + r0[1] + r0[2] + r0[3] + b2[0];
        out[b * 2 + 1] = r1[0] + r1[1] + r1[2] + r1[3] + b2[1];
    }
}

// ---------------- launch ----------------
extern "C" void kernel_launch(void* const* d_in, const int* in_sizes, int n_in,
                              void* d_out, int out_size, void* d_ws, size_t ws_size,
                              hipStream_t stream) {
    const float* sep_images   = (const float*)d_in[0];
    const float* img_pred     = (const float*)d_in[1];
    const int*   input_text   = (const int*)d_in[2];
    const int*   prev_hist    = (const int*)d_in[3];
    const int*   prev_hist_ln = (const int*)d_in[4];
    const unsigned char* masks = (const unsigned char*)d_in[5];
    const float* word_emb = (const float*)d_in[6];
    const float* pos_emb  = (const float*)d_in[7];
    const float* type_emb = (const float*)d_in[8];
    const float* ln_g = (const float*)d_in[9];
    const float* ln_b = (const float*)d_in[10];
    const float* W_sep = (const float*)d_in[11]; const float* b_sep = (const float*)d_in[12];
    const float* W_e2h = (const float*)d_in[13]; const float* b_e2h = (const float*)d_in[14];
    const float* W_hist = (const float*)d_in[15]; const float* b_hist = (const float*)d_in[16];
    const float* W_img = (const float*)d_in[17]; const float* b_img = (const float*)d_in[18];
    const float* W_mm = (const float*)d_in[19]; const float* b_mm = (const float*)d_in[20];
    const float* W_a1 = (const float*)d_in[21]; const float* b_a1 = (const float*)d_in[22];
    const float* W_a2 = (const float*)d_in[23]; const float* b_a2 = (const float*)d_in[24];
    const float* W_f1 = (const float*)d_in[25]; const float* b_f1 = (const float*)d_in[26];
    const float* W_f2 = (const float*)d_in[27]; const float* b_f2 = (const float*)d_in[28];

    const int NROWS = BB * LL;  // 16384

    char* ws = (char*)d_ws;
    size_t o = 0;
    auto alloc = [&](size_t bytes) { void* p = ws + o; o += (bytes + 255) & ~(size_t)255; return p; };

    bf16_t* reps_bf     = (bf16_t*)alloc((size_t)NROWS * EMB * 2);
    bf16_t* input_reps  = (bf16_t*)alloc((size_t)NROWS * HID * 2);
    bf16_t* mm_reps     = (bf16_t*)alloc((size_t)NROWS * HID * 2);
    float*  tanh_out    = (float*)alloc((size_t)NROWS * ATT * 4);
    float*  att         = (float*)alloc((size_t)NROWS * 4);
    float*  wsm         = (float*)alloc((size_t)BB * LL * 4);
    float*  proj_img    = (float*)alloc((size_t)BB * HID * 4);
    float*  img_part    = (float*)alloc((size_t)BB * HID * 4);
    float*  xcat        = (float*)alloc((size_t)BB * 1024 * 4);
    float*  hmid        = (float*)alloc((size_t)BB * HID * 4);
    float*  hist_avg    = (float*)alloc((size_t)BB * SS * EMB * 4);
    float*  hist_parts  = (float*)alloc((size_t)8 * BB * SS * EMB * 4);
    float*  sep_lin     = (float*)alloc((size_t)BB * SS * HID * 4);
    float*  contrib     = (float*)alloc((size_t)BB * SS * HID * 4);
    bf16_t* Wt_e2h      = (bf16_t*)alloc((size_t)EMB * HID * 2);
    bf16_t* Wt_mm       = (bf16_t*)alloc((size_t)HID * HID * 2);
    bf16_t* Wt_a1       = (bf16_t*)alloc((size_t)HID * ATT * 2);
    float*  part        = (float*)alloc((size_t)16 * BB * SS * HID * 4);  // 16 k-splits max

    // weight transpose+convert for MFMA GEMMs
    conv_w<<<(EMB * HID + 255) / 256, 256, 0, stream>>>(W_e2h, Wt_e2h, EMB, HID);
    conv_w<<<(HID * HID + 255) / 256, 256, 0, stream>>>(W_mm, Wt_mm, HID, HID);
    conv_w<<<(HID * ATT + 255) / 256, 256, 0, stream>>>(W_a1, Wt_a1, HID, ATT);

    // utterance path: embeddings
    embed_ln_text<<<NROWS, 256, 0, stream>>>(input_text, word_emb, pos_emb,
                                             type_emb, ln_g, ln_b, reps_bf);

    // proj_img = relu(img_pred @ W_img + b_img)   K=2048 -> 16 splits
    thin_gemm_part<<<dim3(HID / 256, BB / 16, IMG / KCH), 256, 0, stream>>>(
        img_pred, IMG, W_img, HID, part, BB, HID);
    thin_reduce<1><<<BB * HID / 1024, 256, 0, stream>>>(
        part, b_img, proj_img, HID, IMG / KCH, (size_t)BB * HID);
    // img_part = proj_img @ W_mm[512:1024]        K=512 -> 4 splits
    thin_gemm_part<<<dim3(HID / 256, BB / 16, HID / KCH), 256, 0, stream>>>(
        proj_img, HID, W_mm + (size_t)HID * HID, HID, part, BB, HID);
    thin_reduce<0><<<BB * HID / 1024, 256, 0, stream>>>(
        part, nullptr, img_part, HID, HID / KCH, (size_t)BB * HID);

    // MFMA GEMM chain
    mfma_gemm<1, true, false><<<dim3(HID / 128, NROWS / 128), 256, 0, stream>>>(
        reps_bf, Wt_e2h, b_e2h, nullptr, 1, input_reps, NROWS, HID, EMB);
    mfma_gemm<1, true, true><<<dim3(HID / 128, NROWS / 128), 256, 0, stream>>>(
        input_reps, Wt_mm, b_mm, img_part, LL, mm_reps, NROWS, HID, HID);
    mfma_gemm<2, false, false><<<dim3(ATT / 128, NROWS / 128), 256, 0, stream>>>(
        mm_reps, Wt_a1, b_a1, nullptr, 1, tanh_out, NROWS, ATT, HID);

    // att scores + mask, softmax weights, attend (writes xcat[:,512:])
    att_dot<<<NROWS, 256, 0, stream>>>(tanh_out, W_a2, b_a2, masks, att);
    softmax_w<<<BB, 512, 0, stream>>>(att, wsm);
    attend<<<dim3(BB, HID / 64), 256, 0, stream>>>(wsm, mm_reps, xcat);

    // history/image path (token-parallel)
    hist_embed_part<<<dim3(BB * SS, 8), 256, 0, stream>>>(
        prev_hist, prev_hist_ln, word_emb, pos_emb, type_emb, ln_g, ln_b, hist_parts);
    hist_avg_reduce<<<BB * SS, 256, 0, stream>>>(hist_parts, prev_hist_ln, hist_avg);

    // sep_lin = sep_images @ W_sep + b_sep        K=2048 -> 16 splits
    thin_gemm_part<<<dim3(HID / 256, BB * SS / 16, IMG / KCH), 256, 0, stream>>>(
        sep_images, IMG, W_sep, HID, part, BB * SS, HID);
    thin_reduce<0><<<BB * SS * HID / 1024, 256, 0, stream>>>(
        part, b_sep, sep_lin, HID, IMG / KCH, (size_t)BB * SS * HID);
    // contrib = relu(hist_avg @ W_hist + b_hist)  K=768 -> 6 splits
    thin_gemm_part<<<dim3(HID / 256, BB * SS / 16, EMB / KCH), 256, 0, stream>>>(
        hist_avg, EMB, W_hist, HID, part, BB * SS, HID);
    thin_reduce<1><<<BB * SS * HID / 1024, 256, 0, stream>>>(
        part, b_hist, contrib, HID, EMB / KCH, (size_t)BB * SS * HID);

    sep_fuse<<<BB, 256, 0, stream>>>(sep_lin, contrib, prev_hist_ln, xcat);

    // final MLP via split-K: hmid = gelu(xcat @ W_f1 + b_f1)  K=1024 -> 8 splits
    thin_gemm_part<<<dim3(HID / 256, BB / 16, 1024 / KCH), 256, 0, stream>>>(
        xcat, 1024, W_f1, HID, part, BB, HID);
    thin_reduce<3><<<BB * HID / 1024, 256, 0, stream>>>(
        part, b_f1, hmid, HID, 1024 / KCH, (size_t)BB * HID);
    // out = hmid @ W_f2 + b_f2
    final_out<<<BB, 256, 0, stream>>>(hmid, W_f2, b_f2, (float*)d_out);
}

// Round 7
// 212.112 us; speedup vs baseline: 4.3853x; 1.0607x over previous
//
#include <hip/hip_runtime.h>
#include <hip/hip_bf16.h>
#include <math.h>

// Problem constants
#define VOCAB 30522
#define EMB 768
#define MAXPOS 512
#define HID 512
#define IMG 2048
#define ATT 256
#define BB 32      // batch
#define LL 512     // text length
#define SS 6       // images/history slots
#define HL 128     // history length
#define LN_EPS 1e-12f
#define KCH 128    // thin-GEMM k-chunk
#define NROWS (BB * LL)

typedef __bf16 bf16_t;
typedef __attribute__((ext_vector_type(8))) __bf16 bf16x8;
typedef __attribute__((ext_vector_type(4))) float f32x4;

#define AS1 __attribute__((address_space(1)))
#define AS3 __attribute__((address_space(3)))
__device__ __forceinline__ void gload_lds16(const bf16_t* g, bf16_t* l) {
    __builtin_amdgcn_global_load_lds((const AS1 void*)g, (AS3 void*)l, 16, 0, 0);
}

// ---------------- reduction helpers ----------------
__device__ __forceinline__ float wave_sum(float v) {
    v += __shfl_xor(v, 1);  v += __shfl_xor(v, 2);  v += __shfl_xor(v, 4);
    v += __shfl_xor(v, 8);  v += __shfl_xor(v, 16); v += __shfl_xor(v, 32);
    return v;
}
__device__ __forceinline__ float wave_max(float v) {
    v = fmaxf(v, __shfl_xor(v, 1));  v = fmaxf(v, __shfl_xor(v, 2));
    v = fmaxf(v, __shfl_xor(v, 4));  v = fmaxf(v, __shfl_xor(v, 8));
    v = fmaxf(v, __shfl_xor(v, 16)); v = fmaxf(v, __shfl_xor(v, 32));
    return v;
}

// ---------------- 1. BERT embed + LayerNorm for text (bf16 out) ----------
__global__ void embed_ln_text(const int* __restrict__ ids,
                              const float* __restrict__ we,
                              const float* __restrict__ pe,
                              const float* __restrict__ te,
                              const float* __restrict__ g,
                              const float* __restrict__ bta,
                              bf16_t* __restrict__ out) {
    int r = blockIdx.x;
    int l = r & (LL - 1);
    int id = ids[r];
    const float* wrow = we + (size_t)id * EMB;
    const float* prow = pe + (size_t)l * EMB;
    int tid = threadIdx.x;
    float x0 = wrow[tid]       + prow[tid]       + te[tid];
    float x1 = wrow[tid + 256] + prow[tid + 256] + te[tid + 256];
    float x2 = wrow[tid + 512] + prow[tid + 512] + te[tid + 512];
    float s  = x0 + x1 + x2;
    float ss = x0 * x0 + x1 * x1 + x2 * x2;
    s = wave_sum(s); ss = wave_sum(ss);
    __shared__ float as_[4], ass_[4];
    int wid = tid >> 6, lane = tid & 63;
    if (lane == 0) { as_[wid] = s; ass_[wid] = ss; }
    __syncthreads();
    float tot  = as_[0] + as_[1] + as_[2] + as_[3];
    float tots = ass_[0] + ass_[1] + ass_[2] + ass_[3];
    float mu = tot * (1.0f / EMB);
    float var = tots * (1.0f / EMB) - mu * mu;
    float rs = rsqrtf(var + LN_EPS);
    bf16_t* orow = out + (size_t)r * EMB;
    orow[tid]       = (bf16_t)(g[tid]       * (x0 - mu) * rs + bta[tid]);
    orow[tid + 256] = (bf16_t)(g[tid + 256] * (x1 - mu) * rs + bta[tid + 256]);
    orow[tid + 512] = (bf16_t)(g[tid + 512] * (x2 - mu) * rs + bta[tid + 512]);
}

// ---------------- tiled weight transpose + bf16: [K][N] -> [N][K] --------
// grid (N/32, K/32), block 256 (32x8)
__global__ void conv_t(const float* __restrict__ in, bf16_t* __restrict__ out,
                       int K, int N) {
    __shared__ float t[32][33];
    int n0 = blockIdx.x * 32, k0 = blockIdx.y * 32;
    int tx = threadIdx.x & 31, ty = threadIdx.x >> 5;
#pragma unroll
    for (int i = 0; i < 4; i++)
        t[ty + i * 8][tx] = in[(size_t)(k0 + ty + i * 8) * N + n0 + tx];
    __syncthreads();
#pragma unroll
    for (int i = 0; i < 4; i++)
        out[(size_t)(n0 + ty + i * 8) * K + k0 + tx] = (bf16_t)t[tx][ty + i * 8];
}

// ---------------- MFMA bf16 GEMM (global_load_lds, dbuf, 1 barrier/K) ----
// A:[M,K] bf16 rm; Bt:[N,K] bf16 rm. 128x128 tile, BK=32, 4 waves (2x2).
// LDS linear [128][32] with slot-swizzle: pos S holds logical slot S^((row>>1)&3).
// FUSE_ATT: epilogue computes att_part[bx*M+row] = sum_col tanh(v)*w2[col], no C.
template <int ACT, bool OBF16, bool ROWADD, bool FUSE_ATT>
__global__ __launch_bounds__(256)
void mfma_gemm(const bf16_t* __restrict__ A, const bf16_t* __restrict__ Bt,
               const float* __restrict__ bias,
               const float* __restrict__ rowadd, int rowdiv,
               void* __restrict__ Cv,
               const float* __restrict__ w2, float* __restrict__ att_part,
               int M, int N, int K) {
    __shared__ __align__(16) bf16_t As[2][128 * 32];
    __shared__ __align__(16) bf16_t Bs[2][128 * 32];
    __shared__ float attp[128][2];
    int tid = threadIdx.x;
    int lane = tid & 63, wid = tid >> 6;
    int wr = wid >> 1, wc = wid & 1;
    int row0 = blockIdx.y * 128, col0 = blockIdx.x * 128;

    int srow = tid >> 2;      // staging row 0..63 (+64 on round 1)
    int sslot = tid & 3;      // 16B slot within 64B row

    const bf16_t* Ag = A + (size_t)row0 * K;
    const bf16_t* Bg = Bt + (size_t)col0 * K;

    f32x4 acc[4][4] = {};
    int lrow = lane & 15;
    int g8 = lane >> 4;       // logical k-group (8 els)

    auto stage_pair = [&](int buf, int kb) {
#pragma unroll
        for (int rr = 0; rr < 2; rr++) {
            int r = srow + rr * 64;
            int sl = sslot ^ ((r >> 1) & 3);
            gload_lds16(Ag + (size_t)r * K + kb + sl * 8,
                        &As[buf][wid * 512 + rr * 2048]);
            gload_lds16(Bg + (size_t)r * K + kb + sl * 8,
                        &Bs[buf][wid * 512 + rr * 2048]);
        }
    };

    stage_pair(0, 0);
    __syncthreads();
    int cur = 0;
    for (int kb = 0; kb < K; kb += 32) {
        if (kb + 32 < K) stage_pair(cur ^ 1, kb + 32);
        bf16x8 af[4], bfr[4];
#pragma unroll
        for (int mi = 0; mi < 4; mi++) {
            int r = wr * 64 + mi * 16 + lrow;
            int sl = g8 ^ ((r >> 1) & 3);
            af[mi] = *(const bf16x8*)&As[cur][r * 32 + sl * 8];
        }
#pragma unroll
        for (int ni = 0; ni < 4; ni++) {
            int r = wc * 64 + ni * 16 + lrow;
            int sl = g8 ^ ((r >> 1) & 3);
            bfr[ni] = *(const bf16x8*)&Bs[cur][r * 32 + sl * 8];
        }
#pragma unroll
        for (int mi = 0; mi < 4; mi++)
#pragma unroll
            for (int ni = 0; ni < 4; ni++)
                acc[mi][ni] = __builtin_amdgcn_mfma_f32_16x16x32_bf16(
                    af[mi], bfr[ni], acc[mi][ni], 0, 0, 0);
        __syncthreads();
        cur ^= 1;
    }

    if (FUSE_ATT) {
        float w2v[4];
#pragma unroll
        for (int ni = 0; ni < 4; ni++)
            w2v[ni] = w2[col0 + wc * 64 + ni * 16 + lrow];
#pragma unroll
        for (int mi = 0; mi < 4; mi++) {
#pragma unroll
            for (int r = 0; r < 4; r++) {
                float s = 0.f;
#pragma unroll
                for (int ni = 0; ni < 4; ni++) {
                    int col = col0 + wc * 64 + ni * 16 + lrow;
                    float v = tanhf(acc[mi][ni][r] + bias[col]);
                    s += v * w2v[ni];
                }
                s += __shfl_xor(s, 1); s += __shfl_xor(s, 2);
                s += __shfl_xor(s, 4); s += __shfl_xor(s, 8);
                if ((lane & 15) == 0)
                    attp[wr * 64 + mi * 16 + (lane >> 4) * 4 + r][wc] = s;
            }
        }
        __syncthreads();
        if (tid < 128)
            att_part[(size_t)blockIdx.x * M + row0 + tid] =
                attp[tid][0] + attp[tid][1];
        return;
    }

    float* Cf = (float*)Cv;
    bf16_t* Cb = (bf16_t*)Cv;
    int rg = (lane >> 4) * 4;
#pragma unroll
    for (int mi = 0; mi < 4; mi++) {
#pragma unroll
        for (int ni = 0; ni < 4; ni++) {
            int col = col0 + wc * 64 + ni * 16 + lrow;
#pragma unroll
            for (int r = 0; r < 4; r++) {
                int row = row0 + wr * 64 + mi * 16 + rg + r;
                float v = acc[mi][ni][r] + bias[col];
                if (ROWADD) v += rowadd[(size_t)(row / rowdiv) * N + col];
                if (ACT == 1) v = fmaxf(v, 0.f);
                if (ACT == 2) v = tanhf(v);
                if (OBF16) Cb[(size_t)row * N + col] = (bf16_t)v;
                else       Cf[(size_t)row * N + col] = v;
            }
        }
    }
}

// ---------------- split-K thin GEMM for tiny-M fp32 matmuls --------------
__global__ __launch_bounds__(256)
void thin_gemm_part(const float* __restrict__ A, int lda,
                    const float* __restrict__ B, int ldb,
                    float* __restrict__ part, int M, int N) {
    __shared__ float As[16][KCH];
    int tid = threadIdx.x;
    int n0 = blockIdx.x * 256, m0 = blockIdx.y * 16, k0 = blockIdx.z * KCH;
#pragma unroll
    for (int i = 0; i < 2; i++) {
        int lin = (i * 256 + tid) * 4;
        int m = lin >> 7, k = lin & (KCH - 1);
        *(float4*)&As[m][k] = *(const float4*)(A + (size_t)(m0 + m) * lda + k0 + k);
    }
    __syncthreads();
    int nq = tid & 63, mg = tid >> 6;
    const float* Bp = B + (size_t)k0 * ldb + n0 + nq * 4;
    float4 acc[4] = {};
    for (int kk = 0; kk < KCH; kk += 8) {
        float4 b0 = *(const float4*)(Bp + (size_t)(kk + 0) * ldb);
        float4 b1 = *(const float4*)(Bp + (size_t)(kk + 1) * ldb);
        float4 b2 = *(const float4*)(Bp + (size_t)(kk + 2) * ldb);
        float4 b3 = *(const float4*)(Bp + (size_t)(kk + 3) * ldb);
        float4 b4 = *(const float4*)(Bp + (size_t)(kk + 4) * ldb);
        float4 b5 = *(const float4*)(Bp + (size_t)(kk + 5) * ldb);
        float4 b6 = *(const float4*)(Bp + (size_t)(kk + 6) * ldb);
        float4 b7 = *(const float4*)(Bp + (size_t)(kk + 7) * ldb);
        float4 bv[8] = {b0, b1, b2, b3, b4, b5, b6, b7};
#pragma unroll
        for (int j = 0; j < 8; j++) {
#pragma unroll
            for (int mi = 0; mi < 4; mi++) {
                float a = As[mg * 4 + mi][kk + j];
                acc[mi].x += a * bv[j].x; acc[mi].y += a * bv[j].y;
                acc[mi].z += a * bv[j].z; acc[mi].w += a * bv[j].w;
            }
        }
    }
    size_t MN = (size_t)M * N;
#pragma unroll
    for (int mi = 0; mi < 4; mi++)
        *(float4*)(part + (size_t)blockIdx.z * MN +
                   (size_t)(m0 + mg * 4 + mi) * N + n0 + nq * 4) = acc[mi];
}

// ACT: 0 none, 1 relu
template <int ACT>
__global__ void thin_reduce(const float* __restrict__ part,
                            const float* __restrict__ bias,
                            float* __restrict__ out, int N, int KS, size_t MN) {
    int idx4 = (blockIdx.x * 256 + threadIdx.x) * 4;
    int n = idx4 & (N - 1);
    float4 v = {};
    if (bias) v = *(const float4*)(bias + n);
    for (int ks = 0; ks < KS; ks++) {
        float4 p = *(const float4*)(part + (size_t)ks * MN + idx4);
        v.x += p.x; v.y += p.y; v.z += p.z; v.w += p.w;
    }
    if (ACT == 1) {
        v.x = fmaxf(v.x, 0.f); v.y = fmaxf(v.y, 0.f);
        v.z = fmaxf(v.z, 0.f); v.w = fmaxf(v.w, 0.f);
    }
    *(float4*)(out + idx4) = v;
}

// ---------------- softmax + attend (fused) -> xcat[b][512+h] -------------
// grid (BB, HID/64); each block recomputes softmax from att_part, attends 64 h
__global__ void attend_sm(const float* __restrict__ att_part,
                          const unsigned char* __restrict__ masks,
                          const float* __restrict__ b2,
                          const bf16_t* __restrict__ mm,
                          float* __restrict__ xcat) {
    int b = blockIdx.x, hc = blockIdx.y;
    int tid = threadIdx.x, wid = tid >> 6, lane = tid & 63;
    __shared__ float wsm[LL];
    __shared__ float arr[4];
    __shared__ float red[4][64];
    int l0 = tid, l1 = tid + 256;
    float v0 = att_part[b * LL + l0] + att_part[(size_t)NROWS + b * LL + l0] + b2[0];
    float v1 = att_part[b * LL + l1] + att_part[(size_t)NROWS + b * LL + l1] + b2[0];
    if (masks[b * LL + l0]) v0 = -INFINITY;
    if (masks[b * LL + l1]) v1 = -INFINITY;
    float m = wave_max(fmaxf(v0, v1));
    if (lane == 0) arr[wid] = m;
    __syncthreads();
    float M = fmaxf(fmaxf(arr[0], arr[1]), fmaxf(arr[2], arr[3]));
    float e0 = expf(v0 - M), e1 = expf(v1 - M);
    wsm[l0] = e0; wsm[l1] = e1;
    float s = wave_sum(e0 + e1);
    __syncthreads();
    if (lane == 0) arr[wid] = s;
    __syncthreads();
    float inv = 1.0f / (arr[0] + arr[1] + arr[2] + arr[3]);
    int h = hc * 64 + lane;
    const bf16_t* base = mm + (size_t)b * LL * HID + h;
    float acc = 0.f;
    int ls = wid * 128;
#pragma unroll 4
    for (int l = ls; l < ls + 128; l++)
        acc += (float)base[(size_t)l * HID] * wsm[l];
    red[wid][lane] = acc;
    __syncthreads();
    if (wid == 0)
        xcat[b * 1024 + 512 + h] =
            (red[0][lane] + red[1][lane] + red[2][lane] + red[3][lane]) * inv;
}

// ---------------- 5a. history embed+LN partial sums ----------------------
__global__ void hist_embed_part(const int* __restrict__ ids,
                                const int* __restrict__ lens,
                                const float* __restrict__ we,
                                const float* __restrict__ pe,
                                const float* __restrict__ te,
                                const float* __restrict__ g,
                                const float* __restrict__ bta,
                                float* __restrict__ parts) {  // [8][192][768]
    int bs = blockIdx.x;
    int grp = blockIdx.y;
    int len = lens[bs];
    int tid = threadIdx.x, wid = tid >> 6, lane = tid & 63;
    __shared__ float acc[4][EMB];
#pragma unroll
    for (int k = 0; k < 12; k++) acc[wid][lane + k * 64] = 0.f;
#pragma unroll
    for (int i = 0; i < 4; i++) {
        int h = grp + 8 * wid + 32 * i;
        if (h >= len) continue;
        int id = ids[bs * HL + h];
        const float* wrow = we + (size_t)id * EMB;
        const float* prow = pe + (size_t)h * EMB;
        float x[12]; float s = 0.f, ss = 0.f;
#pragma unroll
        for (int k = 0; k < 12; k++) {
            int j = lane + k * 64;
            float v = wrow[j] + prow[j] + te[j];
            x[k] = v; s += v; ss += v * v;
        }
        s = wave_sum(s); ss = wave_sum(ss);
        float mu = s * (1.0f / EMB);
        float var = ss * (1.0f / EMB) - mu * mu;
        float rs = rsqrtf(var + LN_EPS);
#pragma unroll
        for (int k = 0; k < 12; k++) {
            int j = lane + k * 64;
            acc[wid][j] += g[j] * (x[k] - mu) * rs + bta[j];
        }
    }
    __syncthreads();
    float* dst = parts + ((size_t)grp * (BB * SS) + bs) * EMB;
    for (int j = tid; j < EMB; j += 256)
        dst[j] = acc[0][j] + acc[1][j] + acc[2][j] + acc[3][j];
}

// ---------------- 5b. hist_avg = (sum_g parts) / max(len,1) --------------
__global__ void hist_avg_reduce(const float* __restrict__ parts,
                                const int* __restrict__ lens,
                                float* __restrict__ out) {
    int bs = blockIdx.x;
    int tid = threadIdx.x;
    float invd = 1.0f / fmaxf((float)lens[bs], 1.0f);
    for (int j = tid; j < EMB; j += 256) {
        float s = 0.f;
#pragma unroll
        for (int g = 0; g < 8; g++)
            s += parts[((size_t)g * (BB * SS) + bs) * EMB + j];
        out[(size_t)bs * EMB + j] = s * invd;
    }
}

// ---------------- 6. sep path fused: reduce parts + relu + L2 + mean -----
// reads partA (16 splits, sep_images@W_sep) and partB (6 splits, hist@W_hist)
__global__ void sep_fuse_all(const float* __restrict__ pA,
                             const float* __restrict__ pB,
                             const float* __restrict__ b_sep,
                             const float* __restrict__ b_hist,
                             const int* __restrict__ lens,
                             float* __restrict__ xcat) {  // [BB][1024]
    int b = blockIdx.x;
    int tid = threadIdx.x;
    __shared__ float arr[4];
    const size_t MN = (size_t)BB * SS * HID;
    float acc0 = 0.f, acc1 = 0.f;
    for (int s = 0; s < SS; s++) {
        int idx = b * SS + s;
        int len = lens[idx];
        size_t base = (size_t)idx * HID;
        float v0 = b_sep[tid], v1 = b_sep[tid + 256];
#pragma unroll
        for (int ks = 0; ks < 16; ks++) {
            v0 += pA[ks * MN + base + tid];
            v1 += pA[ks * MN + base + tid + 256];
        }
        float c0 = b_hist[tid], c1 = b_hist[tid + 256];
#pragma unroll
        for (int ks = 0; ks < 6; ks++) {
            c0 += pB[ks * MN + base + tid];
            c1 += pB[ks * MN + base + tid + 256];
        }
        c0 = fmaxf(c0, 0.f); c1 = fmaxf(c1, 0.f);
        if (len <= 0) { c0 = 0.f; c1 = 0.f; }
        float y0 = fmaxf(v0 + c0, 0.f), y1 = fmaxf(v1 + c1, 0.f);
        float ssq = wave_sum(y0 * y0 + y1 * y1);
        if ((tid & 63) == 0) arr[tid >> 6] = ssq;
        __syncthreads();
        float tot = arr[0] + arr[1] + arr[2] + arr[3];
        float inv = 1.0f / fmaxf(sqrtf(tot), 1e-12f);
        acc0 += y0 * inv; acc1 += y1 * inv;
        __syncthreads();
    }
    xcat[b * 1024 + tid] = acc0 * (1.0f / SS);
    xcat[b * 1024 + 256 + tid] = acc1 * (1.0f / SS);
}

// ---------------- 7. final: reduce f1-parts + bias + gelu, dot W_f2 ------
__global__ void final_out2(const float* __restrict__ part,
                           const float* __restrict__ b1,
                           const float* __restrict__ W2,
                           const float* __restrict__ b2,
                           float* __restrict__ out) {
    int b = blockIdx.x;
    int tid = threadIdx.x;
    __shared__ float h[HID];
    const size_t MN = (size_t)BB * HID;
#pragma unroll
    for (int jj = 0; jj < 2; jj++) {
        int d = tid + jj * 256;
        float a = b1[d];
#pragma unroll
        for (int ks = 0; ks < 8; ks++) a += part[ks * MN + (size_t)b * HID + d];
        h[d] = 0.5f * a * (1.0f + erff(a * 0.70710678118654752f));
    }
    __syncthreads();
    float p0 = 0.f, p1 = 0.f;
    for (int j = tid; j < HID; j += 256) {
        float hv = h[j];
        p0 += hv * W2[j * 2 + 0];
        p1 += hv * W2[j * 2 + 1];
    }
    p0 = wave_sum(p0); p1 = wave_sum(p1);
    __shared__ float r0[4], r1[4];
    int wid = tid >> 6;
    if ((tid & 63) == 0) { r0[wid] = p0; r1[wid] = p1; }
    __syncthreads();
    if (tid == 0) {
        out[b * 2 + 0] = r0[0] + r0[1] + r0[2] + r0[3] + b2[0];
        out[b * 2 + 1] = r1[0] + r1[1] + r1[2] + r1[3] + b2[1];
    }
}

// ---------------- launch ----------------
extern "C" void kernel_launch(void* const* d_in, const int* in_sizes, int n_in,
                              void* d_out, int out_size, void* d_ws, size_t ws_size,
                              hipStream_t stream) {
    const float* sep_images   = (const float*)d_in[0];
    const float* img_pred     = (const float*)d_in[1];
    const int*   input_text   = (const int*)d_in[2];
    const int*   prev_hist    = (const int*)d_in[3];
    const int*   prev_hist_ln = (const int*)d_in[4];
    const unsigned char* masks = (const unsigned char*)d_in[5];
    const float* word_emb = (const float*)d_in[6];
    const float* pos_emb  = (const float*)d_in[7];
    const float* type_emb = (const float*)d_in[8];
    const float* ln_g = (const float*)d_in[9];
    const float* ln_b = (const float*)d_in[10];
    const float* W_sep = (const float*)d_in[11]; const float* b_sep = (const float*)d_in[12];
    const float* W_e2h = (const float*)d_in[13]; const float* b_e2h = (const float*)d_in[14];
    const float* W_hist = (const float*)d_in[15]; const float* b_hist = (const float*)d_in[16];
    const float* W_img = (const float*)d_in[17]; const float* b_img = (const float*)d_in[18];
    const float* W_mm = (const float*)d_in[19]; const float* b_mm = (const float*)d_in[20];
    const float* W_a1 = (const float*)d_in[21]; const float* b_a1 = (const float*)d_in[22];
    const float* W_a2 = (const float*)d_in[23]; const float* b_a2 = (const float*)d_in[24];
    const float* W_f1 = (const float*)d_in[25]; const float* b_f1 = (const float*)d_in[26];
    const float* W_f2 = (const float*)d_in[27]; const float* b_f2 = (const float*)d_in[28];

    char* ws = (char*)d_ws;
    size_t o = 0;
    auto alloc = [&](size_t bytes) { void* p = ws + o; o += (bytes + 255) & ~(size_t)255; return p; };

    bf16_t* reps_bf     = (bf16_t*)alloc((size_t)NROWS * EMB * 2);
    bf16_t* input_reps  = (bf16_t*)alloc((size_t)NROWS * HID * 2);
    bf16_t* mm_reps     = (bf16_t*)alloc((size_t)NROWS * HID * 2);
    float*  att_part    = (float*)alloc((size_t)2 * NROWS * 4);
    float*  proj_img    = (float*)alloc((size_t)BB * HID * 4);
    float*  img_part    = (float*)alloc((size_t)BB * HID * 4);
    float*  xcat        = (float*)alloc((size_t)BB * 1024 * 4);
    float*  hist_avg    = (float*)alloc((size_t)BB * SS * EMB * 4);
    float*  hist_parts  = (float*)alloc((size_t)8 * BB * SS * EMB * 4);
    bf16_t* Wt_e2h      = (bf16_t*)alloc((size_t)EMB * HID * 2);
    bf16_t* Wt_mm       = (bf16_t*)alloc((size_t)HID * HID * 2);
    bf16_t* Wt_a1       = (bf16_t*)alloc((size_t)HID * ATT * 2);
    float*  partA       = (float*)alloc((size_t)16 * BB * SS * HID * 4);
    float*  partB       = (float*)alloc((size_t)6 * BB * SS * HID * 4);

    // weight transposes (tiled)
    conv_t<<<dim3(HID / 32, EMB / 32), 256, 0, stream>>>(W_e2h, Wt_e2h, EMB, HID);
    conv_t<<<dim3(HID / 32, HID / 32), 256, 0, stream>>>(W_mm, Wt_mm, HID, HID);
    conv_t<<<dim3(ATT / 32, HID / 32), 256, 0, stream>>>(W_a1, Wt_a1, HID, ATT);

    // utterance path: embeddings
    embed_ln_text<<<NROWS, 256, 0, stream>>>(input_text, word_emb, pos_emb,
                                             type_emb, ln_g, ln_b, reps_bf);

    // proj_img = relu(img_pred @ W_img + b_img)
    thin_gemm_part<<<dim3(HID / 256, BB / 16, IMG / KCH), 256, 0, stream>>>(
        img_pred, IMG, W_img, HID, partA, BB, HID);
    thin_reduce<1><<<BB * HID / 1024, 256, 0, stream>>>(
        partA, b_img, proj_img, HID, IMG / KCH, (size_t)BB * HID);
    // img_part = proj_img @ W_mm[512:1024]
    thin_gemm_part<<<dim3(HID / 256, BB / 16, HID / KCH), 256, 0, stream>>>(
        proj_img, HID, W_mm + (size_t)HID * HID, HID, partA, BB, HID);
    thin_reduce<0><<<BB * HID / 1024, 256, 0, stream>>>(
        partA, nullptr, img_part, HID, HID / KCH, (size_t)BB * HID);

    // MFMA GEMM chain
    mfma_gemm<1, true, false, false><<<dim3(HID / 128, NROWS / 128), 256, 0, stream>>>(
        reps_bf, Wt_e2h, b_e2h, nullptr, 1, input_reps, nullptr, nullptr,
        NROWS, HID, EMB);
    mfma_gemm<1, true, true, false><<<dim3(HID / 128, NROWS / 128), 256, 0, stream>>>(
        input_reps, Wt_mm, b_mm, img_part, LL, mm_reps, nullptr, nullptr,
        NROWS, HID, HID);
    // a1 GEMM with fused tanh + dot(W_a2): writes att_part[2][NROWS]
    mfma_gemm<2, false, false, true><<<dim3(ATT / 128, NROWS / 128), 256, 0, stream>>>(
        mm_reps, Wt_a1, b_a1, nullptr, 1, nullptr, W_a2, att_part,
        NROWS, ATT, HID);

    // softmax + attend (writes xcat[:,512:])
    attend_sm<<<dim3(BB, HID / 64), 256, 0, stream>>>(att_part, masks, b_a2,
                                                      mm_reps, xcat);

    // history/image path
    hist_embed_part<<<dim3(BB * SS, 8), 256, 0, stream>>>(
        prev_hist, prev_hist_ln, word_emb, pos_emb, type_emb, ln_g, ln_b, hist_parts);
    hist_avg_reduce<<<BB * SS, 256, 0, stream>>>(hist_parts, prev_hist_ln, hist_avg);

    // sep_lin parts (16 splits) and contrib parts (6 splits)
    thin_gemm_part<<<dim3(HID / 256, BB * SS / 16, IMG / KCH), 256, 0, stream>>>(
        sep_images, IMG, W_sep, HID, partA, BB * SS, HID);
    thin_gemm_part<<<dim3(HID / 256, BB * SS / 16, EMB / KCH), 256, 0, stream>>>(
        hist_avg, EMB, W_hist, HID, partB, BB * SS, HID);
    // fused reduce + relu + L2-normalize + mean -> xcat[:,0:512]
    sep_fuse_all<<<BB, 256, 0, stream>>>(partA, partB, b_sep, b_hist,
                                         prev_hist_ln, xcat);

    // final MLP: f1 parts then fused reduce+gelu+W_f2
    thin_gemm_part<<<dim3(HID / 256, BB / 16, 1024 / KCH), 256, 0, stream>>>(
        xcat, 1024, W_f1, HID, partA, BB, HID);
    final_out2<<<BB, 256, 0, stream>>>(partA, b_f1, W_f2, b_f2, (float*)d_out);
}

// Round 8
// 192.883 us; speedup vs baseline: 4.8225x; 1.0997x over previous
//
#include <hip/hip_runtime.h>
#include <hip/hip_bf16.h>
#include <math.h>

// Problem constants
#define VOCAB 30522
#define EMB 768
#define MAXPOS 512
#define HID 512
#define IMG 2048
#define ATT 256
#define BB 32      // batch
#define LL 512     // text length
#define SS 6       // images/history slots
#define HL 128     // history length
#define LN_EPS 1e-12f
#define KCH 128    // thin-GEMM k-chunk
#define NROWS (BB * LL)
#define MPS (BB + BB * SS)   // 224 rows: img_pred(32) + sep_images(192)

typedef __bf16 bf16_t;
typedef __attribute__((ext_vector_type(4))) __bf16 bf16x4;
typedef __attribute__((ext_vector_type(8))) __bf16 bf16x8;
typedef __attribute__((ext_vector_type(4))) float f32x4;

#define AS1 __attribute__((address_space(1)))
#define AS3 __attribute__((address_space(3)))
__device__ __forceinline__ void gload_lds16(const bf16_t* g, bf16_t* l) {
    __builtin_amdgcn_global_load_lds((const AS1 void*)g, (AS3 void*)l, 16, 0, 0);
}

// ---------------- reduction helpers ----------------
__device__ __forceinline__ float wave_sum(float v) {
    v += __shfl_xor(v, 1);  v += __shfl_xor(v, 2);  v += __shfl_xor(v, 4);
    v += __shfl_xor(v, 8);  v += __shfl_xor(v, 16); v += __shfl_xor(v, 32);
    return v;
}
__device__ __forceinline__ float wave_max(float v) {
    v = fmaxf(v, __shfl_xor(v, 1));  v = fmaxf(v, __shfl_xor(v, 2));
    v = fmaxf(v, __shfl_xor(v, 4));  v = fmaxf(v, __shfl_xor(v, 8));
    v = fmaxf(v, __shfl_xor(v, 16)); v = fmaxf(v, __shfl_xor(v, 32));
    return v;
}

// ---------------- 1. BERT embed + LN, wave-per-row, f4 loads -------------
// block = 4 waves = 4 rows; grid NROWS/4
__global__ void embed_ln_text(const int* __restrict__ ids,
                              const float* __restrict__ we,
                              const float* __restrict__ pe,
                              const float* __restrict__ te,
                              const float* __restrict__ g,
                              const float* __restrict__ bta,
                              bf16_t* __restrict__ out) {
    int tid = threadIdx.x, wid = tid >> 6, lane = tid & 63;
    int r = blockIdx.x * 4 + wid;
    int l = r & (LL - 1);
    int id = ids[r];
    const float* wrow = we + (size_t)id * EMB + lane * 12;
    const float* prow = pe + (size_t)l * EMB + lane * 12;
    const float* tp = te + lane * 12;
    float x[12]; float s = 0.f, ss = 0.f;
#pragma unroll
    for (int q = 0; q < 3; q++) {
        float4 a = *(const float4*)(wrow + q * 4);
        float4 b = *(const float4*)(prow + q * 4);
        float4 c = *(const float4*)(tp + q * 4);
        float v0 = a.x + b.x + c.x, v1 = a.y + b.y + c.y;
        float v2 = a.z + b.z + c.z, v3 = a.w + b.w + c.w;
        x[q * 4 + 0] = v0; x[q * 4 + 1] = v1; x[q * 4 + 2] = v2; x[q * 4 + 3] = v3;
        s += v0 + v1 + v2 + v3;
        ss += v0 * v0 + v1 * v1 + v2 * v2 + v3 * v3;
    }
    s = wave_sum(s); ss = wave_sum(ss);
    float mu = s * (1.0f / EMB);
    float var = ss * (1.0f / EMB) - mu * mu;
    float rs = rsqrtf(var + LN_EPS);
    bf16_t* orow = out + (size_t)r * EMB + lane * 12;
    const float* gp = g + lane * 12;
    const float* bp = bta + lane * 12;
#pragma unroll
    for (int q = 0; q < 3; q++) {
        float4 gv = *(const float4*)(gp + q * 4);
        float4 bv = *(const float4*)(bp + q * 4);
        bf16x4 y;
        y[0] = (bf16_t)(gv.x * (x[q * 4 + 0] - mu) * rs + bv.x);
        y[1] = (bf16_t)(gv.y * (x[q * 4 + 1] - mu) * rs + bv.y);
        y[2] = (bf16_t)(gv.z * (x[q * 4 + 2] - mu) * rs + bv.z);
        y[3] = (bf16_t)(gv.w * (x[q * 4 + 3] - mu) * rs + bv.w);
        *(bf16x4*)(orow + q * 4) = y;
    }
}

// ---------------- all 3 weight transposes in one dispatch ----------------
__global__ void conv_all(const float* __restrict__ W1, bf16_t* __restrict__ O1,
                         const float* __restrict__ W2, bf16_t* __restrict__ O2,
                         const float* __restrict__ W3, bf16_t* __restrict__ O3) {
    __shared__ float t[32][33];
    int bid = blockIdx.x;
    const float* in; bf16_t* out; int K, N, x, y;
    if (bid < 384)      { in = W1; out = O1; K = EMB; N = HID; x = bid & 15; y = bid >> 4; }
    else if (bid < 640) { int b = bid - 384; in = W2; out = O2; K = HID; N = HID; x = b & 15; y = b >> 4; }
    else                { int b = bid - 640; in = W3; out = O3; K = HID; N = ATT; x = b & 7;  y = b >> 3; }
    int n0 = x * 32, k0 = y * 32;
    int tx = threadIdx.x & 31, ty = threadIdx.x >> 5;
#pragma unroll
    for (int i = 0; i < 4; i++)
        t[ty + i * 8][tx] = in[(size_t)(k0 + ty + i * 8) * N + n0 + tx];
    __syncthreads();
#pragma unroll
    for (int i = 0; i < 4; i++)
        out[(size_t)(n0 + ty + i * 8) * K + k0 + tx] = (bf16_t)t[tx][ty + i * 8];
}

// ---------------- MFMA bf16 GEMM (global_load_lds, dbuf, 1 barrier/K) ----
template <int ACT, bool OBF16, bool ROWADD, bool FUSE_ATT>
__global__ __launch_bounds__(256)
void mfma_gemm(const bf16_t* __restrict__ A, const bf16_t* __restrict__ Bt,
               const float* __restrict__ bias,
               const float* __restrict__ rowadd, int rowdiv,
               void* __restrict__ Cv,
               const float* __restrict__ w2, float* __restrict__ att_part,
               int M, int N, int K) {
    __shared__ __align__(16) bf16_t As[2][128 * 32];
    __shared__ __align__(16) bf16_t Bs[2][128 * 32];
    __shared__ float attp[128][2];
    int tid = threadIdx.x;
    int lane = tid & 63, wid = tid >> 6;
    int wr = wid >> 1, wc = wid & 1;
    int row0 = blockIdx.y * 128, col0 = blockIdx.x * 128;

    int srow = tid >> 2;
    int sslot = tid & 3;

    const bf16_t* Ag = A + (size_t)row0 * K;
    const bf16_t* Bg = Bt + (size_t)col0 * K;

    f32x4 acc[4][4] = {};
    int lrow = lane & 15;
    int g8 = lane >> 4;

    auto stage_pair = [&](int buf, int kb) {
#pragma unroll
        for (int rr = 0; rr < 2; rr++) {
            int r = srow + rr * 64;
            int sl = sslot ^ ((r >> 1) & 3);
            gload_lds16(Ag + (size_t)r * K + kb + sl * 8,
                        &As[buf][wid * 512 + rr * 2048]);
            gload_lds16(Bg + (size_t)r * K + kb + sl * 8,
                        &Bs[buf][wid * 512 + rr * 2048]);
        }
    };

    stage_pair(0, 0);
    __syncthreads();
    int cur = 0;
    for (int kb = 0; kb < K; kb += 32) {
        if (kb + 32 < K) stage_pair(cur ^ 1, kb + 32);
        bf16x8 af[4], bfr[4];
#pragma unroll
        for (int mi = 0; mi < 4; mi++) {
            int r = wr * 64 + mi * 16 + lrow;
            int sl = g8 ^ ((r >> 1) & 3);
            af[mi] = *(const bf16x8*)&As[cur][r * 32 + sl * 8];
        }
#pragma unroll
        for (int ni = 0; ni < 4; ni++) {
            int r = wc * 64 + ni * 16 + lrow;
            int sl = g8 ^ ((r >> 1) & 3);
            bfr[ni] = *(const bf16x8*)&Bs[cur][r * 32 + sl * 8];
        }
#pragma unroll
        for (int mi = 0; mi < 4; mi++)
#pragma unroll
            for (int ni = 0; ni < 4; ni++)
                acc[mi][ni] = __builtin_amdgcn_mfma_f32_16x16x32_bf16(
                    af[mi], bfr[ni], acc[mi][ni], 0, 0, 0);
        __syncthreads();
        cur ^= 1;
    }

    if (FUSE_ATT) {
        float w2v[4];
#pragma unroll
        for (int ni = 0; ni < 4; ni++)
            w2v[ni] = w2[col0 + wc * 64 + ni * 16 + lrow];
#pragma unroll
        for (int mi = 0; mi < 4; mi++) {
#pragma unroll
            for (int r = 0; r < 4; r++) {
                float s = 0.f;
#pragma unroll
                for (int ni = 0; ni < 4; ni++) {
                    int col = col0 + wc * 64 + ni * 16 + lrow;
                    float v = tanhf(acc[mi][ni][r] + bias[col]);
                    s += v * w2v[ni];
                }
                s += __shfl_xor(s, 1); s += __shfl_xor(s, 2);
                s += __shfl_xor(s, 4); s += __shfl_xor(s, 8);
                if ((lane & 15) == 0)
                    attp[wr * 64 + mi * 16 + (lane >> 4) * 4 + r][wc] = s;
            }
        }
        __syncthreads();
        if (tid < 128)
            att_part[(size_t)blockIdx.x * M + row0 + tid] =
                attp[tid][0] + attp[tid][1];
        return;
    }

    float* Cf = (float*)Cv;
    bf16_t* Cb = (bf16_t*)Cv;
    int rg = (lane >> 4) * 4;
#pragma unroll
    for (int mi = 0; mi < 4; mi++) {
#pragma unroll
        for (int ni = 0; ni < 4; ni++) {
            int col = col0 + wc * 64 + ni * 16 + lrow;
#pragma unroll
            for (int r = 0; r < 4; r++) {
                int row = row0 + wr * 64 + mi * 16 + rg + r;
                float v = acc[mi][ni][r] + bias[col];
                if (ROWADD) v += rowadd[(size_t)(row / rowdiv) * N + col];
                if (ACT == 1) v = fmaxf(v, 0.f);
                if (ACT == 2) v = tanhf(v);
                if (OBF16) Cb[(size_t)row * N + col] = (bf16_t)v;
                else       Cf[(size_t)row * N + col] = v;
            }
        }
    }
}

// ---------------- split-K thin GEMM with A-prologue modes ----------------
// AMODE 0: dual-source direct (A if row<asplit else A2, same lda)
// AMODE 1: A = relu(sum_{ks<16} parts[ks*MNp + row*512 + k] + abias[k])
// AMODE 2: A = (sum_{g<8} parts[g*MNp + row*768 + k]) / max(lens[row],1)
template <int AMODE>
__global__ __launch_bounds__(256)
void thin_gemm(const float* __restrict__ A, const float* __restrict__ A2,
               int asplit, int lda,
               const float* __restrict__ parts, size_t MNp,
               const float* __restrict__ abias, const int* __restrict__ lens,
               const float* __restrict__ B, int ldb,
               float* __restrict__ part, int M, int N) {
    __shared__ float As[16][KCH];
    int tid = threadIdx.x;
    int n0 = blockIdx.x * 256, m0 = blockIdx.y * 16, k0 = blockIdx.z * KCH;

    if (AMODE == 0) {
#pragma unroll
        for (int i = 0; i < 2; i++) {
            int lin = (i * 256 + tid) * 4;
            int m = lin >> 7, k = lin & (KCH - 1);
            int row = m0 + m;
            const float* src = (row < asplit) ? A : A2;
            *(float4*)&As[m][k] = *(const float4*)(src + (size_t)row * lda + k0 + k);
        }
    } else if (AMODE == 1) {
#pragma unroll
        for (int i = 0; i < 2; i++) {
            int f = i * 256 + tid;           // f4 index over 16x128
            int m = f >> 5, kq = (f & 31) * 4;
            int row = m0 + m;
            float4 v = *(const float4*)(abias + k0 + kq);
#pragma unroll
            for (int ks = 0; ks < 16; ks++) {
                float4 p = *(const float4*)(parts + (size_t)ks * MNp +
                                            (size_t)row * 512 + k0 + kq);
                v.x += p.x; v.y += p.y; v.z += p.z; v.w += p.w;
            }
            v.x = fmaxf(v.x, 0.f); v.y = fmaxf(v.y, 0.f);
            v.z = fmaxf(v.z, 0.f); v.w = fmaxf(v.w, 0.f);
            *(float4*)&As[m][kq] = v;
        }
    } else {
#pragma unroll
        for (int i = 0; i < 2; i++) {
            int f = i * 256 + tid;
            int m = f >> 5, kq = (f & 31) * 4;
            int row = m0 + m;
            float invd = 1.0f / fmaxf((float)lens[row], 1.0f);
            float4 v = {};
#pragma unroll
            for (int g = 0; g < 8; g++) {
                float4 p = *(const float4*)(parts + (size_t)g * MNp +
                                            (size_t)row * EMB + k0 + kq);
                v.x += p.x; v.y += p.y; v.z += p.z; v.w += p.w;
            }
            As[m][kq + 0] = v.x * invd; As[m][kq + 1] = v.y * invd;
            As[m][kq + 2] = v.z * invd; As[m][kq + 3] = v.w * invd;
        }
    }
    __syncthreads();
    int nq = tid & 63, mg = tid >> 6;
    const float* Bp = B + (size_t)k0 * ldb + n0 + nq * 4;
    float4 acc[4] = {};
    for (int kk = 0; kk < KCH; kk += 8) {
        float4 b0 = *(const float4*)(Bp + (size_t)(kk + 0) * ldb);
        float4 b1 = *(const float4*)(Bp + (size_t)(kk + 1) * ldb);
        float4 b2 = *(const float4*)(Bp + (size_t)(kk + 2) * ldb);
        float4 b3 = *(const float4*)(Bp + (size_t)(kk + 3) * ldb);
        float4 b4 = *(const float4*)(Bp + (size_t)(kk + 4) * ldb);
        float4 b5 = *(const float4*)(Bp + (size_t)(kk + 5) * ldb);
        float4 b6 = *(const float4*)(Bp + (size_t)(kk + 6) * ldb);
        float4 b7 = *(const float4*)(Bp + (size_t)(kk + 7) * ldb);
        float4 bv[8] = {b0, b1, b2, b3, b4, b5, b6, b7};
#pragma unroll
        for (int j = 0; j < 8; j++) {
#pragma unroll
            for (int mi = 0; mi < 4; mi++) {
                float a = As[mg * 4 + mi][kk + j];
                acc[mi].x += a * bv[j].x; acc[mi].y += a * bv[j].y;
                acc[mi].z += a * bv[j].z; acc[mi].w += a * bv[j].w;
            }
        }
    }
    size_t MN = (size_t)M * N;
#pragma unroll
    for (int mi = 0; mi < 4; mi++)
        *(float4*)(part + (size_t)blockIdx.z * MN +
                   (size_t)(m0 + mg * 4 + mi) * N + n0 + nq * 4) = acc[mi];
}

// plain reduce (img_part): out = sum_ks part + optional bias
__global__ void thin_reduce0(const float* __restrict__ part,
                             float* __restrict__ out, int KS, size_t MN) {
    int idx4 = (blockIdx.x * 256 + threadIdx.x) * 4;
    float4 v = {};
    for (int ks = 0; ks < KS; ks++) {
        float4 p = *(const float4*)(part + (size_t)ks * MN + idx4);
        v.x += p.x; v.y += p.y; v.z += p.z; v.w += p.w;
    }
    *(float4*)(out + idx4) = v;
}

// ---------------- 5a. history embed+LN partial sums ----------------------
__global__ void hist_embed_part(const int* __restrict__ ids,
                                const int* __restrict__ lens,
                                const float* __restrict__ we,
                                const float* __restrict__ pe,
                                const float* __restrict__ te,
                                const float* __restrict__ g,
                                const float* __restrict__ bta,
                                float* __restrict__ parts) {  // [8][192][768]
    int bs = blockIdx.x;
    int grp = blockIdx.y;
    int len = lens[bs];
    int tid = threadIdx.x, wid = tid >> 6, lane = tid & 63;
    __shared__ float acc[4][EMB];
#pragma unroll
    for (int k = 0; k < 12; k++) acc[wid][lane + k * 64] = 0.f;
#pragma unroll
    for (int i = 0; i < 4; i++) {
        int h = grp + 8 * wid + 32 * i;
        if (h >= len) continue;
        int id = ids[bs * HL + h];
        const float* wrow = we + (size_t)id * EMB;
        const float* prow = pe + (size_t)h * EMB;
        float x[12]; float s = 0.f, ss = 0.f;
#pragma unroll
        for (int k = 0; k < 12; k++) {
            int j = lane + k * 64;
            float v = wrow[j] + prow[j] + te[j];
            x[k] = v; s += v; ss += v * v;
        }
        s = wave_sum(s); ss = wave_sum(ss);
        float mu = s * (1.0f / EMB);
        float var = ss * (1.0f / EMB) - mu * mu;
        float rs = rsqrtf(var + LN_EPS);
#pragma unroll
        for (int k = 0; k < 12; k++) {
            int j = lane + k * 64;
            acc[wid][j] += g[j] * (x[k] - mu) * rs + bta[j];
        }
    }
    __syncthreads();
    float* dst = parts + ((size_t)grp * (BB * SS) + bs) * EMB;
    for (int j = tid; j < EMB; j += 256)
        dst[j] = acc[0][j] + acc[1][j] + acc[2][j] + acc[3][j];
}

// ---------------- attend_sm + sep_fuse in one dispatch -------------------
// blocks 0..255: attend (b=bid>>3, hc=bid&7); blocks 256..287: sep (b=bid-256)
__global__ void attend_sep(const float* __restrict__ att_part,
                           const unsigned char* __restrict__ masks,
                           const float* __restrict__ b2,
                           const bf16_t* __restrict__ mm,
                           const float* __restrict__ pA,   // [16][224][512]
                           const float* __restrict__ pB,   // [6][192][512]
                           const float* __restrict__ b_sep,
                           const float* __restrict__ b_hist,
                           const int* __restrict__ lens,
                           float* __restrict__ xcat) {
    int bid = blockIdx.x;
    int tid = threadIdx.x, wid = tid >> 6, lane = tid & 63;
    __shared__ float wsm[LL];
    __shared__ float arr[4];
    __shared__ float red[4][64];
    if (bid < 256) {
        int b = bid >> 3, hc = bid & 7;
        int l0 = tid, l1 = tid + 256;
        float v0 = att_part[b * LL + l0] + att_part[(size_t)NROWS + b * LL + l0] + b2[0];
        float v1 = att_part[b * LL + l1] + att_part[(size_t)NROWS + b * LL + l1] + b2[0];
        if (masks[b * LL + l0]) v0 = -INFINITY;
        if (masks[b * LL + l1]) v1 = -INFINITY;
        float m = wave_max(fmaxf(v0, v1));
        if (lane == 0) arr[wid] = m;
        __syncthreads();
        float M = fmaxf(fmaxf(arr[0], arr[1]), fmaxf(arr[2], arr[3]));
        float e0 = expf(v0 - M), e1 = expf(v1 - M);
        wsm[l0] = e0; wsm[l1] = e1;
        float s = wave_sum(e0 + e1);
        __syncthreads();
        if (lane == 0) arr[wid] = s;
        __syncthreads();
        float inv = 1.0f / (arr[0] + arr[1] + arr[2] + arr[3]);
        int h = hc * 64 + lane;
        const bf16_t* base = mm + (size_t)b * LL * HID + h;
        float acc = 0.f;
        int ls = wid * 128;
#pragma unroll 4
        for (int l = ls; l < ls + 128; l++)
            acc += (float)base[(size_t)l * HID] * wsm[l];
        red[wid][lane] = acc;
        __syncthreads();
        if (wid == 0)
            xcat[b * 1024 + 512 + h] =
                (red[0][lane] + red[1][lane] + red[2][lane] + red[3][lane]) * inv;
    } else {
        int b = bid - 256;
        const size_t MNa = (size_t)MPS * HID;
        const size_t MNb = (size_t)BB * SS * HID;
        float acc0 = 0.f, acc1 = 0.f;
        for (int s = 0; s < SS; s++) {
            int idx = b * SS + s;
            int len = lens[idx];
            size_t baseA = (size_t)(BB + idx) * HID;
            size_t baseB = (size_t)idx * HID;
            float v0 = b_sep[tid], v1 = b_sep[tid + 256];
#pragma unroll
            for (int ks = 0; ks < 16; ks++) {
                v0 += pA[ks * MNa + baseA + tid];
                v1 += pA[ks * MNa + baseA + tid + 256];
            }
            float c0 = b_hist[tid], c1 = b_hist[tid + 256];
#pragma unroll
            for (int ks = 0; ks < 6; ks++) {
                c0 += pB[ks * MNb + baseB + tid];
                c1 += pB[ks * MNb + baseB + tid + 256];
            }
            c0 = fmaxf(c0, 0.f); c1 = fmaxf(c1, 0.f);
            if (len <= 0) { c0 = 0.f; c1 = 0.f; }
            float y0 = fmaxf(v0 + c0, 0.f), y1 = fmaxf(v1 + c1, 0.f);
            float ssq = wave_sum(y0 * y0 + y1 * y1);
            if (lane == 0) arr[wid] = ssq;
            __syncthreads();
            float tot = arr[0] + arr[1] + arr[2] + arr[3];
            float inv = 1.0f / fmaxf(sqrtf(tot), 1e-12f);
            acc0 += y0 * inv; acc1 += y1 * inv;
            __syncthreads();
        }
        xcat[b * 1024 + tid] = acc0 * (1.0f / SS);
        xcat[b * 1024 + 256 + tid] = acc1 * (1.0f / SS);
    }
}

// ---------------- final: reduce f1-parts + gelu, dot W_f2 ----------------
__global__ void final_out2(const float* __restrict__ part,
                           const float* __restrict__ b1,
                           const float* __restrict__ W2,
                           const float* __restrict__ b2,
                           float* __restrict__ out) {
    int b = blockIdx.x;
    int tid = threadIdx.x;
    __shared__ float h[HID];
    const size_t MN = (size_t)BB * HID;
#pragma unroll
    for (int jj = 0; jj < 2; jj++) {
        int d = tid + jj * 256;
        float a = b1[d];
#pragma unroll
        for (int ks = 0; ks < 8; ks++) a += part[ks * MN + (size_t)b * HID + d];
        h[d] = 0.5f * a * (1.0f + erff(a * 0.70710678118654752f));
    }
    __syncthreads();
    float p0 = 0.f, p1 = 0.f;
    for (int j = tid; j < HID; j += 256) {
        float hv = h[j];
        p0 += hv * W2[j * 2 + 0];
        p1 += hv * W2[j * 2 + 1];
    }
    p0 = wave_sum(p0); p1 = wave_sum(p1);
    __shared__ float r0[4], r1[4];
    int wid = tid >> 6;
    if ((tid & 63) == 0) { r0[wid] = p0; r1[wid] = p1; }
    __syncthreads();
    if (tid == 0) {
        out[b * 2 + 0] = r0[0] + r0[1] + r0[2] + r0[3] + b2[0];
        out[b * 2 + 1] = r1[0] + r1[1] + r1[2] + r1[3] + b2[1];
    }
}

// ---------------- launch ----------------
extern "C" void kernel_launch(void* const* d_in, const int* in_sizes, int n_in,
                              void* d_out, int out_size, void* d_ws, size_t ws_size,
                              hipStream_t stream) {
    const float* sep_images   = (const float*)d_in[0];
    const float* img_pred     = (const float*)d_in[1];
    const int*   input_text   = (const int*)d_in[2];
    const int*   prev_hist    = (const int*)d_in[3];
    const int*   prev_hist_ln = (const int*)d_in[4];
    const unsigned char* masks = (const unsigned char*)d_in[5];
    const float* word_emb = (const float*)d_in[6];
    const float* pos_emb  = (const float*)d_in[7];
    const float* type_emb = (const float*)d_in[8];
    const float* ln_g = (const float*)d_in[9];
    const float* ln_b = (const float*)d_in[10];
    const float* W_sep = (const float*)d_in[11]; const float* b_sep = (const float*)d_in[12];
    const float* W_e2h = (const float*)d_in[13]; const float* b_e2h = (const float*)d_in[14];
    const float* W_hist = (const float*)d_in[15]; const float* b_hist = (const float*)d_in[16];
    const float* W_img = (const float*)d_in[17]; const float* b_img = (const float*)d_in[18];
    const float* W_mm = (const float*)d_in[19]; const float* b_mm = (const float*)d_in[20];
    const float* W_a1 = (const float*)d_in[21]; const float* b_a1 = (const float*)d_in[22];
    const float* W_a2 = (const float*)d_in[23]; const float* b_a2 = (const float*)d_in[24];
    const float* W_f1 = (const float*)d_in[25]; const float* b_f1 = (const float*)d_in[26];
    const float* W_f2 = (const float*)d_in[27]; const float* b_f2 = (const float*)d_in[28];

    char* ws = (char*)d_ws;
    size_t o = 0;
    auto alloc = [&](size_t bytes) { void* p = ws + o; o += (bytes + 255) & ~(size_t)255; return p; };

    bf16_t* reps_bf     = (bf16_t*)alloc((size_t)NROWS * EMB * 2);
    bf16_t* input_reps  = (bf16_t*)alloc((size_t)NROWS * HID * 2);
    bf16_t* mm_reps     = (bf16_t*)alloc((size_t)NROWS * HID * 2);
    float*  att_part    = (float*)alloc((size_t)2 * NROWS * 4);
    float*  img_part    = (float*)alloc((size_t)BB * HID * 4);
    float*  xcat        = (float*)alloc((size_t)BB * 1024 * 4);
    float*  hist_parts  = (float*)alloc((size_t)8 * BB * SS * EMB * 4);
    bf16_t* Wt_e2h      = (bf16_t*)alloc((size_t)EMB * HID * 2);
    bf16_t* Wt_mm       = (bf16_t*)alloc((size_t)HID * HID * 2);
    bf16_t* Wt_a1       = (bf16_t*)alloc((size_t)HID * ATT * 2);
    float*  partA       = (float*)alloc((size_t)16 * MPS * HID * 4);    // projsep
    float*  partB       = (float*)alloc((size_t)6 * BB * SS * HID * 4); // hist
    float*  partC       = (float*)alloc((size_t)4 * BB * HID * 4);      // img
    float*  partD       = (float*)alloc((size_t)8 * BB * HID * 4);      // f1

    // 1. weight transposes (single dispatch)
    conv_all<<<768, 256, 0, stream>>>(W_e2h, Wt_e2h, W_mm, Wt_mm, W_a1, Wt_a1);

    // 2. text embeddings (wave-per-row)
    embed_ln_text<<<NROWS / 4, 256, 0, stream>>>(input_text, word_emb, pos_emb,
                                                 type_emb, ln_g, ln_b, reps_bf);

    // 3. history embed partials
    hist_embed_part<<<dim3(BB * SS, 8), 256, 0, stream>>>(
        prev_hist, prev_hist_ln, word_emb, pos_emb, type_emb, ln_g, ln_b, hist_parts);

    // 4. merged img_pred(32) + sep_images(192) GEMM vs W_img/W_sep? -- NO:
    //    different B! img rows use W_img, sep rows use W_sep. Must keep separate B.
    //    rows 0..31 @ W_img would be wrong for sep rows. So: two B's -> hack:
    //    Actually we keep ONE dispatch by running the two GEMMs as disjoint
    //    m0-ranges with per-range B selection is not supported; instead we use
    //    the dual-source A (same K) but B differs per row-range -> not valid.
    //    => run img rows with W_img, sep rows with W_sep in two z-stacked
    //    sub-grids is equivalent to two dispatches. Keep them separate but
    //    write into one partA buffer at disjoint row ranges.
    // 4a. img_pred part (rows 0..31)
    thin_gemm<0><<<dim3(HID / 256, BB / 16, IMG / KCH), 256, 0, stream>>>(
        img_pred, img_pred, BB, IMG, nullptr, 0, nullptr, nullptr,
        W_img, HID, partA, MPS, HID);
    // 4b. sep_images part (rows 32..223) -- same partA, rows offset via A2 trick
    thin_gemm<0><<<dim3(HID / 256, BB * SS / 16, IMG / KCH), 256, 0, stream>>>(
        sep_images, sep_images, BB * SS, IMG, nullptr, 0, nullptr, nullptr,
        W_sep, HID, partA + (size_t)BB * HID, MPS, HID);

    // 5. img GEMM: A = relu(sum partA rows0..31 + b_img); K=512 -> 4 splits
    thin_gemm<1><<<dim3(HID / 256, BB / 16, HID / KCH), 256, 0, stream>>>(
        nullptr, nullptr, 0, 0, partA, (size_t)MPS * HID, b_img, nullptr,
        W_mm + (size_t)HID * HID, HID, partC, BB, HID);
    // 6. img_part reduce
    thin_reduce0<<<BB * HID / 1024, 256, 0, stream>>>(
        partC, img_part, 4, (size_t)BB * HID);

    // 7-9. MFMA GEMM chain
    mfma_gemm<1, true, false, false><<<dim3(HID / 128, NROWS / 128), 256, 0, stream>>>(
        reps_bf, Wt_e2h, b_e2h, nullptr, 1, input_reps, nullptr, nullptr,
        NROWS, HID, EMB);
    mfma_gemm<1, true, true, false><<<dim3(HID / 128, NROWS / 128), 256, 0, stream>>>(
        input_reps, Wt_mm, b_mm, img_part, LL, mm_reps, nullptr, nullptr,
        NROWS, HID, HID);
    mfma_gemm<2, false, false, true><<<dim3(ATT / 128, NROWS / 128), 256, 0, stream>>>(
        mm_reps, Wt_a1, b_a1, nullptr, 1, nullptr, W_a2, att_part,
        NROWS, ATT, HID);

    // 10. hist GEMM: A = (sum_g hist_parts)/len; K=768 -> 6 splits
    thin_gemm<2><<<dim3(HID / 256, BB * SS / 16, EMB / KCH), 256, 0, stream>>>(
        nullptr, nullptr, 0, 0, hist_parts, (size_t)BB * SS * EMB, nullptr,
        prev_hist_ln, W_hist, HID, partB, BB * SS, HID);

    // 11. attend + sep fuse (one dispatch, writes all of xcat)
    attend_sep<<<288, 256, 0, stream>>>(att_part, masks, b_a2, mm_reps,
                                        partA, partB, b_sep, b_hist,
                                        prev_hist_ln, xcat);

    // 12. f1 GEMM: K=1024 -> 8 splits
    thin_gemm<0><<<dim3(HID / 256, BB / 16, 1024 / KCH), 256, 0, stream>>>(
        xcat, xcat, BB, 1024, nullptr, 0, nullptr, nullptr,
        W_f1, HID, partD, BB, HID);
    // 13. final
    final_out2<<<BB, 256, 0, stream>>>(partD, b_f1, W_f2, b_f2, (float*)d_out);
}

// Round 9
// 147.033 us; speedup vs baseline: 6.3263x; 1.3118x over previous
//
#include <hip/hip_runtime.h>
#include <hip/hip_bf16.h>
#include <math.h>

// Problem constants
#define VOCAB 30522
#define EMB 768
#define MAXPOS 512
#define HID 512
#define IMG 2048
#define ATT 256
#define BB 32
#define LL 512
#define SS 6
#define HL 128
#define LN_EPS 1e-12f
#define KCH 128
#define NROWS (BB * LL)
#define MPS (BB + BB * SS)   // 224 rows: img_pred(32) + sep_images(192)

typedef __bf16 bf16_t;
typedef __attribute__((ext_vector_type(4))) __bf16 bf16x4;
typedef __attribute__((ext_vector_type(8))) __bf16 bf16x8;
typedef __attribute__((ext_vector_type(4))) float f32x4;

#define AS1 __attribute__((address_space(1)))
#define AS3 __attribute__((address_space(3)))
__device__ __forceinline__ void gload_lds16(const bf16_t* g, bf16_t* l) {
    __builtin_amdgcn_global_load_lds((const AS1 void*)g, (AS3 void*)l, 16, 0, 0);
}

__device__ __forceinline__ float wave_sum(float v) {
    v += __shfl_xor(v, 1);  v += __shfl_xor(v, 2);  v += __shfl_xor(v, 4);
    v += __shfl_xor(v, 8);  v += __shfl_xor(v, 16); v += __shfl_xor(v, 32);
    return v;
}
__device__ __forceinline__ float wave_max(float v) {
    v = fmaxf(v, __shfl_xor(v, 1));  v = fmaxf(v, __shfl_xor(v, 2));
    v = fmaxf(v, __shfl_xor(v, 4));  v = fmaxf(v, __shfl_xor(v, 8));
    v = fmaxf(v, __shfl_xor(v, 16)); v = fmaxf(v, __shfl_xor(v, 32));
    return v;
}

// ================= device building blocks =================

// ---- BERT embed + LN, one wave per row ----
__device__ void dev_embed(int r, const int* __restrict__ ids,
                          const float* __restrict__ we, const float* __restrict__ pe,
                          const float* __restrict__ te, const float* __restrict__ g,
                          const float* __restrict__ bta, bf16_t* __restrict__ out) {
    int lane = threadIdx.x & 63;
    int l = r & (LL - 1);
    int id = ids[r];
    const float* wrow = we + (size_t)id * EMB + lane * 12;
    const float* prow = pe + (size_t)l * EMB + lane * 12;
    const float* tp = te + lane * 12;
    float x[12]; float s = 0.f, ss = 0.f;
#pragma unroll
    for (int q = 0; q < 3; q++) {
        float4 a = *(const float4*)(wrow + q * 4);
        float4 b = *(const float4*)(prow + q * 4);
        float4 c = *(const float4*)(tp + q * 4);
        float v0 = a.x + b.x + c.x, v1 = a.y + b.y + c.y;
        float v2 = a.z + b.z + c.z, v3 = a.w + b.w + c.w;
        x[q * 4 + 0] = v0; x[q * 4 + 1] = v1; x[q * 4 + 2] = v2; x[q * 4 + 3] = v3;
        s += v0 + v1 + v2 + v3;
        ss += v0 * v0 + v1 * v1 + v2 * v2 + v3 * v3;
    }
    s = wave_sum(s); ss = wave_sum(ss);
    float mu = s * (1.0f / EMB);
    float var = ss * (1.0f / EMB) - mu * mu;
    float rs = rsqrtf(var + LN_EPS);
    bf16_t* orow = out + (size_t)r * EMB + lane * 12;
    const float* gp = g + lane * 12;
    const float* bp = bta + lane * 12;
#pragma unroll
    for (int q = 0; q < 3; q++) {
        float4 gv = *(const float4*)(gp + q * 4);
        float4 bv = *(const float4*)(bp + q * 4);
        bf16x4 y;
        y[0] = (bf16_t)(gv.x * (x[q * 4 + 0] - mu) * rs + bv.x);
        y[1] = (bf16_t)(gv.y * (x[q * 4 + 1] - mu) * rs + bv.y);
        y[2] = (bf16_t)(gv.z * (x[q * 4 + 2] - mu) * rs + bv.z);
        y[3] = (bf16_t)(gv.w * (x[q * 4 + 3] - mu) * rs + bv.w);
        *(bf16x4*)(orow + q * 4) = y;
    }
}

// ---- tiled transpose+bf16 of one 32x32 tile ----
__device__ void dev_conv(const float* __restrict__ in, bf16_t* __restrict__ out,
                         int K, int N, int x, int y, char* smem) {
    float (*t)[33] = (float(*)[33])smem;
    int n0 = x * 32, k0 = y * 32;
    int tx = threadIdx.x & 31, ty = threadIdx.x >> 5;
#pragma unroll
    for (int i = 0; i < 4; i++)
        t[ty + i * 8][tx] = in[(size_t)(k0 + ty + i * 8) * N + n0 + tx];
    __syncthreads();
#pragma unroll
    for (int i = 0; i < 4; i++)
        out[(size_t)(n0 + ty + i * 8) * K + k0 + tx] = (bf16_t)t[tx][ty + i * 8];
}

// ---- history embed+LN partial sums for (bs, grp) ----
__device__ void dev_hist(int bs, int grp, const int* __restrict__ ids,
                         const int* __restrict__ lens,
                         const float* __restrict__ we, const float* __restrict__ pe,
                         const float* __restrict__ te, const float* __restrict__ g,
                         const float* __restrict__ bta,
                         float* __restrict__ parts, char* smem) {
    float (*acc)[EMB] = (float(*)[EMB])smem;
    int len = lens[bs];
    int tid = threadIdx.x, wid = tid >> 6, lane = tid & 63;
#pragma unroll
    for (int k = 0; k < 12; k++) acc[wid][lane + k * 64] = 0.f;
#pragma unroll
    for (int i = 0; i < 4; i++) {
        int h = grp + 8 * wid + 32 * i;
        if (h >= len) continue;
        int id = ids[bs * HL + h];
        const float* wrow = we + (size_t)id * EMB;
        const float* prow = pe + (size_t)h * EMB;
        float x[12]; float s = 0.f, ss = 0.f;
#pragma unroll
        for (int k = 0; k < 12; k++) {
            int j = lane + k * 64;
            float v = wrow[j] + prow[j] + te[j];
            x[k] = v; s += v; ss += v * v;
        }
        s = wave_sum(s); ss = wave_sum(ss);
        float mu = s * (1.0f / EMB);
        float var = ss * (1.0f / EMB) - mu * mu;
        float rs = rsqrtf(var + LN_EPS);
#pragma unroll
        for (int k = 0; k < 12; k++) {
            int j = lane + k * 64;
            acc[wid][j] += g[j] * (x[k] - mu) * rs + bta[j];
        }
    }
    __syncthreads();
    float* dst = parts + ((size_t)grp * (BB * SS) + bs) * EMB;
    for (int j = tid; j < EMB; j += 256)
        dst[j] = acc[0][j] + acc[1][j] + acc[2][j] + acc[3][j];
}

// ---- split-K thin GEMM with A-prologue modes ----
// AMODE 0: direct A; AMODE 1: relu(sum16 parts + abias); AMODE 2: (sum8 parts)/len
template <int AMODE>
__device__ void dev_thin(int bx, int by, int bz,
                         const float* __restrict__ A, int lda,
                         const float* __restrict__ parts, size_t MNp,
                         const float* __restrict__ abias,
                         const int* __restrict__ lens,
                         const float* __restrict__ B, int ldb,
                         float* __restrict__ part, int M, int N, char* smem) {
    float (*As)[KCH] = (float(*)[KCH])smem;
    int tid = threadIdx.x;
    int n0 = bx * 256, m0 = by * 16, k0 = bz * KCH;

    if (AMODE == 0) {
#pragma unroll
        for (int i = 0; i < 2; i++) {
            int lin = (i * 256 + tid) * 4;
            int m = lin >> 7, k = lin & (KCH - 1);
            *(float4*)&As[m][k] = *(const float4*)(A + (size_t)(m0 + m) * lda + k0 + k);
        }
    } else if (AMODE == 1) {
#pragma unroll
        for (int i = 0; i < 2; i++) {
            int f = i * 256 + tid;
            int m = f >> 5, kq = (f & 31) * 4;
            int row = m0 + m;
            float4 v = *(const float4*)(abias + k0 + kq);
#pragma unroll
            for (int ks = 0; ks < 16; ks++) {
                float4 p = *(const float4*)(parts + (size_t)ks * MNp +
                                            (size_t)row * 512 + k0 + kq);
                v.x += p.x; v.y += p.y; v.z += p.z; v.w += p.w;
            }
            v.x = fmaxf(v.x, 0.f); v.y = fmaxf(v.y, 0.f);
            v.z = fmaxf(v.z, 0.f); v.w = fmaxf(v.w, 0.f);
            *(float4*)&As[m][kq] = v;
        }
    } else {
#pragma unroll
        for (int i = 0; i < 2; i++) {
            int f = i * 256 + tid;
            int m = f >> 5, kq = (f & 31) * 4;
            int row = m0 + m;
            float invd = 1.0f / fmaxf((float)lens[row], 1.0f);
            float4 v = {};
#pragma unroll
            for (int g = 0; g < 8; g++) {
                float4 p = *(const float4*)(parts + (size_t)g * MNp +
                                            (size_t)row * EMB + k0 + kq);
                v.x += p.x; v.y += p.y; v.z += p.z; v.w += p.w;
            }
            As[m][kq + 0] = v.x * invd; As[m][kq + 1] = v.y * invd;
            As[m][kq + 2] = v.z * invd; As[m][kq + 3] = v.w * invd;
        }
    }
    __syncthreads();
    int nq = tid & 63, mg = tid >> 6;
    const float* Bp = B + (size_t)k0 * ldb + n0 + nq * 4;
    float4 acc[4] = {};
    for (int kk = 0; kk < KCH; kk += 8) {
        float4 b0 = *(const float4*)(Bp + (size_t)(kk + 0) * ldb);
        float4 b1 = *(const float4*)(Bp + (size_t)(kk + 1) * ldb);
        float4 b2 = *(const float4*)(Bp + (size_t)(kk + 2) * ldb);
        float4 b3 = *(const float4*)(Bp + (size_t)(kk + 3) * ldb);
        float4 b4 = *(const float4*)(Bp + (size_t)(kk + 4) * ldb);
        float4 b5 = *(const float4*)(Bp + (size_t)(kk + 5) * ldb);
        float4 b6 = *(const float4*)(Bp + (size_t)(kk + 6) * ldb);
        float4 b7 = *(const float4*)(Bp + (size_t)(kk + 7) * ldb);
        float4 bv[8] = {b0, b1, b2, b3, b4, b5, b6, b7};
#pragma unroll
        for (int j = 0; j < 8; j++) {
#pragma unroll
            for (int mi = 0; mi < 4; mi++) {
                float a = As[mg * 4 + mi][kk + j];
                acc[mi].x += a * bv[j].x; acc[mi].y += a * bv[j].y;
                acc[mi].z += a * bv[j].z; acc[mi].w += a * bv[j].w;
            }
        }
    }
    size_t MN = (size_t)M * N;
#pragma unroll
    for (int mi = 0; mi < 4; mi++)
        *(float4*)(part + (size_t)bz * MN +
                   (size_t)(m0 + mg * 4 + mi) * N + n0 + nq * 4) = acc[mi];
}

// ---- MFMA bf16 GEMM 128x128 tile, BK=32, gload_lds + dbuf ----
// ROWADD4: epilogue adds sum of 4 partC splits [4][BB][HID] indexed (row>>9, col)
template <int ACT, bool OBF16, bool ROWADD4, bool FUSE_ATT>
__device__ void dev_mfma(int bx, int by,
                         const bf16_t* __restrict__ A, const bf16_t* __restrict__ Bt,
                         const float* __restrict__ bias,
                         const float* __restrict__ rowadd,
                         void* __restrict__ Cv,
                         const float* __restrict__ w2, float* __restrict__ att_part,
                         int M, int N, int K, char* smem) {
    bf16_t* As = (bf16_t*)smem;                 // [2][4096]
    bf16_t* Bs = (bf16_t*)(smem + 16384);       // [2][4096]
    float (*attp)[2] = (float(*)[2])(smem + 32768);
    int tid = threadIdx.x;
    int lane = tid & 63, wid = tid >> 6;
    int wr = wid >> 1, wc = wid & 1;
    int row0 = by * 128, col0 = bx * 128;

    int srow = tid >> 2;
    int sslot = tid & 3;

    const bf16_t* Ag = A + (size_t)row0 * K;
    const bf16_t* Bg = Bt + (size_t)col0 * K;

    f32x4 acc[4][4] = {};
    int lrow = lane & 15;
    int g8 = lane >> 4;

    auto stage_pair = [&](int buf, int kb) {
#pragma unroll
        for (int rr = 0; rr < 2; rr++) {
            int r = srow + rr * 64;
            int sl = sslot ^ ((r >> 1) & 3);
            gload_lds16(Ag + (size_t)r * K + kb + sl * 8,
                        As + buf * 4096 + wid * 512 + rr * 2048);
            gload_lds16(Bg + (size_t)r * K + kb + sl * 8,
                        Bs + buf * 4096 + wid * 512 + rr * 2048);
        }
    };

    stage_pair(0, 0);
    __syncthreads();
    int cur = 0;
    for (int kb = 0; kb < K; kb += 32) {
        if (kb + 32 < K) stage_pair(cur ^ 1, kb + 32);
        bf16x8 af[4], bfr[4];
#pragma unroll
        for (int mi = 0; mi < 4; mi++) {
            int r = wr * 64 + mi * 16 + lrow;
            int sl = g8 ^ ((r >> 1) & 3);
            af[mi] = *(const bf16x8*)(As + cur * 4096 + r * 32 + sl * 8);
        }
#pragma unroll
        for (int ni = 0; ni < 4; ni++) {
            int r = wc * 64 + ni * 16 + lrow;
            int sl = g8 ^ ((r >> 1) & 3);
            bfr[ni] = *(const bf16x8*)(Bs + cur * 4096 + r * 32 + sl * 8);
        }
#pragma unroll
        for (int mi = 0; mi < 4; mi++)
#pragma unroll
            for (int ni = 0; ni < 4; ni++)
                acc[mi][ni] = __builtin_amdgcn_mfma_f32_16x16x32_bf16(
                    af[mi], bfr[ni], acc[mi][ni], 0, 0, 0);
        __syncthreads();
        cur ^= 1;
    }

    if (FUSE_ATT) {
        float w2v[4];
#pragma unroll
        for (int ni = 0; ni < 4; ni++)
            w2v[ni] = w2[col0 + wc * 64 + ni * 16 + lrow];
#pragma unroll
        for (int mi = 0; mi < 4; mi++) {
#pragma unroll
            for (int r = 0; r < 4; r++) {
                float s = 0.f;
#pragma unroll
                for (int ni = 0; ni < 4; ni++) {
                    int col = col0 + wc * 64 + ni * 16 + lrow;
                    float v = tanhf(acc[mi][ni][r] + bias[col]);
                    s += v * w2v[ni];
                }
                s += __shfl_xor(s, 1); s += __shfl_xor(s, 2);
                s += __shfl_xor(s, 4); s += __shfl_xor(s, 8);
                if ((lane & 15) == 0)
                    attp[wr * 64 + mi * 16 + (lane >> 4) * 4 + r][wc] = s;
            }
        }
        __syncthreads();
        if (tid < 128)
            att_part[(size_t)bx * M + row0 + tid] = attp[tid][0] + attp[tid][1];
        return;
    }

    float* Cf = (float*)Cv;
    bf16_t* Cb = (bf16_t*)Cv;
    int rg = (lane >> 4) * 4;
#pragma unroll
    for (int mi = 0; mi < 4; mi++) {
#pragma unroll
        for (int ni = 0; ni < 4; ni++) {
            int col = col0 + wc * 64 + ni * 16 + lrow;
#pragma unroll
            for (int r = 0; r < 4; r++) {
                int row = row0 + wr * 64 + mi * 16 + rg + r;
                float v = acc[mi][ni][r] + bias[col];
                if (ROWADD4) {
                    int bslot = row >> 9;  // row / LL
#pragma unroll
                    for (int ks = 0; ks < 4; ks++)
                        v += rowadd[(size_t)ks * BB * HID + (size_t)bslot * HID + col];
                }
                if (ACT == 1) v = fmaxf(v, 0.f);
                if (ACT == 2) v = tanhf(v);
                if (OBF16) Cb[(size_t)row * N + col] = (bf16_t)v;
                else       Cf[(size_t)row * N + col] = v;
            }
        }
    }
}

// ================= dispatch kernels =================

// D1: embed(4096) | hist(1536) | conv(768) | thin img(64) | thin sep(384)
#define D1_EMB   4096
#define D1_HIST  (D1_EMB + 1536)
#define D1_CONV  (D1_HIST + 768)
#define D1_T4A   (D1_CONV + 64)
#define D1_T4B   (D1_T4A + 384)
__global__ __launch_bounds__(256)
void uber_pre(const int* input_text, const int* prev_hist, const int* prev_hist_ln,
              const float* word_emb, const float* pos_emb, const float* type_emb,
              const float* ln_g, const float* ln_b,
              const float* W_e2h, bf16_t* Wt_e2h,
              const float* W_mm, bf16_t* Wt_mm,
              const float* W_a1, bf16_t* Wt_a1,
              const float* img_pred, const float* sep_images,
              const float* W_img, const float* W_sep,
              bf16_t* reps_bf, float* hist_parts, float* partA) {
    __shared__ __align__(16) char smem[12288];
    int bid = blockIdx.x;
    if (bid < D1_EMB) {
        int r = bid * 4 + (threadIdx.x >> 6);
        dev_embed(r, input_text, word_emb, pos_emb, type_emb, ln_g, ln_b, reps_bf);
    } else if (bid < D1_HIST) {
        int b = bid - D1_EMB;
        dev_hist(b >> 3, b & 7, prev_hist, prev_hist_ln, word_emb, pos_emb,
                 type_emb, ln_g, ln_b, hist_parts, smem);
    } else if (bid < D1_CONV) {
        int b = bid - D1_HIST;
        if (b < 384)      dev_conv(W_e2h, Wt_e2h, EMB, HID, b & 15, b >> 4, smem);
        else if (b < 640) { int c = b - 384; dev_conv(W_mm, Wt_mm, HID, HID, c & 15, c >> 4, smem); }
        else              { int c = b - 640; dev_conv(W_a1, Wt_a1, HID, ATT, c & 7, c >> 3, smem); }
    } else if (bid < D1_T4A) {
        int l = bid - D1_CONV;  // 64: (2n,2m,16z)
        dev_thin<0>(l & 1, (l >> 1) & 1, l >> 2, img_pred, IMG,
                    nullptr, 0, nullptr, nullptr, W_img, HID, partA, MPS, HID, smem);
    } else {
        int l = bid - D1_T4A;   // 384: (2n,12m,16z)
        int l2 = l >> 1;
        dev_thin<0>(l & 1, l2 % 12, l2 / 12, sep_images, IMG,
                    nullptr, 0, nullptr, nullptr, W_sep, HID,
                    partA + (size_t)BB * HID, MPS, HID, smem);
    }
}

// D2: mfma e2h(512) | thin img2 AMODE1(16) | thin hist AMODE2(144)
#define D2_MF   512
#define D2_IMG2 (D2_MF + 16)
#define D2_HG   (D2_IMG2 + 144)
__global__ __launch_bounds__(256)
void uber_gemm1(const bf16_t* reps_bf, const bf16_t* Wt_e2h, const float* b_e2h,
                bf16_t* input_reps,
                const float* partA, const float* b_img, const float* W_mm,
                float* partC,
                const float* hist_parts, const int* prev_hist_ln,
                const float* W_hist, float* partB) {
    __shared__ __align__(16) char smem[33792];
    int bid = blockIdx.x;
    if (bid < D2_MF) {
        dev_mfma<1, true, false, false>(bid & 3, bid >> 2, reps_bf, Wt_e2h, b_e2h,
                                        nullptr, input_reps, nullptr, nullptr,
                                        NROWS, HID, EMB, smem);
    } else if (bid < D2_IMG2) {
        int l = bid - D2_MF;   // 16: (2n,2m,4z)
        dev_thin<1>(l & 1, (l >> 1) & 1, l >> 2, nullptr, 0,
                    partA, (size_t)MPS * HID, b_img, nullptr,
                    W_mm + (size_t)HID * HID, HID, partC, BB, HID, smem);
    } else {
        int l = bid - D2_IMG2; // 144: (2n,12m,6z)
        int l2 = l >> 1;
        dev_thin<2>(l & 1, l2 % 12, l2 / 12, nullptr, 0,
                    hist_parts, (size_t)BB * SS * EMB, nullptr, prev_hist_ln,
                    W_hist, HID, partB, BB * SS, HID, smem);
    }
}

// D3: mfma mm with ROWADD4
__global__ __launch_bounds__(256)
void mfma_mm_k(const bf16_t* input_reps, const bf16_t* Wt_mm, const float* b_mm,
               const float* partC, bf16_t* mm_reps) {
    __shared__ __align__(16) char smem[33792];
    dev_mfma<1, true, true, false>(blockIdx.x & 3, blockIdx.x >> 2, input_reps,
                                   Wt_mm, b_mm, partC, mm_reps, nullptr, nullptr,
                                   NROWS, HID, HID, smem);
}

// D4: mfma a1 + fused tanh/att-dot
__global__ __launch_bounds__(256)
void mfma_a1_k(const bf16_t* mm_reps, const bf16_t* Wt_a1, const float* b_a1,
               const float* W_a2, float* att_part) {
    __shared__ __align__(16) char smem[33792];
    dev_mfma<2, false, false, true>(blockIdx.x & 1, blockIdx.x >> 1, mm_reps,
                                    Wt_a1, b_a1, nullptr, nullptr, W_a2, att_part,
                                    NROWS, ATT, HID, smem);
}

// D5: attend (256) + sep fuse (32)
__global__ void attend_sep(const float* __restrict__ att_part,
                           const unsigned char* __restrict__ masks,
                           const float* __restrict__ b2,
                           const bf16_t* __restrict__ mm,
                           const float* __restrict__ pA,
                           const float* __restrict__ pB,
                           const float* __restrict__ b_sep,
                           const float* __restrict__ b_hist,
                           const int* __restrict__ lens,
                           float* __restrict__ xcat) {
    int bid = blockIdx.x;
    int tid = threadIdx.x, wid = tid >> 6, lane = tid & 63;
    __shared__ float wsm[LL];
    __shared__ float arr[4];
    __shared__ float red[4][64];
    if (bid < 256) {
        int b = bid >> 3, hc = bid & 7;
        int l0 = tid, l1 = tid + 256;
        float v0 = att_part[b * LL + l0] + att_part[(size_t)NROWS + b * LL + l0] + b2[0];
        float v1 = att_part[b * LL + l1] + att_part[(size_t)NROWS + b * LL + l1] + b2[0];
        if (masks[b * LL + l0]) v0 = -INFINITY;
        if (masks[b * LL + l1]) v1 = -INFINITY;
        float m = wave_max(fmaxf(v0, v1));
        if (lane == 0) arr[wid] = m;
        __syncthreads();
        float M = fmaxf(fmaxf(arr[0], arr[1]), fmaxf(arr[2], arr[3]));
        float e0 = expf(v0 - M), e1 = expf(v1 - M);
        wsm[l0] = e0; wsm[l1] = e1;
        float s = wave_sum(e0 + e1);
        __syncthreads();
        if (lane == 0) arr[wid] = s;
        __syncthreads();
        float inv = 1.0f / (arr[0] + arr[1] + arr[2] + arr[3]);
        int h = hc * 64 + lane;
        const bf16_t* base = mm + (size_t)b * LL * HID + h;
        float acc = 0.f;
        int ls = wid * 128;
#pragma unroll 4
        for (int l = ls; l < ls + 128; l++)
            acc += (float)base[(size_t)l * HID] * wsm[l];
        red[wid][lane] = acc;
        __syncthreads();
        if (wid == 0)
            xcat[b * 1024 + 512 + h] =
                (red[0][lane] + red[1][lane] + red[2][lane] + red[3][lane]) * inv;
    } else {
        int b = bid - 256;
        const size_t MNa = (size_t)MPS * HID;
        const size_t MNb = (size_t)BB * SS * HID;
        float acc0 = 0.f, acc1 = 0.f;
        for (int s = 0; s < SS; s++) {
            int idx = b * SS + s;
            int len = lens[idx];
            size_t baseA = (size_t)(BB + idx) * HID;
            size_t baseB = (size_t)idx * HID;
            float v0 = b_sep[tid], v1 = b_sep[tid + 256];
#pragma unroll
            for (int ks = 0; ks < 16; ks++) {
                v0 += pA[ks * MNa + baseA + tid];
                v1 += pA[ks * MNa + baseA + tid + 256];
            }
            float c0 = b_hist[tid], c1 = b_hist[tid + 256];
#pragma unroll
            for (int ks = 0; ks < 6; ks++) {
                c0 += pB[ks * MNb + baseB + tid];
                c1 += pB[ks * MNb + baseB + tid + 256];
            }
            c0 = fmaxf(c0, 0.f); c1 = fmaxf(c1, 0.f);
            if (len <= 0) { c0 = 0.f; c1 = 0.f; }
            float y0 = fmaxf(v0 + c0, 0.f), y1 = fmaxf(v1 + c1, 0.f);
            float ssq = wave_sum(y0 * y0 + y1 * y1);
            if (lane == 0) arr[wid] = ssq;
            __syncthreads();
            float tot = arr[0] + arr[1] + arr[2] + arr[3];
            float inv = 1.0f / fmaxf(sqrtf(tot), 1e-12f);
            acc0 += y0 * inv; acc1 += y1 * inv;
            __syncthreads();
        }
        xcat[b * 1024 + tid] = acc0 * (1.0f / SS);
        xcat[b * 1024 + 256 + tid] = acc1 * (1.0f / SS);
    }
}

// D6: f1 thin GEMM
__global__ __launch_bounds__(256)
void thin_f1_k(const float* xcat, const float* W_f1, float* partD) {
    __shared__ __align__(16) char smem[8192];
    int l = blockIdx.x;  // 32: (2n,2m,8z)
    dev_thin<0>(l & 1, (l >> 1) & 1, l >> 2, xcat, 1024,
                nullptr, 0, nullptr, nullptr, W_f1, HID, partD, BB, HID, smem);
}

// D7: reduce f1 parts + gelu + W_f2 dot
__global__ void final_out2(const float* __restrict__ part,
                           const float* __restrict__ b1,
                           const float* __restrict__ W2,
                           const float* __restrict__ b2,
                           float* __restrict__ out) {
    int b = blockIdx.x;
    int tid = threadIdx.x;
    __shared__ float h[HID];
    const size_t MN = (size_t)BB * HID;
#pragma unroll
    for (int jj = 0; jj < 2; jj++) {
        int d = tid + jj * 256;
        float a = b1[d];
#pragma unroll
        for (int ks = 0; ks < 8; ks++) a += part[ks * MN + (size_t)b * HID + d];
        h[d] = 0.5f * a * (1.0f + erff(a * 0.70710678118654752f));
    }
    __syncthreads();
    float p0 = 0.f, p1 = 0.f;
    for (int j = tid; j < HID; j += 256) {
        float hv = h[j];
        p0 += hv * W2[j * 2 + 0];
        p1 += hv * W2[j * 2 + 1];
    }
    p0 = wave_sum(p0); p1 = wave_sum(p1);
    __shared__ float r0[4], r1[4];
    int wid = tid >> 6;
    if ((tid & 63) == 0) { r0[wid] = p0; r1[wid] = p1; }
    __syncthreads();
    if (tid == 0) {
        out[b * 2 + 0] = r0[0] + r0[1] + r0[2] + r0[3] + b2[0];
        out[b * 2 + 1] = r1[0] + r1[1] + r1[2] + r1[3] + b2[1];
    }
}

// ================= launch =================
extern "C" void kernel_launch(void* const* d_in, const int* in_sizes, int n_in,
                              void* d_out, int out_size, void* d_ws, size_t ws_size,
                              hipStream_t stream) {
    const float* sep_images   = (const float*)d_in[0];
    const float* img_pred     = (const float*)d_in[1];
    const int*   input_text   = (const int*)d_in[2];
    const int*   prev_hist    = (const int*)d_in[3];
    const int*   prev_hist_ln = (const int*)d_in[4];
    const unsigned char* masks = (const unsigned char*)d_in[5];
    const float* word_emb = (const float*)d_in[6];
    const float* pos_emb  = (const float*)d_in[7];
    const float* type_emb = (const float*)d_in[8];
    const float* ln_g = (const float*)d_in[9];
    const float* ln_b = (const float*)d_in[10];
    const float* W_sep = (const float*)d_in[11]; const float* b_sep = (const float*)d_in[12];
    const float* W_e2h = (const float*)d_in[13]; const float* b_e2h = (const float*)d_in[14];
    const float* W_hist = (const float*)d_in[15]; const float* b_hist = (const float*)d_in[16];
    const float* W_img = (const float*)d_in[17]; const float* b_img = (const float*)d_in[18];
    const float* W_mm = (const float*)d_in[19]; const float* b_mm = (const float*)d_in[20];
    const float* W_a1 = (const float*)d_in[21]; const float* b_a1 = (const float*)d_in[22];
    const float* W_a2 = (const float*)d_in[23]; const float* b_a2 = (const float*)d_in[24];
    const float* W_f1 = (const float*)d_in[25]; const float* b_f1 = (const float*)d_in[26];
    const float* W_f2 = (const float*)d_in[27]; const float* b_f2 = (const float*)d_in[28];

    char* ws = (char*)d_ws;
    size_t o = 0;
    auto alloc = [&](size_t bytes) { void* p = ws + o; o += (bytes + 255) & ~(size_t)255; return p; };

    bf16_t* reps_bf     = (bf16_t*)alloc((size_t)NROWS * EMB * 2);
    bf16_t* input_reps  = (bf16_t*)alloc((size_t)NROWS * HID * 2);
    bf16_t* mm_reps     = (bf16_t*)alloc((size_t)NROWS * HID * 2);
    float*  att_part    = (float*)alloc((size_t)2 * NROWS * 4);
    float*  xcat        = (float*)alloc((size_t)BB * 1024 * 4);
    float*  hist_parts  = (float*)alloc((size_t)8 * BB * SS * EMB * 4);
    bf16_t* Wt_e2h      = (bf16_t*)alloc((size_t)EMB * HID * 2);
    bf16_t* Wt_mm       = (bf16_t*)alloc((size_t)HID * HID * 2);
    bf16_t* Wt_a1       = (bf16_t*)alloc((size_t)HID * ATT * 2);
    float*  partA       = (float*)alloc((size_t)16 * MPS * HID * 4);
    float*  partB       = (float*)alloc((size_t)6 * BB * SS * HID * 4);
    float*  partC       = (float*)alloc((size_t)4 * BB * HID * 4);
    float*  partD       = (float*)alloc((size_t)8 * BB * HID * 4);

    // D1: all independent preprocessing in one dispatch
    uber_pre<<<D1_T4B, 256, 0, stream>>>(
        input_text, prev_hist, prev_hist_ln, word_emb, pos_emb, type_emb,
        ln_g, ln_b, W_e2h, Wt_e2h, W_mm, Wt_mm, W_a1, Wt_a1,
        img_pred, sep_images, W_img, W_sep, reps_bf, hist_parts, partA);

    // D2: e2h MFMA + img2 + hist GEMMs
    uber_gemm1<<<D2_HG, 256, 0, stream>>>(
        reps_bf, Wt_e2h, b_e2h, input_reps,
        partA, b_img, W_mm, partC,
        hist_parts, prev_hist_ln, W_hist, partB);

    // D3: mm MFMA (+4-way img rowadd)
    mfma_mm_k<<<512, 256, 0, stream>>>(input_reps, Wt_mm, b_mm, partC, mm_reps);

    // D4: a1 MFMA + fused att dot
    mfma_a1_k<<<256, 256, 0, stream>>>(mm_reps, Wt_a1, b_a1, W_a2, att_part);

    // D5: softmax+attend | sep fuse
    attend_sep<<<288, 256, 0, stream>>>(att_part, masks, b_a2, mm_reps,
                                        partA, partB, b_sep, b_hist,
                                        prev_hist_ln, xcat);

    // D6: f1 GEMM
    thin_f1_k<<<32, 256, 0, stream>>>(xcat, W_f1, partD);

    // D7: final
    final_out2<<<BB, 256, 0, stream>>>(partD, b_f1, W_f2, b_f2, (float*)d_out);
}